// Round 1
// baseline (1566.079 us; speedup 1.0000x reference)
//
#include <hip/hip_runtime.h>
#include <math.h>

#define B 2
#define M 32
#define T 512
#define D 128
#define H 4
#define DK 32
#define LW 16
#define NTOK (B*M*T)   /* 32768 rows */

// ---------------- LayerNorm: one wave per row of 128 ----------------
__global__ __launch_bounds__(256) void ln_kernel(const float* __restrict__ in, float* __restrict__ out,
                                                 const float* __restrict__ g, const float* __restrict__ b)
{
    int wave = threadIdx.x >> 6;
    int lane = threadIdx.x & 63;
    int row  = blockIdx.x * 4 + wave;
    const float* rp = in + (size_t)row * D;
    float v0 = rp[lane], v1 = rp[lane + 64];
    float s = v0 + v1, ss = v0 * v0 + v1 * v1;
    #pragma unroll
    for (int off = 32; off; off >>= 1) { s += __shfl_xor(s, off); ss += __shfl_xor(ss, off); }
    float mu  = s * (1.0f / 128.0f);
    float var = ss * (1.0f / 128.0f) - mu * mu;
    float rs  = rsqrtf(var + 1e-6f);
    float* op = out + (size_t)row * D;
    op[lane]      = (v0 - mu) * rs * g[lane]      + b[lane];
    op[lane + 64] = (v1 - mu) * rs * g[lane + 64] + b[lane + 64];
}

// ---------------- GEMM: out[N x Dout] = act(in[N x Din] . W^T + bias) (+res) ----------------
// W is (Dout, Din) row-major, per reference einsum '...i,oi->...o'.
__global__ __launch_bounds__(256) void gemm_kernel(const float* __restrict__ A, const float* __restrict__ W,
                                                   const float* __restrict__ bias, const float* res, float* out,
                                                   int Din, int Dout, int relu)
{
    __shared__ float As[16][68];   // [kk][row], stride 68 floats (=17*16B) -> aligned float4, 2-way banks
    __shared__ float Bs[16][68];   // [kk][col]
    int tid = threadIdx.x;
    int rowBase = blockIdx.y * 64;
    int colBase = blockIdx.x * 64;
    int tr = tid >> 4, tc = tid & 15;
    int lr = tid >> 2, lc4 = tid & 3;
    float acc[4][4] = {};
    const float* ap = A + (size_t)(rowBase + lr) * Din + lc4 * 4;
    const float* wp = W + (size_t)(colBase + lr) * Din + lc4 * 4;
    for (int k0 = 0; k0 < Din; k0 += 16) {
        float4 av = *(const float4*)(ap + k0);
        float4 wv = *(const float4*)(wp + k0);
        __syncthreads();
        As[lc4*4+0][lr] = av.x; As[lc4*4+1][lr] = av.y; As[lc4*4+2][lr] = av.z; As[lc4*4+3][lr] = av.w;
        Bs[lc4*4+0][lr] = wv.x; Bs[lc4*4+1][lr] = wv.y; Bs[lc4*4+2][lr] = wv.z; Bs[lc4*4+3][lr] = wv.w;
        __syncthreads();
        #pragma unroll
        for (int kk = 0; kk < 16; kk++) {
            float4 a4 = *(const float4*)&As[kk][tr * 4];
            float4 b4 = *(const float4*)&Bs[kk][tc * 4];
            float ar[4] = {a4.x, a4.y, a4.z, a4.w};
            float br[4] = {b4.x, b4.y, b4.z, b4.w};
            #pragma unroll
            for (int i = 0; i < 4; i++)
                #pragma unroll
                for (int j = 0; j < 4; j++)
                    acc[i][j] = fmaf(ar[i], br[j], acc[i][j]);
        }
    }
    float4 bv = *(const float4*)(bias + colBase + tc * 4);
    float bb[4] = {bv.x, bv.y, bv.z, bv.w};
    #pragma unroll
    for (int i = 0; i < 4; i++) {
        int row = rowBase + tr * 4 + i;
        size_t o = (size_t)row * Dout + colBase + tc * 4;
        float v[4];
        #pragma unroll
        for (int j = 0; j < 4; j++) v[j] = acc[i][j] + bb[j];
        if (res) {
            float4 rv = *(const float4*)(res + o);
            v[0] += rv.x; v[1] += rv.y; v[2] += rv.z; v[3] += rv.w;
        }
        if (relu) {
            #pragma unroll
            for (int j = 0; j < 4; j++) v[j] = fmaxf(v[j], 0.0f);
        }
        *(float4*)(out + o) = make_float4(v[0], v[1], v[2], v[3]);
    }
}

// ---------------- Context attention (window L=16 over full d=128) ----------------
// Block: (b*m, 64 positions). Stage rows [t0-15, t0+63] in LDS (zeros for t<0 -> score 0, unmasked).
__global__ __launch_bounds__(256) void ctx_kernel(const float* __restrict__ in, float* __restrict__ out)
{
    __shared__ float xs[79 * D];
    int bm = blockIdx.x >> 3;
    int t0 = (blockIdx.x & 7) * 64;
    const float* base = in + (size_t)bm * T * D;
    for (int idx4 = threadIdx.x; idx4 < 79 * 32; idx4 += 256) {
        int j = idx4 >> 5, c4 = idx4 & 31;
        int t = t0 - 15 + j;
        float4 v = (t >= 0) ? *(const float4*)(base + (size_t)t * D + c4 * 4) : make_float4(0, 0, 0, 0);
        *(float4*)&xs[j * D + c4 * 4] = v;
    }
    __syncthreads();
    int wave = threadIdx.x >> 6, lane = threadIdx.x & 63;
    const float rscale = 0.0883883476483184f;   // 1/sqrt(128)
    for (int p = 0; p < 16; p++) {
        int lt = wave * 16 + p;
        float x0 = xs[(lt + 15) * D + lane];
        float x1 = xs[(lt + 15) * D + 64 + lane];
        float sc[LW];
        #pragma unroll
        for (int l = 0; l < LW; l++) {
            float prod = x0 * xs[(lt + l) * D + lane] + x1 * xs[(lt + l) * D + 64 + lane];
            #pragma unroll
            for (int off = 32; off; off >>= 1) prod += __shfl_xor(prod, off);
            sc[l] = prod * rscale;
        }
        float mx = sc[0];
        #pragma unroll
        for (int l = 1; l < LW; l++) mx = fmaxf(mx, sc[l]);
        float sum = 0.0f;
        #pragma unroll
        for (int l = 0; l < LW; l++) { sc[l] = __expf(sc[l] - mx); sum += sc[l]; }
        float rs = 1.0f / sum;
        float o0 = 0.0f, o1 = 0.0f;
        #pragma unroll
        for (int l = 0; l < LW; l++) { o0 += sc[l] * xs[(lt + l) * D + lane]; o1 += sc[l] * xs[(lt + l) * D + 64 + lane]; }
        out[(size_t)(bm * T + t0 + lt) * D + lane]      = o0 * rs;
        out[(size_t)(bm * T + t0 + lt) * D + 64 + lane] = o1 * rs;
    }
}

// ---------------- Full attention per (b,m,h): flash-style, 1 wave, lane = q row ----------------
__global__ __launch_bounds__(64) void attn_kernel(const float* __restrict__ q, const float* __restrict__ k,
                                                  const float* __restrict__ v, float* __restrict__ out)
{
    __shared__ float Ks[128][36];
    __shared__ float Vs[128][36];
    int qc   = blockIdx.x & 7;
    int h    = (blockIdx.x >> 3) & 3;
    int bm   = blockIdx.x >> 5;
    int lane = threadIdx.x;
    int tq   = qc * 64 + lane;
    const float* qp = q + (size_t)(bm * T + tq) * D + h * DK;
    float qr[32];
    #pragma unroll
    for (int i = 0; i < 8; i++) {
        float4 t4 = *(const float4*)(qp + i * 4);
        qr[i*4] = t4.x; qr[i*4+1] = t4.y; qr[i*4+2] = t4.z; qr[i*4+3] = t4.w;
    }
    float m = -INFINITY, l = 0.0f, O[32];
    #pragma unroll
    for (int i = 0; i < 32; i++) O[i] = 0.0f;
    const float rscale = 0.1767766952966369f;   // 1/sqrt(32)
    for (int kt = 0; kt < 4; kt++) {
        const float* kbase = k + (size_t)(bm * T + kt * 128) * D + h * DK;
        const float* vbase = v + (size_t)(bm * T + kt * 128) * D + h * DK;
        __syncthreads();
        for (int idx = lane; idx < 1024; idx += 64) {
            int r = idx >> 3, c4 = idx & 7;
            *(float4*)&Ks[r][c4 * 4] = *(const float4*)(kbase + (size_t)r * D + c4 * 4);
            *(float4*)&Vs[r][c4 * 4] = *(const float4*)(vbase + (size_t)r * D + c4 * 4);
        }
        __syncthreads();
        for (int c = 0; c < 8; c++) {
            float sv[16];
            #pragma unroll
            for (int u = 0; u < 16; u++) {
                int kr = c * 16 + u;
                float s = 0.0f;
                #pragma unroll
                for (int c8 = 0; c8 < 8; c8++) {
                    float4 k4 = *(const float4*)&Ks[kr][c8 * 4];
                    s = fmaf(qr[c8*4], k4.x, s); s = fmaf(qr[c8*4+1], k4.y, s);
                    s = fmaf(qr[c8*4+2], k4.z, s); s = fmaf(qr[c8*4+3], k4.w, s);
                }
                sv[u] = s * rscale;
            }
            float tm = sv[0];
            #pragma unroll
            for (int u = 1; u < 16; u++) tm = fmaxf(tm, sv[u]);
            float mnew = fmaxf(m, tm);
            float corr = __expf(m - mnew);
            l *= corr;
            #pragma unroll
            for (int i = 0; i < 32; i++) O[i] *= corr;
            #pragma unroll
            for (int u = 0; u < 16; u++) {
                int kr = c * 16 + u;
                float p = __expf(sv[u] - mnew);
                l += p;
                #pragma unroll
                for (int c8 = 0; c8 < 8; c8++) {
                    float4 v4 = *(const float4*)&Vs[kr][c8 * 4];
                    O[c8*4]   = fmaf(p, v4.x, O[c8*4]);   O[c8*4+1] = fmaf(p, v4.y, O[c8*4+1]);
                    O[c8*4+2] = fmaf(p, v4.z, O[c8*4+2]); O[c8*4+3] = fmaf(p, v4.w, O[c8*4+3]);
                }
            }
            m = mnew;
        }
    }
    float rl = 1.0f / l;
    float* op = out + (size_t)(bm * T + tq) * D + h * DK;
    #pragma unroll
    for (int i = 0; i < 8; i++)
        *(float4*)(op + i * 4) = make_float4(O[i*4]*rl, O[i*4+1]*rl, O[i*4+2]*rl, O[i*4+3]*rl);
}

// ---------------- Cross-m attention per (b,t): 4 heads of 32x32 ----------------
__global__ __launch_bounds__(256) void crossm_kernel(const float* __restrict__ in, float* __restrict__ out)
{
    __shared__ float xs[32][133];    // stride 133 (odd*4+128): conflict-free column access
    __shared__ float ss[4][32][33];
    int b = blockIdx.x >> 9;
    int t = blockIdx.x & 511;
    int tid = threadIdx.x;
    for (int idx4 = tid; idx4 < 32 * 32; idx4 += 256) {
        int mq = idx4 >> 5, c4 = idx4 & 31;
        float4 v = *(const float4*)(in + (size_t)((b * M + mq) * T + t) * D + c4 * 4);
        xs[mq][c4*4] = v.x; xs[mq][c4*4+1] = v.y; xs[mq][c4*4+2] = v.z; xs[mq][c4*4+3] = v.w;
    }
    __syncthreads();
    int head = tid >> 6, sub = tid & 63, qi = sub >> 1, half = sub & 1;
    int off = head * 32;
    const float rscale = 0.1767766952966369f;   // 1/sqrt(32)
    float sreg[16];
    #pragma unroll
    for (int u = 0; u < 16; u++) sreg[u] = 0.0f;
    for (int dc = 0; dc < 32; dc++) {
        float xq = xs[qi][off + dc];
        #pragma unroll
        for (int u = 0; u < 16; u++)
            sreg[u] = fmaf(xq, xs[half * 16 + u][off + dc], sreg[u]);
    }
    #pragma unroll
    for (int u = 0; u < 16; u++) ss[head][qi][half * 16 + u] = sreg[u] * rscale;
    __syncthreads();
    if (tid < 128) {
        int hh = tid >> 5, qq = tid & 31;
        float mx = ss[hh][qq][0];
        for (int kk = 1; kk < 32; kk++) mx = fmaxf(mx, ss[hh][qq][kk]);
        float sum = 0.0f;
        for (int kk = 0; kk < 32; kk++) { float e = __expf(ss[hh][qq][kk] - mx); ss[hh][qq][kk] = e; sum += e; }
        float rs = 1.0f / sum;
        for (int kk = 0; kk < 32; kk++) ss[hh][qq][kk] *= rs;
    }
    __syncthreads();
    float o[16];
    #pragma unroll
    for (int u = 0; u < 16; u++) o[u] = 0.0f;
    for (int kk = 0; kk < 32; kk++) {
        float w = ss[head][qi][kk];
        #pragma unroll
        for (int u = 0; u < 16; u++)
            o[u] = fmaf(w, xs[kk][off + half * 16 + u], o[u]);
    }
    float* op = out + (size_t)((b * M + qi) * T + t) * D + off + half * 16;
    #pragma unroll
    for (int u = 0; u < 4; u++)
        *(float4*)(op + u * 4) = make_float4(o[u*4], o[u*4+1], o[u*4+2], o[u*4+3]);
}

// ---------------- launch ----------------
extern "C" void kernel_launch(void* const* d_in, const int* in_sizes, int n_in,
                              void* d_out, int out_size, void* d_ws, size_t ws_size,
                              hipStream_t stream)
{
    (void)in_sizes; (void)n_in; (void)out_size; (void)ws_size;
    const float* xin = (const float*)d_in[0];
    const float* Wq  = (const float*)d_in[1];
    const float* bq  = (const float*)d_in[2];
    const float* Wk  = (const float*)d_in[3];
    const float* bk  = (const float*)d_in[4];
    const float* Wv  = (const float*)d_in[5];
    const float* bv  = (const float*)d_in[6];
    const float* Wfc = (const float*)d_in[7];
    const float* bfc = (const float*)d_in[8];
    const float* W1  = (const float*)d_in[9];
    const float* b1  = (const float*)d_in[10];
    const float* W2  = (const float*)d_in[11];
    const float* b2  = (const float*)d_in[12];
    const float* g1  = (const float*)d_in[13];
    const float* be1 = (const float*)d_in[14];
    const float* g2  = (const float*)d_in[15];
    const float* be2 = (const float*)d_in[16];
    const float* gf  = (const float*)d_in[17];
    const float* bef = (const float*)d_in[18];

    float* X  = (float*)d_out;                 // running residual state
    float* ws = (float*)d_ws;
    const size_t SEG = (size_t)NTOK * D;       // 4,194,304 floats = 16 MiB
    float* Y  = ws;                            // LN output; later aliased as CQ
    float* Qb = ws + SEG;
    float* Kb = ws + 2 * SEG;
    float* Vb = ws + 3 * SEG;
    float* CK = ws + 4 * SEG;
    float* CQ = Y;                             // Y is dead after the 3 projections
    float* Hb = Qb;                            // MLP hidden (32768 x 512) spans Qb..CK

    hipMemcpyAsync(X, xin, SEG * sizeof(float), hipMemcpyDeviceToDevice, stream);

    for (int i = 0; i < 2; i++) {
        ln_kernel<<<NTOK / 4, 256, 0, stream>>>(X, Y, g1 + i * D, be1 + i * D);
        gemm_kernel<<<dim3(2, NTOK / 64), 256, 0, stream>>>(Y, Wq + i * D * D, bq + i * D, nullptr, Qb, D, D, 0);
        gemm_kernel<<<dim3(2, NTOK / 64), 256, 0, stream>>>(Y, Wk + i * D * D, bk + i * D, nullptr, Kb, D, D, 0);
        gemm_kernel<<<dim3(2, NTOK / 64), 256, 0, stream>>>(Y, Wv + i * D * D, bv + i * D, nullptr, Vb, D, D, 0);
        ctx_kernel<<<B * M * (T / 64), 256, 0, stream>>>(Qb, CQ);
        ctx_kernel<<<B * M * (T / 64), 256, 0, stream>>>(Kb, CK);
        attn_kernel<<<B * M * H * (T / 64), 64, 0, stream>>>(CQ, CK, Vb, Qb);
        crossm_kernel<<<B * T, 256, 0, stream>>>(Qb, Kb);
        gemm_kernel<<<dim3(2, NTOK / 64), 256, 0, stream>>>(Kb, Wfc + i * D * D, bfc + i * D, X, X, D, D, 0);
        ln_kernel<<<NTOK / 4, 256, 0, stream>>>(X, Y, g2 + i * D, be2 + i * D);
        gemm_kernel<<<dim3(8, NTOK / 64), 256, 0, stream>>>(Y, W1 + i * 4 * D * D, b1 + i * 4 * D, nullptr, Hb, D, 4 * D, 1);
        gemm_kernel<<<dim3(2, NTOK / 64), 256, 0, stream>>>(Hb, W2 + i * 4 * D * D, b2 + i * D, X, X, 4 * D, D, 0);
    }
    ln_kernel<<<NTOK / 4, 256, 0, stream>>>(X, X, gf, bef);
}

// Round 2
// 799.254 us; speedup vs baseline: 1.9594x; 1.9594x over previous
//
#include <hip/hip_runtime.h>
#include <math.h>

#define B 2
#define M 32
#define T 512
#define D 128
#define H 4
#define DK 32
#define LW 16
#define NTOK (B*M*T)   /* 32768 rows */

using s16x8 = __attribute__((ext_vector_type(8))) short;
using f32x4 = __attribute__((ext_vector_type(4))) float;

__device__ __forceinline__ short f2bf(float x) {
    union { float f; unsigned u; } a; a.f = x;
    unsigned r = a.u + 0x7fffu + ((a.u >> 16) & 1u);   // RNE
    return (short)(r >> 16);
}

// ---------------- LayerNorm: one wave per row of 128 ----------------
__global__ __launch_bounds__(256) void ln_kernel(const float* __restrict__ in, float* __restrict__ out,
                                                 const float* __restrict__ g, const float* __restrict__ b)
{
    int wave = threadIdx.x >> 6;
    int lane = threadIdx.x & 63;
    int row  = blockIdx.x * 4 + wave;
    const float* rp = in + (size_t)row * D;
    float v0 = rp[lane], v1 = rp[lane + 64];
    float s = v0 + v1, ss = v0 * v0 + v1 * v1;
    #pragma unroll
    for (int off = 32; off; off >>= 1) { s += __shfl_xor(s, off); ss += __shfl_xor(ss, off); }
    float mu  = s * (1.0f / 128.0f);
    float var = ss * (1.0f / 128.0f) - mu * mu;
    float rs  = rsqrtf(var + 1e-6f);
    float* op = out + (size_t)row * D;
    op[lane]      = (v0 - mu) * rs * g[lane]      + b[lane];
    op[lane + 64] = (v1 - mu) * rs * g[lane + 64] + b[lane + 64];
}

// ---------------- GEMM: out[N x Dout] = act(in[N x Din] . W^T + bias) (+res) ----------------
// W is (Dout, Din) row-major. If obf != nullptr, write bf16 there instead of fp32 out.
__global__ __launch_bounds__(256) void gemm_kernel(const float* __restrict__ A, const float* __restrict__ W,
                                                   const float* __restrict__ bias, const float* res, float* out,
                                                   short* obf, int Din, int Dout, int relu)
{
    __shared__ float As[16][68];
    __shared__ float Bs[16][68];
    int tid = threadIdx.x;
    int rowBase = blockIdx.y * 64;
    int colBase = blockIdx.x * 64;
    int tr = tid >> 4, tc = tid & 15;
    int lr = tid >> 2, lc4 = tid & 3;
    float acc[4][4] = {};
    const float* ap = A + (size_t)(rowBase + lr) * Din + lc4 * 4;
    const float* wp = W + (size_t)(colBase + lr) * Din + lc4 * 4;
    for (int k0 = 0; k0 < Din; k0 += 16) {
        float4 av = *(const float4*)(ap + k0);
        float4 wv = *(const float4*)(wp + k0);
        __syncthreads();
        As[lc4*4+0][lr] = av.x; As[lc4*4+1][lr] = av.y; As[lc4*4+2][lr] = av.z; As[lc4*4+3][lr] = av.w;
        Bs[lc4*4+0][lr] = wv.x; Bs[lc4*4+1][lr] = wv.y; Bs[lc4*4+2][lr] = wv.z; Bs[lc4*4+3][lr] = wv.w;
        __syncthreads();
        #pragma unroll
        for (int kk = 0; kk < 16; kk++) {
            float4 a4 = *(const float4*)&As[kk][tr * 4];
            float4 b4 = *(const float4*)&Bs[kk][tc * 4];
            float ar[4] = {a4.x, a4.y, a4.z, a4.w};
            float br[4] = {b4.x, b4.y, b4.z, b4.w};
            #pragma unroll
            for (int i = 0; i < 4; i++)
                #pragma unroll
                for (int j = 0; j < 4; j++)
                    acc[i][j] = fmaf(ar[i], br[j], acc[i][j]);
        }
    }
    float4 bv = *(const float4*)(bias + colBase + tc * 4);
    float bb[4] = {bv.x, bv.y, bv.z, bv.w};
    #pragma unroll
    for (int i = 0; i < 4; i++) {
        int row = rowBase + tr * 4 + i;
        size_t o = (size_t)row * Dout + colBase + tc * 4;
        float v[4];
        #pragma unroll
        for (int j = 0; j < 4; j++) v[j] = acc[i][j] + bb[j];
        if (res) {
            float4 rv = *(const float4*)(res + o);
            v[0] += rv.x; v[1] += rv.y; v[2] += rv.z; v[3] += rv.w;
        }
        if (relu) {
            #pragma unroll
            for (int j = 0; j < 4; j++) v[j] = fmaxf(v[j], 0.0f);
        }
        if (obf) {
            ushort4 u;
            u.x = (unsigned short)f2bf(v[0]); u.y = (unsigned short)f2bf(v[1]);
            u.z = (unsigned short)f2bf(v[2]); u.w = (unsigned short)f2bf(v[3]);
            *(ushort4*)(obf + o) = u;
        } else {
            *(float4*)(out + o) = make_float4(v[0], v[1], v[2], v[3]);
        }
    }
}

// ---------------- Context attention (window L=16 over full d=128), bf16 output ----------------
__global__ __launch_bounds__(256) void ctx_kernel(const float* __restrict__ in, short* __restrict__ out)
{
    __shared__ float xs[79 * D];
    int bm = blockIdx.x >> 3;
    int t0 = (blockIdx.x & 7) * 64;
    const float* base = in + (size_t)bm * T * D;
    for (int idx4 = threadIdx.x; idx4 < 79 * 32; idx4 += 256) {
        int j = idx4 >> 5, c4 = idx4 & 31;
        int t = t0 - 15 + j;
        float4 v = (t >= 0) ? *(const float4*)(base + (size_t)t * D + c4 * 4) : make_float4(0, 0, 0, 0);
        *(float4*)&xs[j * D + c4 * 4] = v;
    }
    __syncthreads();
    int wave = threadIdx.x >> 6, lane = threadIdx.x & 63;
    const float rscale = 0.0883883476483184f;   // 1/sqrt(128)
    for (int p = 0; p < 16; p++) {
        int lt = wave * 16 + p;
        float x0 = xs[(lt + 15) * D + lane];
        float x1 = xs[(lt + 15) * D + 64 + lane];
        float sc[LW];
        #pragma unroll
        for (int l = 0; l < LW; l++) {
            float prod = x0 * xs[(lt + l) * D + lane] + x1 * xs[(lt + l) * D + 64 + lane];
            #pragma unroll
            for (int off = 32; off; off >>= 1) prod += __shfl_xor(prod, off);
            sc[l] = prod * rscale;
        }
        float mx = sc[0];
        #pragma unroll
        for (int l = 1; l < LW; l++) mx = fmaxf(mx, sc[l]);
        float sum = 0.0f;
        #pragma unroll
        for (int l = 0; l < LW; l++) { sc[l] = __expf(sc[l] - mx); sum += sc[l]; }
        float rs = 1.0f / sum;
        float o0 = 0.0f, o1 = 0.0f;
        #pragma unroll
        for (int l = 0; l < LW; l++) { o0 += sc[l] * xs[(lt + l) * D + lane]; o1 += sc[l] * xs[(lt + l) * D + 64 + lane]; }
        short* op = out + (size_t)(bm * T + t0 + lt) * D;
        op[lane]      = f2bf(o0 * rs);
        op[lane + 64] = f2bf(o1 * rs);
    }
}

// ---------------- Full attention per (b,m,h): bf16 MFMA flash, 8 waves x 64 q-rows ----------------
#define KPAD 40     /* K/P LDS row stride in bf16 elems (80 B, 16B-aligned, 2-way banks) */
#define VTP  520    /* V^T LDS row stride in bf16 elems (1040 B) */
__global__ __launch_bounds__(512, 2) void attn_mfma_kernel(const short* __restrict__ q, const short* __restrict__ k,
                                                           const short* __restrict__ v, float* __restrict__ out)
{
    __shared__ short Ks[512 * KPAD];      // [kpos][d]   40 KiB
    __shared__ short Vt[32 * VTP];        // [d][kpos]   32.5 KiB
    __shared__ short Ps[8][64 * KPAD];    // per-wave P tile [q][k] 40 KiB

    int h  = blockIdx.x & 3;
    int bm = blockIdx.x >> 2;
    int tid = threadIdx.x;
    size_t headoff = (size_t)(bm * T) * D + h * DK;

    // ---- stage K (row-major, padded) and V^T (scatter) ----
    {
        const s16x8* krow = (const s16x8*)(k + headoff + (size_t)tid * D);
        s16x8 k0 = krow[0], k1 = krow[1], k2 = krow[2], k3 = krow[3];
        short* kd = &Ks[tid * KPAD];
        *(s16x8*)(kd)      = k0;
        *(s16x8*)(kd + 8)  = k1;
        *(s16x8*)(kd + 16) = k2;
        *(s16x8*)(kd + 24) = k3;
        const s16x8* vrow = (const s16x8*)(v + headoff + (size_t)tid * D);
        s16x8 v0 = vrow[0], v1 = vrow[1], v2 = vrow[2], v3 = vrow[3];
        #pragma unroll
        for (int d = 0; d < 8; d++) {
            Vt[(d)      * VTP + tid] = v0[d];
            Vt[(d + 8)  * VTP + tid] = v1[d];
            Vt[(d + 16) * VTP + tid] = v2[d];
            Vt[(d + 24) * VTP + tid] = v3[d];
        }
    }
    __syncthreads();

    int w = tid >> 6, l = tid & 63;
    int lg = l >> 4, lr = l & 15;
    int qw = w * 64;
    short* myP = Ps[w];

    // ---- Q fragments: A-frag lane holds Q[row=lr][k=lg*8+j] ----
    s16x8 qf[4];
    #pragma unroll
    for (int qi = 0; qi < 4; qi++)
        qf[qi] = *(const s16x8*)(q + headoff + (size_t)(qw + qi * 16 + lr) * D + lg * 8);

    f32x4 Oa[4][2];
    float mrow[4][4], lrow[4][4];
    #pragma unroll
    for (int qi = 0; qi < 4; qi++) {
        #pragma unroll
        for (int r = 0; r < 4; r++) { mrow[qi][r] = -1e30f; lrow[qi][r] = 0.0f; Oa[qi][0][r] = 0.0f; Oa[qi][1][r] = 0.0f; }
    }
    const float scale = 0.1767766952966369f;   // 1/sqrt(32)
    f32x4 zacc = {0.0f, 0.0f, 0.0f, 0.0f};

    for (int kt = 0; kt < 16; kt++) {
        // S = Q . K^T  (B-frag of K^T == A-frag of K)
        s16x8 kf0 = *(const s16x8*)&Ks[(kt * 32 + lr) * KPAD + lg * 8];
        s16x8 kf1 = *(const s16x8*)&Ks[(kt * 32 + 16 + lr) * KPAD + lg * 8];
        f32x4 s[4][2];
        #pragma unroll
        for (int qi = 0; qi < 4; qi++) {
            s[qi][0] = __builtin_amdgcn_mfma_f32_16x16x32_bf16(qf[qi], kf0, zacc, 0, 0, 0);
            s[qi][1] = __builtin_amdgcn_mfma_f32_16x16x32_bf16(qf[qi], kf1, zacc, 0, 0, 0);
        }
        // online softmax; C layout: row=(l>>4)*4+r, col=lr
        #pragma unroll
        for (int qi = 0; qi < 4; qi++) {
            #pragma unroll
            for (int r = 0; r < 4; r++) {
                float s0 = s[qi][0][r] * scale;
                float s1 = s[qi][1][r] * scale;
                float mx = fmaxf(s0, s1);
                mx = fmaxf(mx, __shfl_xor(mx, 1));
                mx = fmaxf(mx, __shfl_xor(mx, 2));
                mx = fmaxf(mx, __shfl_xor(mx, 4));
                mx = fmaxf(mx, __shfl_xor(mx, 8));
                float mold = mrow[qi][r];
                float mnew = fmaxf(mold, mx);
                float corr = __expf(mold - mnew);
                float p0 = __expf(s0 - mnew);
                float p1 = __expf(s1 - mnew);
                lrow[qi][r] = lrow[qi][r] * corr + p0 + p1;
                mrow[qi][r] = mnew;
                Oa[qi][0][r] *= corr;
                Oa[qi][1][r] *= corr;
                int qrow = qi * 16 + lg * 4 + r;
                myP[qrow * KPAD + lr]      = f2bf(p0);
                myP[qrow * KPAD + 16 + lr] = f2bf(p1);
            }
        }
        // wave-level LDS visibility for cross-lane P reads (no cross-wave data)
        asm volatile("s_waitcnt lgkmcnt(0)" ::: "memory");
        __builtin_amdgcn_sched_barrier(0);
        // O += P . V   (B-frag from V^T rows, contiguous in k)
        s16x8 vf0 = *(const s16x8*)&Vt[lr * VTP + kt * 32 + lg * 8];
        s16x8 vf1 = *(const s16x8*)&Vt[(16 + lr) * VTP + kt * 32 + lg * 8];
        #pragma unroll
        for (int qi = 0; qi < 4; qi++) {
            s16x8 pf = *(const s16x8*)&myP[(qi * 16 + lr) * KPAD + lg * 8];
            Oa[qi][0] = __builtin_amdgcn_mfma_f32_16x16x32_bf16(pf, vf0, Oa[qi][0], 0, 0, 0);
            Oa[qi][1] = __builtin_amdgcn_mfma_f32_16x16x32_bf16(pf, vf1, Oa[qi][1], 0, 0, 0);
        }
    }

    // ---- epilogue: reduce l across the 16-lane row group, normalize, store fp32 ----
    #pragma unroll
    for (int qi = 0; qi < 4; qi++) {
        #pragma unroll
        for (int r = 0; r < 4; r++) {
            float lv = lrow[qi][r];
            lv += __shfl_xor(lv, 1);
            lv += __shfl_xor(lv, 2);
            lv += __shfl_xor(lv, 4);
            lv += __shfl_xor(lv, 8);
            float rl = 1.0f / lv;
            int qrow = qw + qi * 16 + lg * 4 + r;
            float* op = out + headoff + (size_t)qrow * D;
            op[lr]      = Oa[qi][0][r] * rl;
            op[16 + lr] = Oa[qi][1][r] * rl;
        }
    }
}

// ---------------- Cross-m attention per (b,t): 4 heads of 32x32 ----------------
__global__ __launch_bounds__(256) void crossm_kernel(const float* __restrict__ in, float* __restrict__ out)
{
    __shared__ float xs[32][133];
    __shared__ float ss[4][32][33];
    int b = blockIdx.x >> 9;
    int t = blockIdx.x & 511;
    int tid = threadIdx.x;
    for (int idx4 = tid; idx4 < 32 * 32; idx4 += 256) {
        int mq = idx4 >> 5, c4 = idx4 & 31;
        float4 v = *(const float4*)(in + (size_t)((b * M + mq) * T + t) * D + c4 * 4);
        xs[mq][c4*4] = v.x; xs[mq][c4*4+1] = v.y; xs[mq][c4*4+2] = v.z; xs[mq][c4*4+3] = v.w;
    }
    __syncthreads();
    int head = tid >> 6, sub = tid & 63, qi = sub >> 1, half = sub & 1;
    int off = head * 32;
    const float rscale = 0.1767766952966369f;
    float sreg[16];
    #pragma unroll
    for (int u = 0; u < 16; u++) sreg[u] = 0.0f;
    for (int dc = 0; dc < 32; dc++) {
        float xq = xs[qi][off + dc];
        #pragma unroll
        for (int u = 0; u < 16; u++)
            sreg[u] = fmaf(xq, xs[half * 16 + u][off + dc], sreg[u]);
    }
    #pragma unroll
    for (int u = 0; u < 16; u++) ss[head][qi][half * 16 + u] = sreg[u] * rscale;
    __syncthreads();
    if (tid < 128) {
        int hh = tid >> 5, qq = tid & 31;
        float mx = ss[hh][qq][0];
        for (int kk = 1; kk < 32; kk++) mx = fmaxf(mx, ss[hh][qq][kk]);
        float sum = 0.0f;
        for (int kk = 0; kk < 32; kk++) { float e = __expf(ss[hh][qq][kk] - mx); ss[hh][qq][kk] = e; sum += e; }
        float rs = 1.0f / sum;
        for (int kk = 0; kk < 32; kk++) ss[hh][qq][kk] *= rs;
    }
    __syncthreads();
    float o[16];
    #pragma unroll
    for (int u = 0; u < 16; u++) o[u] = 0.0f;
    for (int kk = 0; kk < 32; kk++) {
        float w = ss[head][qi][kk];
        #pragma unroll
        for (int u = 0; u < 16; u++)
            o[u] = fmaf(w, xs[kk][off + half * 16 + u], o[u]);
    }
    float* op = out + (size_t)((b * M + qi) * T + t) * D + off + half * 16;
    #pragma unroll
    for (int u = 0; u < 4; u++)
        *(float4*)(op + u * 4) = make_float4(o[u*4], o[u*4+1], o[u*4+2], o[u*4+3]);
}

// ---------------- launch ----------------
extern "C" void kernel_launch(void* const* d_in, const int* in_sizes, int n_in,
                              void* d_out, int out_size, void* d_ws, size_t ws_size,
                              hipStream_t stream)
{
    (void)in_sizes; (void)n_in; (void)out_size; (void)ws_size;
    const float* xin = (const float*)d_in[0];
    const float* Wq  = (const float*)d_in[1];
    const float* bq  = (const float*)d_in[2];
    const float* Wk  = (const float*)d_in[3];
    const float* bk  = (const float*)d_in[4];
    const float* Wv  = (const float*)d_in[5];
    const float* bv  = (const float*)d_in[6];
    const float* Wfc = (const float*)d_in[7];
    const float* bfc = (const float*)d_in[8];
    const float* W1  = (const float*)d_in[9];
    const float* b1  = (const float*)d_in[10];
    const float* W2  = (const float*)d_in[11];
    const float* b2  = (const float*)d_in[12];
    const float* g1  = (const float*)d_in[13];
    const float* be1 = (const float*)d_in[14];
    const float* g2  = (const float*)d_in[15];
    const float* be2 = (const float*)d_in[16];
    const float* gf  = (const float*)d_in[17];
    const float* bef = (const float*)d_in[18];

    float* X = (float*)d_out;
    char* wsb = (char*)d_ws;
    const size_t SEGB = (size_t)NTOK * D * sizeof(float);   // 16 MiB
    float* Y   = (float*)(wsb);
    float* Qb  = (float*)(wsb + SEGB);
    float* Kb  = (float*)(wsb + 2 * SEGB);
    short* Vbf = (short*)(wsb + 3 * SEGB);            // 8 MiB bf16
    short* CQb = (short*)(wsb + 3 * SEGB + SEGB / 2); // 8 MiB bf16
    short* CKb = (short*)(wsb + 4 * SEGB);            // 8 MiB bf16 (ends at 72 MiB)
    float* Hb  = Qb;                                  // MLP hidden spans 16..80 MiB (all dead then)

    hipMemcpyAsync(X, xin, SEGB, hipMemcpyDeviceToDevice, stream);

    for (int i = 0; i < 2; i++) {
        ln_kernel<<<NTOK / 4, 256, 0, stream>>>(X, Y, g1 + i * D, be1 + i * D);
        gemm_kernel<<<dim3(2, NTOK / 64), 256, 0, stream>>>(Y, Wq + i * D * D, bq + i * D, nullptr, Qb, nullptr, D, D, 0);
        gemm_kernel<<<dim3(2, NTOK / 64), 256, 0, stream>>>(Y, Wk + i * D * D, bk + i * D, nullptr, Kb, nullptr, D, D, 0);
        gemm_kernel<<<dim3(2, NTOK / 64), 256, 0, stream>>>(Y, Wv + i * D * D, bv + i * D, nullptr, nullptr, Vbf, D, D, 0);
        ctx_kernel<<<B * M * (T / 64), 256, 0, stream>>>(Qb, CQb);
        ctx_kernel<<<B * M * (T / 64), 256, 0, stream>>>(Kb, CKb);
        attn_mfma_kernel<<<B * M * H, 512, 0, stream>>>(CQb, CKb, Vbf, Qb);
        crossm_kernel<<<B * T, 256, 0, stream>>>(Qb, Kb);
        gemm_kernel<<<dim3(2, NTOK / 64), 256, 0, stream>>>(Kb, Wfc + i * D * D, bfc + i * D, X, X, nullptr, D, D, 0);
        ln_kernel<<<NTOK / 4, 256, 0, stream>>>(X, Y, g2 + i * D, be2 + i * D);
        gemm_kernel<<<dim3(8, NTOK / 64), 256, 0, stream>>>(Y, W1 + i * 4 * D * D, b1 + i * 4 * D, nullptr, Hb, nullptr, D, 4 * D, 1);
        gemm_kernel<<<dim3(2, NTOK / 64), 256, 0, stream>>>(Hb, W2 + i * 4 * D * D, b2 + i * D, X, X, nullptr, 4 * D, D, 0);
    }
    ln_kernel<<<NTOK / 4, 256, 0, stream>>>(X, X, gf, bef);
}

// Round 3
// 524.611 us; speedup vs baseline: 2.9852x; 1.5235x over previous
//
#include <hip/hip_runtime.h>
#include <math.h>

#define B 2
#define M 32
#define T 512
#define D 128
#define H 4
#define DK 32
#define LW 16
#define NTOK (B*M*T)   /* 32768 rows */

using s16x8 = __attribute__((ext_vector_type(8))) short;
using f32x4 = __attribute__((ext_vector_type(4))) float;

__device__ __forceinline__ short f2bf(float x) {
    union { float f; unsigned u; } a; a.f = x;
    unsigned r = a.u + 0x7fffu + ((a.u >> 16) & 1u);   // RNE
    return (short)(r >> 16);
}
__device__ __forceinline__ float bf2f(short x) {
    union { unsigned u; float f; } a; a.u = ((unsigned)(unsigned short)x) << 16;
    return a.f;
}

// ---------------- fp32 -> bf16 bulk convert (weights) ----------------
__global__ __launch_bounds__(256) void cvt_kernel(const float* __restrict__ in, short* __restrict__ out, int n)
{
    int i = (blockIdx.x * 256 + threadIdx.x) * 4;
    if (i >= n) return;
    float4 v = *(const float4*)(in + i);
    ushort4 u;
    u.x = (unsigned short)f2bf(v.x); u.y = (unsigned short)f2bf(v.y);
    u.z = (unsigned short)f2bf(v.z); u.w = (unsigned short)f2bf(v.w);
    *(ushort4*)(out + i) = u;
}

// ---------------- LayerNorm: one wave per row of 128; fp32 or bf16 out ----------------
__global__ __launch_bounds__(256) void ln_kernel(const float* __restrict__ in, float* __restrict__ outf,
                                                 short* __restrict__ outb,
                                                 const float* __restrict__ g, const float* __restrict__ b)
{
    int wave = threadIdx.x >> 6;
    int lane = threadIdx.x & 63;
    int row  = blockIdx.x * 4 + wave;
    const float* rp = in + (size_t)row * D;
    float v0 = rp[lane], v1 = rp[lane + 64];
    float s = v0 + v1, ss = v0 * v0 + v1 * v1;
    #pragma unroll
    for (int off = 32; off; off >>= 1) { s += __shfl_xor(s, off); ss += __shfl_xor(ss, off); }
    float mu  = s * (1.0f / 128.0f);
    float var = ss * (1.0f / 128.0f) - mu * mu;
    float rs  = rsqrtf(var + 1e-6f);
    float y0 = (v0 - mu) * rs * g[lane]      + b[lane];
    float y1 = (v1 - mu) * rs * g[lane + 64] + b[lane + 64];
    if (outb) {
        short* op = outb + (size_t)row * D;
        op[lane] = f2bf(y0); op[lane + 64] = f2bf(y1);
    } else {
        float* op = outf + (size_t)row * D;
        op[lane] = y0; op[lane + 64] = y1;
    }
}

// ---------------- bf16 MFMA GEMM: out[N x Dout] = act(A . W^T + bias) (+res) ----------------
// A: N x DIN bf16 row-major; W: Dout x DIN bf16 row-major. 128x128 tile, 8 waves (2x4), wave = 64x32.
#define KP 136   /* LDS row stride in bf16 elems: 272 B -> 8 bank-groups per wave64 b128 op */
template<int DIN>
__global__ __launch_bounds__(512) void gemm_bf16_kernel(const short* __restrict__ A, const short* __restrict__ W,
                                                        const float* __restrict__ bias, const float* __restrict__ res,
                                                        float* __restrict__ outf, short* __restrict__ outb,
                                                        int Dout, int relu)
{
    __shared__ short As[128 * KP];
    __shared__ short Ws[128 * KP];
    const int tid = threadIdx.x;
    const int rowBase = blockIdx.y * 128;
    const int colBase = blockIdx.x * 128;
    const int sr = tid >> 2, sq = tid & 3;        // staging: row, 32-elem quarter
    const int w = tid >> 6, l = tid & 63;
    const int lg = l >> 4, lr = l & 15;
    const int wr = w >> 2, wc = w & 3;            // 2 x 4 wave grid

    f32x4 acc[4][2];
    #pragma unroll
    for (int qi = 0; qi < 4; qi++)
        #pragma unroll
        for (int nj = 0; nj < 2; nj++)
            acc[qi][nj] = (f32x4){0.0f, 0.0f, 0.0f, 0.0f};

    const short* ap = A + (size_t)(rowBase + sr) * DIN + sq * 32;
    const short* wp = W + (size_t)(colBase + sr) * DIN + sq * 32;
    short* asd = &As[sr * KP + sq * 32];
    short* wsd = &Ws[sr * KP + sq * 32];

    #pragma unroll
    for (int kt = 0; kt < DIN / 128; kt++) {
        s16x8 av[4], wv[4];
        #pragma unroll
        for (int i = 0; i < 4; i++) {
            av[i] = *(const s16x8*)(ap + kt * 128 + i * 8);
            wv[i] = *(const s16x8*)(wp + kt * 128 + i * 8);
        }
        if (kt) __syncthreads();
        #pragma unroll
        for (int i = 0; i < 4; i++) {
            *(s16x8*)(asd + i * 8) = av[i];
            *(s16x8*)(wsd + i * 8) = wv[i];
        }
        __syncthreads();
        #pragma unroll
        for (int kk = 0; kk < 4; kk++) {
            s16x8 af[4], bfr[2];
            #pragma unroll
            for (int qi = 0; qi < 4; qi++)
                af[qi] = *(const s16x8*)&As[(wr * 64 + qi * 16 + lr) * KP + kk * 32 + lg * 8];
            #pragma unroll
            for (int nj = 0; nj < 2; nj++)
                bfr[nj] = *(const s16x8*)&Ws[(wc * 32 + nj * 16 + lr) * KP + kk * 32 + lg * 8];
            #pragma unroll
            for (int qi = 0; qi < 4; qi++)
                #pragma unroll
                for (int nj = 0; nj < 2; nj++)
                    acc[qi][nj] = __builtin_amdgcn_mfma_f32_16x16x32_bf16(af[qi], bfr[nj], acc[qi][nj], 0, 0, 0);
        }
    }

    // epilogue; C layout: row=(l>>4)*4+reg, col=l&15
    #pragma unroll
    for (int nj = 0; nj < 2; nj++) {
        int col = colBase + wc * 32 + nj * 16 + lr;
        float bb = bias[col];
        #pragma unroll
        for (int qi = 0; qi < 4; qi++) {
            #pragma unroll
            for (int rr = 0; rr < 4; rr++) {
                int row = rowBase + wr * 64 + qi * 16 + lg * 4 + rr;
                size_t o = (size_t)row * Dout + col;
                float v = acc[qi][nj][rr] + bb;
                if (res) v += res[o];
                if (relu) v = fmaxf(v, 0.0f);
                if (outb) outb[o] = f2bf(v);
                else      outf[o] = v;
            }
        }
    }
}

// ---------------- Context attention (window L=16 over d=128), bf16 in/out ----------------
__global__ __launch_bounds__(256) void ctx_kernel(const short* __restrict__ in, short* __restrict__ out)
{
    __shared__ float xs[79 * D];
    int bm = blockIdx.x >> 3;
    int t0 = (blockIdx.x & 7) * 64;
    const short* base = in + (size_t)bm * T * D;
    for (int idx = threadIdx.x; idx < 79 * 16; idx += 256) {
        int j = idx >> 4, c8 = idx & 15;
        int t = t0 - 15 + j;
        float f[8];
        if (t >= 0) {
            s16x8 v = *(const s16x8*)(base + (size_t)t * D + c8 * 8);
            #pragma unroll
            for (int d = 0; d < 8; d++) f[d] = bf2f(v[d]);
        } else {
            #pragma unroll
            for (int d = 0; d < 8; d++) f[d] = 0.0f;
        }
        #pragma unroll
        for (int d = 0; d < 8; d++) xs[j * D + c8 * 8 + d] = f[d];
    }
    __syncthreads();
    int wave = threadIdx.x >> 6, lane = threadIdx.x & 63;
    const float rscale = 0.0883883476483184f;   // 1/sqrt(128)
    for (int p = 0; p < 16; p++) {
        int lt = wave * 16 + p;
        float x0 = xs[(lt + 15) * D + lane];
        float x1 = xs[(lt + 15) * D + 64 + lane];
        float sc[LW];
        #pragma unroll
        for (int lw = 0; lw < LW; lw++) {
            float prod = x0 * xs[(lt + lw) * D + lane] + x1 * xs[(lt + lw) * D + 64 + lane];
            #pragma unroll
            for (int off = 32; off; off >>= 1) prod += __shfl_xor(prod, off);
            sc[lw] = prod * rscale;
        }
        float mx = sc[0];
        #pragma unroll
        for (int lw = 1; lw < LW; lw++) mx = fmaxf(mx, sc[lw]);
        float sum = 0.0f;
        #pragma unroll
        for (int lw = 0; lw < LW; lw++) { sc[lw] = __expf(sc[lw] - mx); sum += sc[lw]; }
        float rs = 1.0f / sum;
        float o0 = 0.0f, o1 = 0.0f;
        #pragma unroll
        for (int lw = 0; lw < LW; lw++) { o0 += sc[lw] * xs[(lt + lw) * D + lane]; o1 += sc[lw] * xs[(lt + lw) * D + 64 + lane]; }
        short* op = out + (size_t)(bm * T + t0 + lt) * D;
        op[lane]      = f2bf(o0 * rs);
        op[lane + 64] = f2bf(o1 * rs);
    }
}

// ---------------- Full attention per (b,m,h): bf16 MFMA flash, 8 waves x 64 q-rows ----------------
#define KPAD 40
#define VTP  520
__global__ __launch_bounds__(512, 2) void attn_mfma_kernel(const short* __restrict__ q, const short* __restrict__ k,
                                                           const short* __restrict__ v, short* __restrict__ out)
{
    __shared__ short Ks[512 * KPAD];
    __shared__ short Vt[32 * VTP];
    __shared__ short Ps[8][64 * KPAD];

    int h  = blockIdx.x & 3;
    int bm = blockIdx.x >> 2;
    int tid = threadIdx.x;
    size_t headoff = (size_t)(bm * T) * D + h * DK;

    {
        const s16x8* krow = (const s16x8*)(k + headoff + (size_t)tid * D);
        s16x8 k0 = krow[0], k1 = krow[1], k2 = krow[2], k3 = krow[3];
        short* kd = &Ks[tid * KPAD];
        *(s16x8*)(kd)      = k0;
        *(s16x8*)(kd + 8)  = k1;
        *(s16x8*)(kd + 16) = k2;
        *(s16x8*)(kd + 24) = k3;
        const s16x8* vrow = (const s16x8*)(v + headoff + (size_t)tid * D);
        s16x8 v0 = vrow[0], v1 = vrow[1], v2 = vrow[2], v3 = vrow[3];
        #pragma unroll
        for (int d = 0; d < 8; d++) {
            Vt[(d)      * VTP + tid] = v0[d];
            Vt[(d + 8)  * VTP + tid] = v1[d];
            Vt[(d + 16) * VTP + tid] = v2[d];
            Vt[(d + 24) * VTP + tid] = v3[d];
        }
    }
    __syncthreads();

    int w = tid >> 6, l = tid & 63;
    int lg = l >> 4, lr = l & 15;
    int qw = w * 64;
    short* myP = Ps[w];

    s16x8 qf[4];
    #pragma unroll
    for (int qi = 0; qi < 4; qi++)
        qf[qi] = *(const s16x8*)(q + headoff + (size_t)(qw + qi * 16 + lr) * D + lg * 8);

    f32x4 Oa[4][2];
    float mrow[4][4], lrow[4][4];
    #pragma unroll
    for (int qi = 0; qi < 4; qi++) {
        #pragma unroll
        for (int r = 0; r < 4; r++) { mrow[qi][r] = -1e30f; lrow[qi][r] = 0.0f; Oa[qi][0][r] = 0.0f; Oa[qi][1][r] = 0.0f; }
    }
    const float scale = 0.1767766952966369f;
    f32x4 zacc = {0.0f, 0.0f, 0.0f, 0.0f};

    for (int kt = 0; kt < 16; kt++) {
        s16x8 kf0 = *(const s16x8*)&Ks[(kt * 32 + lr) * KPAD + lg * 8];
        s16x8 kf1 = *(const s16x8*)&Ks[(kt * 32 + 16 + lr) * KPAD + lg * 8];
        f32x4 s[4][2];
        #pragma unroll
        for (int qi = 0; qi < 4; qi++) {
            s[qi][0] = __builtin_amdgcn_mfma_f32_16x16x32_bf16(qf[qi], kf0, zacc, 0, 0, 0);
            s[qi][1] = __builtin_amdgcn_mfma_f32_16x16x32_bf16(qf[qi], kf1, zacc, 0, 0, 0);
        }
        #pragma unroll
        for (int qi = 0; qi < 4; qi++) {
            #pragma unroll
            for (int r = 0; r < 4; r++) {
                float s0 = s[qi][0][r] * scale;
                float s1 = s[qi][1][r] * scale;
                float mx = fmaxf(s0, s1);
                mx = fmaxf(mx, __shfl_xor(mx, 1));
                mx = fmaxf(mx, __shfl_xor(mx, 2));
                mx = fmaxf(mx, __shfl_xor(mx, 4));
                mx = fmaxf(mx, __shfl_xor(mx, 8));
                float mold = mrow[qi][r];
                float mnew = fmaxf(mold, mx);
                float corr = __expf(mold - mnew);
                float p0 = __expf(s0 - mnew);
                float p1 = __expf(s1 - mnew);
                lrow[qi][r] = lrow[qi][r] * corr + p0 + p1;
                mrow[qi][r] = mnew;
                Oa[qi][0][r] *= corr;
                Oa[qi][1][r] *= corr;
                int qrow = qi * 16 + lg * 4 + r;
                myP[qrow * KPAD + lr]      = f2bf(p0);
                myP[qrow * KPAD + 16 + lr] = f2bf(p1);
            }
        }
        asm volatile("s_waitcnt lgkmcnt(0)" ::: "memory");
        __builtin_amdgcn_sched_barrier(0);
        s16x8 vf0 = *(const s16x8*)&Vt[lr * VTP + kt * 32 + lg * 8];
        s16x8 vf1 = *(const s16x8*)&Vt[(16 + lr) * VTP + kt * 32 + lg * 8];
        #pragma unroll
        for (int qi = 0; qi < 4; qi++) {
            s16x8 pf = *(const s16x8*)&myP[(qi * 16 + lr) * KPAD + lg * 8];
            Oa[qi][0] = __builtin_amdgcn_mfma_f32_16x16x32_bf16(pf, vf0, Oa[qi][0], 0, 0, 0);
            Oa[qi][1] = __builtin_amdgcn_mfma_f32_16x16x32_bf16(pf, vf1, Oa[qi][1], 0, 0, 0);
        }
    }

    #pragma unroll
    for (int qi = 0; qi < 4; qi++) {
        #pragma unroll
        for (int r = 0; r < 4; r++) {
            float lv = lrow[qi][r];
            lv += __shfl_xor(lv, 1);
            lv += __shfl_xor(lv, 2);
            lv += __shfl_xor(lv, 4);
            lv += __shfl_xor(lv, 8);
            float rl = 1.0f / lv;
            int qrow = qw + qi * 16 + lg * 4 + r;
            short* op = out + headoff + (size_t)qrow * D;
            op[lr]      = f2bf(Oa[qi][0][r] * rl);
            op[16 + lr] = f2bf(Oa[qi][1][r] * rl);
        }
    }
}

// ---------------- Cross-m attention per (b,t): 4 heads of 32x32, bf16 in/out ----------------
__global__ __launch_bounds__(256) void crossm_kernel(const short* __restrict__ in, short* __restrict__ out)
{
    __shared__ float xs[32][133];
    __shared__ float ss[4][32][33];
    int b = blockIdx.x >> 9;
    int t = blockIdx.x & 511;
    int tid = threadIdx.x;
    for (int idx = tid; idx < 32 * 16; idx += 256) {
        int mq = idx >> 4, c8 = idx & 15;
        s16x8 v = *(const s16x8*)(in + (size_t)((b * M + mq) * T + t) * D + c8 * 8);
        #pragma unroll
        for (int d = 0; d < 8; d++) xs[mq][c8 * 8 + d] = bf2f(v[d]);
    }
    __syncthreads();
    int head = tid >> 6, sub = tid & 63, qi = sub >> 1, half = sub & 1;
    int off = head * 32;
    const float rscale = 0.1767766952966369f;
    float sreg[16];
    #pragma unroll
    for (int u = 0; u < 16; u++) sreg[u] = 0.0f;
    for (int dc = 0; dc < 32; dc++) {
        float xq = xs[qi][off + dc];
        #pragma unroll
        for (int u = 0; u < 16; u++)
            sreg[u] = fmaf(xq, xs[half * 16 + u][off + dc], sreg[u]);
    }
    #pragma unroll
    for (int u = 0; u < 16; u++) ss[head][qi][half * 16 + u] = sreg[u] * rscale;
    __syncthreads();
    if (tid < 128) {
        int hh = tid >> 5, qq = tid & 31;
        float mx = ss[hh][qq][0];
        for (int kk = 1; kk < 32; kk++) mx = fmaxf(mx, ss[hh][qq][kk]);
        float sum = 0.0f;
        for (int kk = 0; kk < 32; kk++) { float e = __expf(ss[hh][qq][kk] - mx); ss[hh][qq][kk] = e; sum += e; }
        float rs = 1.0f / sum;
        for (int kk = 0; kk < 32; kk++) ss[hh][qq][kk] *= rs;
    }
    __syncthreads();
    float o[16];
    #pragma unroll
    for (int u = 0; u < 16; u++) o[u] = 0.0f;
    for (int kk = 0; kk < 32; kk++) {
        float wgt = ss[head][qi][kk];
        #pragma unroll
        for (int u = 0; u < 16; u++)
            o[u] = fmaf(wgt, xs[kk][off + half * 16 + u], o[u]);
    }
    short* op = out + (size_t)((b * M + qi) * T + t) * D + off + half * 16;
    #pragma unroll
    for (int u = 0; u < 4; u++) {
        ushort4 pk;
        pk.x = (unsigned short)f2bf(o[u*4]);   pk.y = (unsigned short)f2bf(o[u*4+1]);
        pk.z = (unsigned short)f2bf(o[u*4+2]); pk.w = (unsigned short)f2bf(o[u*4+3]);
        *(ushort4*)(op + u * 4) = pk;
    }
}

// ---------------- launch ----------------
extern "C" void kernel_launch(void* const* d_in, const int* in_sizes, int n_in,
                              void* d_out, int out_size, void* d_ws, size_t ws_size,
                              hipStream_t stream)
{
    (void)in_sizes; (void)n_in; (void)out_size; (void)ws_size;
    const float* xin = (const float*)d_in[0];
    const float* Wq  = (const float*)d_in[1];
    const float* bq  = (const float*)d_in[2];
    const float* Wk  = (const float*)d_in[3];
    const float* bk  = (const float*)d_in[4];
    const float* Wv  = (const float*)d_in[5];
    const float* bv  = (const float*)d_in[6];
    const float* Wfc = (const float*)d_in[7];
    const float* bfc = (const float*)d_in[8];
    const float* W1  = (const float*)d_in[9];
    const float* b1  = (const float*)d_in[10];
    const float* W2  = (const float*)d_in[11];
    const float* b2  = (const float*)d_in[12];
    const float* g1  = (const float*)d_in[13];
    const float* be1 = (const float*)d_in[14];
    const float* g2  = (const float*)d_in[15];
    const float* be2 = (const float*)d_in[16];
    const float* gf  = (const float*)d_in[17];
    const float* bef = (const float*)d_in[18];

    float* X = (float*)d_out;
    char* wsb = (char*)d_ws;
    const size_t SEGB = (size_t)NTOK * D * sizeof(float);   // 16 MiB
    const size_t SEGH = SEGB / 2;                           // 8 MiB (bf16 segment)
    short* Ybf = (short*)(wsb);                  // 0..8 MiB
    short* Qpb = (short*)(wsb + SEGH);           // 8..16
    short* Kpb = (short*)(wsb + 2 * SEGH);       // 16..24
    short* Vbf = (short*)(wsb + 3 * SEGH);       // 24..32
    short* CQb = (short*)(wsb + 4 * SEGH);       // 32..40
    short* CKb = (short*)(wsb + 5 * SEGH);       // 40..48
    short* Hbf = Qpb;                            // MLP hidden bf16, 8..40 MiB (Qpb..CQb dead then)

    size_t woff = 6 * SEGH;                      // 48 MiB
    short* Wqb  = (short*)(wsb + woff); woff += (size_t)2 * D * D * 2;
    short* Wkb  = (short*)(wsb + woff); woff += (size_t)2 * D * D * 2;
    short* Wvb  = (short*)(wsb + woff); woff += (size_t)2 * D * D * 2;
    short* Wfcb = (short*)(wsb + woff); woff += (size_t)2 * D * D * 2;
    short* W1b  = (short*)(wsb + woff); woff += (size_t)2 * 4 * D * D * 2;
    short* W2b  = (short*)(wsb + woff);

    hipMemcpyAsync(X, xin, SEGB, hipMemcpyDeviceToDevice, stream);

    cvt_kernel<<<(2 * D * D) / 1024, 256, 0, stream>>>(Wq,  Wqb,  2 * D * D);
    cvt_kernel<<<(2 * D * D) / 1024, 256, 0, stream>>>(Wk,  Wkb,  2 * D * D);
    cvt_kernel<<<(2 * D * D) / 1024, 256, 0, stream>>>(Wv,  Wvb,  2 * D * D);
    cvt_kernel<<<(2 * D * D) / 1024, 256, 0, stream>>>(Wfc, Wfcb, 2 * D * D);
    cvt_kernel<<<(2 * 4 * D * D) / 1024, 256, 0, stream>>>(W1, W1b, 2 * 4 * D * D);
    cvt_kernel<<<(2 * 4 * D * D) / 1024, 256, 0, stream>>>(W2, W2b, 2 * 4 * D * D);

    for (int i = 0; i < 2; i++) {
        ln_kernel<<<NTOK / 4, 256, 0, stream>>>(X, nullptr, Ybf, g1 + i * D, be1 + i * D);
        gemm_bf16_kernel<128><<<dim3(1, NTOK / 128), 512, 0, stream>>>(Ybf, Wqb + i * D * D, bq + i * D, nullptr, nullptr, Qpb, D, 0);
        gemm_bf16_kernel<128><<<dim3(1, NTOK / 128), 512, 0, stream>>>(Ybf, Wkb + i * D * D, bk + i * D, nullptr, nullptr, Kpb, D, 0);
        gemm_bf16_kernel<128><<<dim3(1, NTOK / 128), 512, 0, stream>>>(Ybf, Wvb + i * D * D, bv + i * D, nullptr, nullptr, Vbf, D, 0);
        ctx_kernel<<<B * M * (T / 64), 256, 0, stream>>>(Qpb, CQb);
        ctx_kernel<<<B * M * (T / 64), 256, 0, stream>>>(Kpb, CKb);
        attn_mfma_kernel<<<B * M * H, 512, 0, stream>>>(CQb, CKb, Vbf, Qpb);
        crossm_kernel<<<B * T, 256, 0, stream>>>(Qpb, Kpb);
        gemm_bf16_kernel<128><<<dim3(1, NTOK / 128), 512, 0, stream>>>(Kpb, Wfcb + i * D * D, bfc + i * D, X, X, nullptr, D, 0);
        ln_kernel<<<NTOK / 4, 256, 0, stream>>>(X, nullptr, Ybf, g2 + i * D, be2 + i * D);
        gemm_bf16_kernel<128><<<dim3(4, NTOK / 128), 512, 0, stream>>>(Ybf, W1b + i * 4 * D * D, b1 + i * 4 * D, nullptr, nullptr, Hbf, 4 * D, 1);
        gemm_bf16_kernel<512><<<dim3(1, NTOK / 128), 512, 0, stream>>>(Hbf, W2b + i * 4 * D * D, b2 + i * D, X, X, nullptr, D, 0);
    }
    ln_kernel<<<NTOK / 4, 256, 0, stream>>>(X, X, nullptr, gf, bef);
}

// Round 4
// 499.156 us; speedup vs baseline: 3.1375x; 1.0510x over previous
//
#include <hip/hip_runtime.h>
#include <hip/hip_bf16.h>
#include <math.h>

#define B 2
#define M 32
#define T 512
#define D 128
#define H 4
#define DK 32
#define LW 16
#define NTOK (B*M*T)   /* 32768 rows */

using s16x8 = __attribute__((ext_vector_type(8))) short;
using s16x4 = __attribute__((ext_vector_type(4))) short;
using f32x4 = __attribute__((ext_vector_type(4))) float;

__device__ __forceinline__ short f2bf(float x) {
    union { float f; unsigned u; } a; a.f = x;
    unsigned r = a.u + 0x7fffu + ((a.u >> 16) & 1u);   // RNE
    return (short)(r >> 16);
}
__device__ __forceinline__ float bf2f(short x) {
    union { unsigned u; float f; } a; a.u = ((unsigned)(unsigned short)x) << 16;
    return a.f;
}
__device__ __forceinline__ unsigned pkbf(float lo, float hi) {
    union { __hip_bfloat162 h; unsigned u; } c;
    c.h = __float22bfloat162_rn(float2{lo, hi});
    return c.u;
}

// ---------------- fp32 -> bf16 bulk convert (weights) ----------------
__global__ __launch_bounds__(256) void cvt_kernel(const float* __restrict__ in, short* __restrict__ out, int n)
{
    int i = (blockIdx.x * 256 + threadIdx.x) * 4;
    if (i >= n) return;
    float4 v = *(const float4*)(in + i);
    ushort4 u;
    u.x = (unsigned short)f2bf(v.x); u.y = (unsigned short)f2bf(v.y);
    u.z = (unsigned short)f2bf(v.z); u.w = (unsigned short)f2bf(v.w);
    *(ushort4*)(out + i) = u;
}

// ---------------- LayerNorm: one wave per row of 128; fp32 or bf16 out ----------------
__global__ __launch_bounds__(256) void ln_kernel(const float* __restrict__ in, float* __restrict__ outf,
                                                 short* __restrict__ outb,
                                                 const float* __restrict__ g, const float* __restrict__ b)
{
    int wave = threadIdx.x >> 6;
    int lane = threadIdx.x & 63;
    int row  = blockIdx.x * 4 + wave;
    const float* rp = in + (size_t)row * D;
    float v0 = rp[lane], v1 = rp[lane + 64];
    float s = v0 + v1, ss = v0 * v0 + v1 * v1;
    #pragma unroll
    for (int off = 32; off; off >>= 1) { s += __shfl_xor(s, off); ss += __shfl_xor(ss, off); }
    float mu  = s * (1.0f / 128.0f);
    float var = ss * (1.0f / 128.0f) - mu * mu;
    float rs  = rsqrtf(var + 1e-6f);
    float y0 = (v0 - mu) * rs * g[lane]      + b[lane];
    float y1 = (v1 - mu) * rs * g[lane + 64] + b[lane + 64];
    if (outb) {
        short* op = outb + (size_t)row * D;
        op[lane] = f2bf(y0); op[lane + 64] = f2bf(y1);
    } else {
        float* op = outf + (size_t)row * D;
        op[lane] = y0; op[lane + 64] = y1;
    }
}

// ---------------- bf16 MFMA GEMM: out[N x Dout] = act(A . W^T + bias) (+res) ----------------
#define KP 136
template<int DIN>
__global__ __launch_bounds__(512) void gemm_bf16_kernel(const short* __restrict__ A, const short* __restrict__ W,
                                                        const float* __restrict__ bias, const float* __restrict__ res,
                                                        float* __restrict__ outf, short* __restrict__ outb,
                                                        int Dout, int relu)
{
    __shared__ short As[128 * KP];
    __shared__ short Ws[128 * KP];
    const int tid = threadIdx.x;
    const int rowBase = blockIdx.y * 128;
    const int colBase = blockIdx.x * 128;
    const int sr = tid >> 2, sq = tid & 3;
    const int w = tid >> 6, l = tid & 63;
    const int lg = l >> 4, lr = l & 15;
    const int wr = w >> 2, wc = w & 3;

    f32x4 acc[4][2];
    #pragma unroll
    for (int qi = 0; qi < 4; qi++)
        #pragma unroll
        for (int nj = 0; nj < 2; nj++)
            acc[qi][nj] = (f32x4){0.0f, 0.0f, 0.0f, 0.0f};

    const short* ap = A + (size_t)(rowBase + sr) * DIN + sq * 32;
    const short* wp = W + (size_t)(colBase + sr) * DIN + sq * 32;
    short* asd = &As[sr * KP + sq * 32];
    short* wsd = &Ws[sr * KP + sq * 32];

    #pragma unroll
    for (int kt = 0; kt < DIN / 128; kt++) {
        s16x8 av[4], wv[4];
        #pragma unroll
        for (int i = 0; i < 4; i++) {
            av[i] = *(const s16x8*)(ap + kt * 128 + i * 8);
            wv[i] = *(const s16x8*)(wp + kt * 128 + i * 8);
        }
        if (kt) __syncthreads();
        #pragma unroll
        for (int i = 0; i < 4; i++) {
            *(s16x8*)(asd + i * 8) = av[i];
            *(s16x8*)(wsd + i * 8) = wv[i];
        }
        __syncthreads();
        #pragma unroll
        for (int kk = 0; kk < 4; kk++) {
            s16x8 af[4], bfr[2];
            #pragma unroll
            for (int qi = 0; qi < 4; qi++)
                af[qi] = *(const s16x8*)&As[(wr * 64 + qi * 16 + lr) * KP + kk * 32 + lg * 8];
            #pragma unroll
            for (int nj = 0; nj < 2; nj++)
                bfr[nj] = *(const s16x8*)&Ws[(wc * 32 + nj * 16 + lr) * KP + kk * 32 + lg * 8];
            #pragma unroll
            for (int qi = 0; qi < 4; qi++)
                #pragma unroll
                for (int nj = 0; nj < 2; nj++)
                    acc[qi][nj] = __builtin_amdgcn_mfma_f32_16x16x32_bf16(af[qi], bfr[nj], acc[qi][nj], 0, 0, 0);
        }
    }

    #pragma unroll
    for (int nj = 0; nj < 2; nj++) {
        int col = colBase + wc * 32 + nj * 16 + lr;
        float bb = bias[col];
        #pragma unroll
        for (int qi = 0; qi < 4; qi++) {
            #pragma unroll
            for (int rr = 0; rr < 4; rr++) {
                int row = rowBase + wr * 64 + qi * 16 + lg * 4 + rr;
                size_t o = (size_t)row * Dout + col;
                float v = acc[qi][nj][rr] + bb;
                if (res) v += res[o];
                if (relu) v = fmaxf(v, 0.0f);
                if (outb) outb[o] = f2bf(v);
                else      outf[o] = v;
            }
        }
    }
}

// ---------------- Context attention (window L=16 over d=128), bf16 in/out ----------------
__global__ __launch_bounds__(256) void ctx_kernel(const short* __restrict__ in, short* __restrict__ out)
{
    __shared__ float xs[79 * D];
    int bm = blockIdx.x >> 3;
    int t0 = (blockIdx.x & 7) * 64;
    const short* base = in + (size_t)bm * T * D;
    for (int idx = threadIdx.x; idx < 79 * 16; idx += 256) {
        int j = idx >> 4, c8 = idx & 15;
        int t = t0 - 15 + j;
        float f[8];
        if (t >= 0) {
            s16x8 v = *(const s16x8*)(base + (size_t)t * D + c8 * 8);
            #pragma unroll
            for (int d = 0; d < 8; d++) f[d] = bf2f(v[d]);
        } else {
            #pragma unroll
            for (int d = 0; d < 8; d++) f[d] = 0.0f;
        }
        #pragma unroll
        for (int d = 0; d < 8; d++) xs[j * D + c8 * 8 + d] = f[d];
    }
    __syncthreads();
    int wave = threadIdx.x >> 6, lane = threadIdx.x & 63;
    const float rscale = 0.0883883476483184f;   // 1/sqrt(128)
    for (int p = 0; p < 16; p++) {
        int lt = wave * 16 + p;
        float x0 = xs[(lt + 15) * D + lane];
        float x1 = xs[(lt + 15) * D + 64 + lane];
        float sc[LW];
        #pragma unroll
        for (int lw = 0; lw < LW; lw++) {
            float prod = x0 * xs[(lt + lw) * D + lane] + x1 * xs[(lt + lw) * D + 64 + lane];
            #pragma unroll
            for (int off = 32; off; off >>= 1) prod += __shfl_xor(prod, off);
            sc[lw] = prod * rscale;
        }
        float mx = sc[0];
        #pragma unroll
        for (int lw = 1; lw < LW; lw++) mx = fmaxf(mx, sc[lw]);
        float sum = 0.0f;
        #pragma unroll
        for (int lw = 0; lw < LW; lw++) { sc[lw] = __expf(sc[lw] - mx); sum += sc[lw]; }
        float rs = 1.0f / sum;
        float o0 = 0.0f, o1 = 0.0f;
        #pragma unroll
        for (int lw = 0; lw < LW; lw++) { o0 += sc[lw] * xs[(lt + lw) * D + lane]; o1 += sc[lw] * xs[(lt + lw) * D + 64 + lane]; }
        short* op = out + (size_t)(bm * T + t0 + lt) * D;
        op[lane]      = f2bf(o0 * rs);
        op[lane + 64] = f2bf(o1 * rs);
    }
}

// ---------------- Full attention per (b,m,h,qhalf): swapped-layout bf16 MFMA flash ----------------
#define KPAD 40
#define VTP  520
__global__ __launch_bounds__(256) void attn_mfma_kernel(const short* __restrict__ q, const short* __restrict__ k,
                                                        const short* __restrict__ v, short* __restrict__ out)
{
    __shared__ short Ks[512 * KPAD];   // 40960 B
    __shared__ short Vt[32 * VTP];     // 33280 B

    int qh = blockIdx.x & 1;
    int h  = (blockIdx.x >> 1) & 3;
    int bm = blockIdx.x >> 3;
    int tid = threadIdx.x;
    size_t headoff = (size_t)(bm * T) * D + h * DK;

    #pragma unroll
    for (int rr = 0; rr < 2; rr++) {
        int row = tid + rr * 256;
        const s16x8* krow = (const s16x8*)(k + headoff + (size_t)row * D);
        s16x8 k0 = krow[0], k1 = krow[1], k2 = krow[2], k3 = krow[3];
        short* kd = &Ks[row * KPAD];
        *(s16x8*)(kd)      = k0;
        *(s16x8*)(kd + 8)  = k1;
        *(s16x8*)(kd + 16) = k2;
        *(s16x8*)(kd + 24) = k3;
        const s16x8* vrow = (const s16x8*)(v + headoff + (size_t)row * D);
        s16x8 v0 = vrow[0], v1 = vrow[1], v2 = vrow[2], v3 = vrow[3];
        #pragma unroll
        for (int d = 0; d < 8; d++) {
            Vt[(d)      * VTP + row] = v0[d];
            Vt[(d + 8)  * VTP + row] = v1[d];
            Vt[(d + 16) * VTP + row] = v2[d];
            Vt[(d + 24) * VTP + row] = v3[d];
        }
    }
    __syncthreads();

    int w = tid >> 6, l = tid & 63;
    int lg = l >> 4, lr = l & 15;
    int qw = qh * 256 + w * 64;

    s16x8 qf[4];
    #pragma unroll
    for (int qi = 0; qi < 4; qi++)
        qf[qi] = *(const s16x8*)(q + headoff + (size_t)(qw + qi * 16 + lr) * D + lg * 8);

    f32x4 Oa[4][2];
    float mrow[4], lrow[4];
    #pragma unroll
    for (int qi = 0; qi < 4; qi++) {
        mrow[qi] = -1e30f; lrow[qi] = 0.0f;
        #pragma unroll
        for (int r = 0; r < 4; r++) { Oa[qi][0][r] = 0.0f; Oa[qi][1][r] = 0.0f; }
    }
    const float C1 = 0.17677669529663689f * 1.4426950408889634f;
    f32x4 zacc = {0.0f, 0.0f, 0.0f, 0.0f};

    for (int kt = 0; kt < 8; kt++) {
        int kb = kt * 64;
        s16x8 kf[2][2];
        #pragma unroll
        for (int s = 0; s < 2; s++)
            #pragma unroll
            for (int hh = 0; hh < 2; hh++)
                kf[s][hh] = *(const s16x8*)&Ks[(kb + s * 32 + hh * 16 + lr) * KPAD + lg * 8];
        s16x8 vf[2][2];
        #pragma unroll
        for (int dh = 0; dh < 2; dh++)
            #pragma unroll
            for (int s = 0; s < 2; s++) {
                const short* vb = &Vt[(dh * 16 + lr) * VTP + kb + s * 32 + lg * 4];
                s16x4 a = *(const s16x4*)(vb);
                s16x4 b = *(const s16x4*)(vb + 16);
                vf[dh][s] = __builtin_shufflevector(a, b, 0, 1, 2, 3, 4, 5, 6, 7);
            }
        #pragma unroll
        for (int qi = 0; qi < 4; qi++) {
            f32x4 sa[2][2];
            #pragma unroll
            for (int s = 0; s < 2; s++)
                #pragma unroll
                for (int hh = 0; hh < 2; hh++)
                    sa[s][hh] = __builtin_amdgcn_mfma_f32_16x16x32_bf16(kf[s][hh], qf[qi], zacc, 0, 0, 0);
            float zm = sa[0][0][0];
            #pragma unroll
            for (int s = 0; s < 2; s++)
                #pragma unroll
                for (int hh = 0; hh < 2; hh++)
                    #pragma unroll
                    for (int r = 0; r < 4; r++) zm = fmaxf(zm, sa[s][hh][r]);
            zm = fmaxf(zm, __shfl_xor(zm, 16));
            zm = fmaxf(zm, __shfl_xor(zm, 32));
            float mold = mrow[qi];
            float mnew = fmaxf(mold, zm);
            float corr = exp2f((mold - mnew) * C1);
            float mc   = mnew * C1;
            float p[2][8];
            float ps = 0.0f;
            #pragma unroll
            for (int s = 0; s < 2; s++)
                #pragma unroll
                for (int hh = 0; hh < 2; hh++)
                    #pragma unroll
                    for (int r = 0; r < 4; r++) {
                        float e = exp2f(fmaf(sa[s][hh][r], C1, -mc));
                        p[s][hh * 4 + r] = e;
                        ps += e;
                    }
            lrow[qi] = lrow[qi] * corr + ps;
            mrow[qi] = mnew;
            #pragma unroll
            for (int r = 0; r < 4; r++) { Oa[qi][0][r] *= corr; Oa[qi][1][r] *= corr; }
            s16x8 pf[2];
            #pragma unroll
            for (int s = 0; s < 2; s++) {
                union { unsigned u[4]; s16x8 v8; } pu;
                pu.u[0] = pkbf(p[s][0], p[s][1]);
                pu.u[1] = pkbf(p[s][2], p[s][3]);
                pu.u[2] = pkbf(p[s][4], p[s][5]);
                pu.u[3] = pkbf(p[s][6], p[s][7]);
                pf[s] = pu.v8;
            }
            #pragma unroll
            for (int dh = 0; dh < 2; dh++)
                #pragma unroll
                for (int s = 0; s < 2; s++)
                    Oa[qi][dh] = __builtin_amdgcn_mfma_f32_16x16x32_bf16(vf[dh][s], pf[s], Oa[qi][dh], 0, 0, 0);
        }
    }

    #pragma unroll
    for (int qi = 0; qi < 4; qi++) {
        float lv = lrow[qi];
        lv += __shfl_xor(lv, 16);
        lv += __shfl_xor(lv, 32);
        float rl = 1.0f / lv;
        int qrow = qw + qi * 16 + lr;
        short* op = out + headoff + (size_t)qrow * D;
        #pragma unroll
        for (int dh = 0; dh < 2; dh++) {
            union { unsigned u[2]; ushort4 s4; } ou;
            ou.u[0] = pkbf(Oa[qi][dh][0] * rl, Oa[qi][dh][1] * rl);
            ou.u[1] = pkbf(Oa[qi][dh][2] * rl, Oa[qi][dh][3] * rl);
            *(ushort4*)(op + dh * 16 + lg * 4) = ou.s4;
        }
    }
}

// ---------------- Cross-m attention per (b,t): 4 heads of 32x32, bf16 in/out ----------------
__global__ __launch_bounds__(256) void crossm_kernel(const short* __restrict__ in, short* __restrict__ out)
{
    __shared__ float xs[32][133];
    __shared__ float ss[4][32][33];
    int b = blockIdx.x >> 9;
    int t = blockIdx.x & 511;
    int tid = threadIdx.x;
    for (int idx = tid; idx < 32 * 16; idx += 256) {
        int mq = idx >> 4, c8 = idx & 15;
        s16x8 v = *(const s16x8*)(in + (size_t)((b * M + mq) * T + t) * D + c8 * 8);
        #pragma unroll
        for (int d = 0; d < 8; d++) xs[mq][c8 * 8 + d] = bf2f(v[d]);
    }
    __syncthreads();
    int head = tid >> 6, sub = tid & 63, qi = sub >> 1, half = sub & 1;
    int off = head * 32;
    const float rscale = 0.1767766952966369f;
    float sreg[16];
    #pragma unroll
    for (int u = 0; u < 16; u++) sreg[u] = 0.0f;
    for (int dc = 0; dc < 32; dc++) {
        float xq = xs[qi][off + dc];
        #pragma unroll
        for (int u = 0; u < 16; u++)
            sreg[u] = fmaf(xq, xs[half * 16 + u][off + dc], sreg[u]);
    }
    #pragma unroll
    for (int u = 0; u < 16; u++) ss[head][qi][half * 16 + u] = sreg[u] * rscale;
    __syncthreads();
    if (tid < 128) {
        int hh = tid >> 5, qq = tid & 31;
        float mx = ss[hh][qq][0];
        for (int kk = 1; kk < 32; kk++) mx = fmaxf(mx, ss[hh][qq][kk]);
        float sum = 0.0f;
        for (int kk = 0; kk < 32; kk++) { float e = __expf(ss[hh][qq][kk] - mx); ss[hh][qq][kk] = e; sum += e; }
        float rs = 1.0f / sum;
        for (int kk = 0; kk < 32; kk++) ss[hh][qq][kk] *= rs;
    }
    __syncthreads();
    float o[16];
    #pragma unroll
    for (int u = 0; u < 16; u++) o[u] = 0.0f;
    for (int kk = 0; kk < 32; kk++) {
        float wgt = ss[head][qi][kk];
        #pragma unroll
        for (int u = 0; u < 16; u++)
            o[u] = fmaf(wgt, xs[kk][off + half * 16 + u], o[u]);
    }
    short* op = out + (size_t)((b * M + qi) * T + t) * D + off + half * 16;
    #pragma unroll
    for (int u = 0; u < 4; u++) {
        ushort4 pk;
        pk.x = (unsigned short)f2bf(o[u*4]);   pk.y = (unsigned short)f2bf(o[u*4+1]);
        pk.z = (unsigned short)f2bf(o[u*4+2]); pk.w = (unsigned short)f2bf(o[u*4+3]);
        *(ushort4*)(op + u * 4) = pk;
    }
}

// ---------------- launch ----------------
extern "C" void kernel_launch(void* const* d_in, const int* in_sizes, int n_in,
                              void* d_out, int out_size, void* d_ws, size_t ws_size,
                              hipStream_t stream)
{
    (void)in_sizes; (void)n_in; (void)out_size; (void)ws_size;
    const float* xin = (const float*)d_in[0];
    const float* Wq  = (const float*)d_in[1];
    const float* bq  = (const float*)d_in[2];
    const float* Wk  = (const float*)d_in[3];
    const float* bk  = (const float*)d_in[4];
    const float* Wv  = (const float*)d_in[5];
    const float* bv  = (const float*)d_in[6];
    const float* Wfc = (const float*)d_in[7];
    const float* bfc = (const float*)d_in[8];
    const float* W1  = (const float*)d_in[9];
    const float* b1  = (const float*)d_in[10];
    const float* W2  = (const float*)d_in[11];
    const float* b2  = (const float*)d_in[12];
    const float* g1  = (const float*)d_in[13];
    const float* be1 = (const float*)d_in[14];
    const float* g2  = (const float*)d_in[15];
    const float* be2 = (const float*)d_in[16];
    const float* gf  = (const float*)d_in[17];
    const float* bef = (const float*)d_in[18];

    float* X = (float*)d_out;
    char* wsb = (char*)d_ws;
    const size_t SEGB = (size_t)NTOK * D * sizeof(float);
    const size_t SEGH = SEGB / 2;
    short* Ybf = (short*)(wsb);
    short* Qpb = (short*)(wsb + SEGH);
    short* Kpb = (short*)(wsb + 2 * SEGH);
    short* Vbf = (short*)(wsb + 3 * SEGH);
    short* CQb = (short*)(wsb + 4 * SEGH);
    short* CKb = (short*)(wsb + 5 * SEGH);
    short* Hbf = Qpb;

    size_t woff = 6 * SEGH;
    short* Wqb  = (short*)(wsb + woff); woff += (size_t)2 * D * D * 2;
    short* Wkb  = (short*)(wsb + woff); woff += (size_t)2 * D * D * 2;
    short* Wvb  = (short*)(wsb + woff); woff += (size_t)2 * D * D * 2;
    short* Wfcb = (short*)(wsb + woff); woff += (size_t)2 * D * D * 2;
    short* W1b  = (short*)(wsb + woff); woff += (size_t)2 * 4 * D * D * 2;
    short* W2b  = (short*)(wsb + woff);

    hipMemcpyAsync(X, xin, SEGB, hipMemcpyDeviceToDevice, stream);

    cvt_kernel<<<(2 * D * D) / 1024, 256, 0, stream>>>(Wq,  Wqb,  2 * D * D);
    cvt_kernel<<<(2 * D * D) / 1024, 256, 0, stream>>>(Wk,  Wkb,  2 * D * D);
    cvt_kernel<<<(2 * D * D) / 1024, 256, 0, stream>>>(Wv,  Wvb,  2 * D * D);
    cvt_kernel<<<(2 * D * D) / 1024, 256, 0, stream>>>(Wfc, Wfcb, 2 * D * D);
    cvt_kernel<<<(2 * 4 * D * D) / 1024, 256, 0, stream>>>(W1, W1b, 2 * 4 * D * D);
    cvt_kernel<<<(2 * 4 * D * D) / 1024, 256, 0, stream>>>(W2, W2b, 2 * 4 * D * D);

    for (int i = 0; i < 2; i++) {
        ln_kernel<<<NTOK / 4, 256, 0, stream>>>(X, nullptr, Ybf, g1 + i * D, be1 + i * D);
        gemm_bf16_kernel<128><<<dim3(1, NTOK / 128), 512, 0, stream>>>(Ybf, Wqb + i * D * D, bq + i * D, nullptr, nullptr, Qpb, D, 0);
        gemm_bf16_kernel<128><<<dim3(1, NTOK / 128), 512, 0, stream>>>(Ybf, Wkb + i * D * D, bk + i * D, nullptr, nullptr, Kpb, D, 0);
        gemm_bf16_kernel<128><<<dim3(1, NTOK / 128), 512, 0, stream>>>(Ybf, Wvb + i * D * D, bv + i * D, nullptr, nullptr, Vbf, D, 0);
        ctx_kernel<<<B * M * (T / 64), 256, 0, stream>>>(Qpb, CQb);
        ctx_kernel<<<B * M * (T / 64), 256, 0, stream>>>(Kpb, CKb);
        attn_mfma_kernel<<<B * M * H * 2, 256, 0, stream>>>(CQb, CKb, Vbf, Qpb);
        crossm_kernel<<<B * T, 256, 0, stream>>>(Qpb, Kpb);
        gemm_bf16_kernel<128><<<dim3(1, NTOK / 128), 512, 0, stream>>>(Kpb, Wfcb + i * D * D, bfc + i * D, X, X, nullptr, D, 0);
        ln_kernel<<<NTOK / 4, 256, 0, stream>>>(X, nullptr, Ybf, g2 + i * D, be2 + i * D);
        gemm_bf16_kernel<128><<<dim3(4, NTOK / 128), 512, 0, stream>>>(Ybf, W1b + i * 4 * D * D, b1 + i * 4 * D, nullptr, nullptr, Hbf, 4 * D, 1);
        gemm_bf16_kernel<512><<<dim3(1, NTOK / 128), 512, 0, stream>>>(Hbf, W2b + i * 4 * D * D, b2 + i * D, X, X, nullptr, D, 0);
    }
    ln_kernel<<<NTOK / 4, 256, 0, stream>>>(X, X, nullptr, gf, bef);
}

// Round 5
// 349.499 us; speedup vs baseline: 4.4809x; 1.4282x over previous
//
#include <hip/hip_runtime.h>
#include <hip/hip_bf16.h>
#include <math.h>

#define B 2
#define M 32
#define T 512
#define D 128
#define H 4
#define DK 32
#define LW 16
#define NTOK (B*M*T)   /* 32768 rows */

using s16x8 = __attribute__((ext_vector_type(8))) short;
using s16x4 = __attribute__((ext_vector_type(4))) short;
using f32x4 = __attribute__((ext_vector_type(4))) float;

__device__ __forceinline__ short f2bf(float x) {
    union { float f; unsigned u; } a; a.f = x;
    unsigned r = a.u + 0x7fffu + ((a.u >> 16) & 1u);   // RNE
    return (short)(r >> 16);
}
__device__ __forceinline__ float bf2f(short x) {
    union { unsigned u; float f; } a; a.u = ((unsigned)(unsigned short)x) << 16;
    return a.f;
}
__device__ __forceinline__ unsigned pkbf(float lo, float hi) {
    union { __hip_bfloat162 h; unsigned u; } c;
    c.h = __float22bfloat162_rn(float2{lo, hi});
    return c.u;
}

// ---------------- fp32 -> bf16 bulk convert (weights) ----------------
__global__ __launch_bounds__(256) void cvt_kernel(const float* __restrict__ in, short* __restrict__ out, int n)
{
    int i = (blockIdx.x * 256 + threadIdx.x) * 4;
    if (i >= n) return;
    float4 v = *(const float4*)(in + i);
    ushort4 u;
    u.x = (unsigned short)f2bf(v.x); u.y = (unsigned short)f2bf(v.y);
    u.z = (unsigned short)f2bf(v.z); u.w = (unsigned short)f2bf(v.w);
    *(ushort4*)(out + i) = u;
}

// ---------------- LayerNorm: one wave per row of 128; fp32 or bf16 out ----------------
__global__ __launch_bounds__(256) void ln_kernel(const float* __restrict__ in, float* __restrict__ outf,
                                                 short* __restrict__ outb,
                                                 const float* __restrict__ g, const float* __restrict__ b)
{
    int wave = threadIdx.x >> 6;
    int lane = threadIdx.x & 63;
    int row  = blockIdx.x * 4 + wave;
    const float* rp = in + (size_t)row * D;
    float v0 = rp[lane], v1 = rp[lane + 64];
    float s = v0 + v1, ss = v0 * v0 + v1 * v1;
    #pragma unroll
    for (int off = 32; off; off >>= 1) { s += __shfl_xor(s, off); ss += __shfl_xor(ss, off); }
    float mu  = s * (1.0f / 128.0f);
    float var = ss * (1.0f / 128.0f) - mu * mu;
    float rs  = rsqrtf(var + 1e-6f);
    float y0 = (v0 - mu) * rs * g[lane]      + b[lane];
    float y1 = (v1 - mu) * rs * g[lane + 64] + b[lane + 64];
    if (outb) {
        short* op = outb + (size_t)row * D;
        op[lane] = f2bf(y0); op[lane + 64] = f2bf(y1);
    } else {
        float* op = outf + (size_t)row * D;
        op[lane] = y0; op[lane + 64] = y1;
    }
}

// ---------------- bf16 MFMA GEMM: out[N x Dout] = act(A . W^T + bias) (+res) ----------------
#define KP 136
template<int DIN>
__global__ __launch_bounds__(512) void gemm_bf16_kernel(const short* __restrict__ A, const short* __restrict__ W,
                                                        const float* __restrict__ bias, const float* __restrict__ res,
                                                        float* __restrict__ outf, short* __restrict__ outb,
                                                        int Dout, int relu)
{
    __shared__ short As[128 * KP];
    __shared__ short Ws[128 * KP];
    const int tid = threadIdx.x;
    const int rowBase = blockIdx.y * 128;
    const int colBase = blockIdx.x * 128;
    const int sr = tid >> 2, sq = tid & 3;
    const int w = tid >> 6, l = tid & 63;
    const int lg = l >> 4, lr = l & 15;
    const int wr = w >> 2, wc = w & 3;

    f32x4 acc[4][2];
    #pragma unroll
    for (int qi = 0; qi < 4; qi++)
        #pragma unroll
        for (int nj = 0; nj < 2; nj++)
            acc[qi][nj] = (f32x4){0.0f, 0.0f, 0.0f, 0.0f};

    const short* ap = A + (size_t)(rowBase + sr) * DIN + sq * 32;
    const short* wp = W + (size_t)(colBase + sr) * DIN + sq * 32;
    short* asd = &As[sr * KP + sq * 32];
    short* wsd = &Ws[sr * KP + sq * 32];

    #pragma unroll
    for (int kt = 0; kt < DIN / 128; kt++) {
        s16x8 av[4], wv[4];
        #pragma unroll
        for (int i = 0; i < 4; i++) {
            av[i] = *(const s16x8*)(ap + kt * 128 + i * 8);
            wv[i] = *(const s16x8*)(wp + kt * 128 + i * 8);
        }
        if (kt) __syncthreads();
        #pragma unroll
        for (int i = 0; i < 4; i++) {
            *(s16x8*)(asd + i * 8) = av[i];
            *(s16x8*)(wsd + i * 8) = wv[i];
        }
        __syncthreads();
        #pragma unroll
        for (int kk = 0; kk < 4; kk++) {
            s16x8 af[4], bfr[2];
            #pragma unroll
            for (int qi = 0; qi < 4; qi++)
                af[qi] = *(const s16x8*)&As[(wr * 64 + qi * 16 + lr) * KP + kk * 32 + lg * 8];
            #pragma unroll
            for (int nj = 0; nj < 2; nj++)
                bfr[nj] = *(const s16x8*)&Ws[(wc * 32 + nj * 16 + lr) * KP + kk * 32 + lg * 8];
            #pragma unroll
            for (int qi = 0; qi < 4; qi++)
                #pragma unroll
                for (int nj = 0; nj < 2; nj++)
                    acc[qi][nj] = __builtin_amdgcn_mfma_f32_16x16x32_bf16(af[qi], bfr[nj], acc[qi][nj], 0, 0, 0);
        }
    }

    #pragma unroll
    for (int nj = 0; nj < 2; nj++) {
        int col = colBase + wc * 32 + nj * 16 + lr;
        float bb = bias[col];
        #pragma unroll
        for (int qi = 0; qi < 4; qi++) {
            #pragma unroll
            for (int rr = 0; rr < 4; rr++) {
                int row = rowBase + wr * 64 + qi * 16 + lg * 4 + rr;
                size_t o = (size_t)row * Dout + col;
                float v = acc[qi][nj][rr] + bb;
                if (res) v += res[o];
                if (relu) v = fmaxf(v, 0.0f);
                if (outb) outb[o] = f2bf(v);
                else      outf[o] = v;
            }
        }
    }
}

// ---------------- Context attention via banded MFMA (window L=16, d=128) ----------------
// Block: (bm, 64 queries). Wave = 16 queries. S^T = mfma(K,Q) over 2 16-col k-tiles;
// mask dlt notin [-15,0]; pad rows (t<0) staged zero -> score 0 unmasked (matches jnp.pad).
// PV: O^T = mfma(X^T frag, P^T frag) with in-lane permuted-k P pack.
#define XSP 136   /* Xs row stride (bf16) */
#define XTP 84    /* Xt row stride (bf16); mult of 4 for 8B-aligned b64 reads */
__global__ __launch_bounds__(256) void ctx_mfma_kernel(const short* __restrict__ in0, short* __restrict__ out0,
                                                       const short* __restrict__ in1, short* __restrict__ out1)
{
    __shared__ short Xs[80 * XSP];    // rows t0-16 .. t0+63, [pos][d]
    __shared__ short Xt[128 * XTP];   // [d][pos_rel]

    const short* in  = blockIdx.y ? in1 : in0;
    short*       out = blockIdx.y ? out1 : out0;
    int bm = blockIdx.x >> 3;
    int t0 = (blockIdx.x & 7) * 64;
    int tid = threadIdx.x;
    const short* base = in + (size_t)bm * T * D;

    // Phase A: global -> Xs (coalesced; c16-fast)
    #pragma unroll
    for (int it = 0; it < 5; it++) {
        int idx = it * 256 + tid;
        int row = idx >> 4, c16 = idx & 15;
        int t = t0 - 16 + row;
        s16x8 v = {0, 0, 0, 0, 0, 0, 0, 0};
        if (t >= 0) v = *(const s16x8*)(base + (size_t)t * D + c16 * 8);
        *(s16x8*)&Xs[row * XSP + c16 * 8] = v;
    }
    __syncthreads();
    // Phase B: Xs -> Xt transpose (row-fast: scatter writes conflict-free)
    #pragma unroll
    for (int it = 0; it < 5; it++) {
        int task = it * 256 + tid;
        int g = task / 80, row = task % 80;
        s16x8 v = *(const s16x8*)&Xs[row * XSP + g * 8];
        #pragma unroll
        for (int j = 0; j < 8; j++) Xt[(g * 8 + j) * XTP + row] = v[j];
    }
    __syncthreads();

    int w = tid >> 6, l = tid & 63;
    int lg = l >> 4, lr = l & 15;
    f32x4 zacc = {0.0f, 0.0f, 0.0f, 0.0f};
    const float C1 = 0.0883883476483184f * 1.4426950408889634f;   // (1/sqrt(128))*log2e

    // Q fragments (B-side): q = t0 + w*16 + lr -> Xs row rel 16 + w*16 + lr
    s16x8 qf[4];
    #pragma unroll
    for (int kd = 0; kd < 4; kd++)
        qf[kd] = *(const s16x8*)&Xs[(16 + w * 16 + lr) * XSP + kd * 32 + lg * 8];

    // S^T: two k-tiles (k rel rows w*16 + s*16 + lr), K=128 chained
    f32x4 sacc[2];
    #pragma unroll
    for (int s = 0; s < 2; s++) {
        f32x4 a = zacc;
        #pragma unroll
        for (int kd = 0; kd < 4; kd++) {
            s16x8 kf = *(const s16x8*)&Xs[(w * 16 + s * 16 + lr) * XSP + kd * 32 + lg * 8];
            a = __builtin_amdgcn_mfma_f32_16x16x32_bf16(kf, qf[kd], a, 0, 0, 0);
        }
        sacc[s] = a;
    }

    // mask + softmax (lane-local over 8, + 2 shfls over lg axis)
    float p[2][4];
    float mx = -1e30f;
    #pragma unroll
    for (int s = 0; s < 2; s++)
        #pragma unroll
        for (int r = 0; r < 4; r++) {
            int dlt = s * 16 + lg * 4 + r - 16 - lr;   // k - q
            float val = (dlt >= -15 && dlt <= 0) ? sacc[s][r] : -1e30f;
            p[s][r] = val;
            mx = fmaxf(mx, val);
        }
    mx = fmaxf(mx, __shfl_xor(mx, 16));
    mx = fmaxf(mx, __shfl_xor(mx, 32));
    float mc = mx * C1;
    float ps = 0.0f;
    #pragma unroll
    for (int s = 0; s < 2; s++)
        #pragma unroll
        for (int r = 0; r < 4; r++) {
            float e = exp2f(fmaf(p[s][r], C1, -mc));
            p[s][r] = e;
            ps += e;
        }
    ps += __shfl_xor(ps, 16);
    ps += __shfl_xor(ps, 32);

    // pack P^T fragment (permuted-k order shared with Xt reads)
    union { unsigned u[4]; s16x8 v8; } pu;
    pu.u[0] = pkbf(p[0][0], p[0][1]);
    pu.u[1] = pkbf(p[0][2], p[0][3]);
    pu.u[2] = pkbf(p[1][0], p[1][1]);
    pu.u[3] = pkbf(p[1][2], p[1][3]);
    s16x8 pf = pu.v8;

    // O^T = X^T . P^T per 16-d tile
    float rl = 1.0f / ps;
    short* op = out + (size_t)(bm * T + t0 + w * 16 + lr) * D;
    #pragma unroll
    for (int dt = 0; dt < 8; dt++) {
        const short* vb = &Xt[(dt * 16 + lr) * XTP + w * 16 + lg * 4];
        s16x4 a = *(const s16x4*)(vb);
        s16x4 b = *(const s16x4*)(vb + 16);
        s16x8 vf = __builtin_shufflevector(a, b, 0, 1, 2, 3, 4, 5, 6, 7);
        f32x4 Oa = __builtin_amdgcn_mfma_f32_16x16x32_bf16(vf, pf, zacc, 0, 0, 0);
        union { unsigned u[2]; ushort4 s4; } ou;
        ou.u[0] = pkbf(Oa[0] * rl, Oa[1] * rl);
        ou.u[1] = pkbf(Oa[2] * rl, Oa[3] * rl);
        *(ushort4*)(op + dt * 16 + lg * 4) = ou.s4;
    }
}

// ---------------- Full attention per (b,m,h,qhalf): swapped-layout bf16 MFMA flash ----------------
#define KPAD 40
#define VTP  520
__global__ __launch_bounds__(256) void attn_mfma_kernel(const short* __restrict__ q, const short* __restrict__ k,
                                                        const short* __restrict__ v, short* __restrict__ out)
{
    __shared__ short Ks[512 * KPAD];   // 40960 B
    __shared__ short Vt[32 * VTP];     // 33280 B

    int qh = blockIdx.x & 1;
    int h  = (blockIdx.x >> 1) & 3;
    int bm = blockIdx.x >> 3;
    int tid = threadIdx.x;
    size_t headoff = (size_t)(bm * T) * D + h * DK;

    #pragma unroll
    for (int rr = 0; rr < 2; rr++) {
        int row = tid + rr * 256;
        const s16x8* krow = (const s16x8*)(k + headoff + (size_t)row * D);
        s16x8 k0 = krow[0], k1 = krow[1], k2 = krow[2], k3 = krow[3];
        short* kd = &Ks[row * KPAD];
        *(s16x8*)(kd)      = k0;
        *(s16x8*)(kd + 8)  = k1;
        *(s16x8*)(kd + 16) = k2;
        *(s16x8*)(kd + 24) = k3;
        const s16x8* vrow = (const s16x8*)(v + headoff + (size_t)row * D);
        s16x8 v0 = vrow[0], v1 = vrow[1], v2 = vrow[2], v3 = vrow[3];
        #pragma unroll
        for (int d = 0; d < 8; d++) {
            Vt[(d)      * VTP + row] = v0[d];
            Vt[(d + 8)  * VTP + row] = v1[d];
            Vt[(d + 16) * VTP + row] = v2[d];
            Vt[(d + 24) * VTP + row] = v3[d];
        }
    }
    __syncthreads();

    int w = tid >> 6, l = tid & 63;
    int lg = l >> 4, lr = l & 15;
    int qw = qh * 256 + w * 64;

    s16x8 qf[4];
    #pragma unroll
    for (int qi = 0; qi < 4; qi++)
        qf[qi] = *(const s16x8*)(q + headoff + (size_t)(qw + qi * 16 + lr) * D + lg * 8);

    f32x4 Oa[4][2];
    float mrow[4], lrow[4];
    #pragma unroll
    for (int qi = 0; qi < 4; qi++) {
        mrow[qi] = -1e30f; lrow[qi] = 0.0f;
        #pragma unroll
        for (int r = 0; r < 4; r++) { Oa[qi][0][r] = 0.0f; Oa[qi][1][r] = 0.0f; }
    }
    const float C1 = 0.17677669529663689f * 1.4426950408889634f;
    f32x4 zacc = {0.0f, 0.0f, 0.0f, 0.0f};

    for (int kt = 0; kt < 8; kt++) {
        int kb = kt * 64;
        s16x8 kf[2][2];
        #pragma unroll
        for (int s = 0; s < 2; s++)
            #pragma unroll
            for (int hh = 0; hh < 2; hh++)
                kf[s][hh] = *(const s16x8*)&Ks[(kb + s * 32 + hh * 16 + lr) * KPAD + lg * 8];
        s16x8 vf[2][2];
        #pragma unroll
        for (int dh = 0; dh < 2; dh++)
            #pragma unroll
            for (int s = 0; s < 2; s++) {
                const short* vb = &Vt[(dh * 16 + lr) * VTP + kb + s * 32 + lg * 4];
                s16x4 a = *(const s16x4*)(vb);
                s16x4 b = *(const s16x4*)(vb + 16);
                vf[dh][s] = __builtin_shufflevector(a, b, 0, 1, 2, 3, 4, 5, 6, 7);
            }
        #pragma unroll
        for (int qi = 0; qi < 4; qi++) {
            f32x4 sa[2][2];
            #pragma unroll
            for (int s = 0; s < 2; s++)
                #pragma unroll
                for (int hh = 0; hh < 2; hh++)
                    sa[s][hh] = __builtin_amdgcn_mfma_f32_16x16x32_bf16(kf[s][hh], qf[qi], zacc, 0, 0, 0);
            float zm = sa[0][0][0];
            #pragma unroll
            for (int s = 0; s < 2; s++)
                #pragma unroll
                for (int hh = 0; hh < 2; hh++)
                    #pragma unroll
                    for (int r = 0; r < 4; r++) zm = fmaxf(zm, sa[s][hh][r]);
            zm = fmaxf(zm, __shfl_xor(zm, 16));
            zm = fmaxf(zm, __shfl_xor(zm, 32));
            float mold = mrow[qi];
            float mnew = fmaxf(mold, zm);
            float corr = exp2f((mold - mnew) * C1);
            float mc   = mnew * C1;
            float p[2][8];
            float ps = 0.0f;
            #pragma unroll
            for (int s = 0; s < 2; s++)
                #pragma unroll
                for (int hh = 0; hh < 2; hh++)
                    #pragma unroll
                    for (int r = 0; r < 4; r++) {
                        float e = exp2f(fmaf(sa[s][hh][r], C1, -mc));
                        p[s][hh * 4 + r] = e;
                        ps += e;
                    }
            lrow[qi] = lrow[qi] * corr + ps;
            mrow[qi] = mnew;
            #pragma unroll
            for (int r = 0; r < 4; r++) { Oa[qi][0][r] *= corr; Oa[qi][1][r] *= corr; }
            s16x8 pf[2];
            #pragma unroll
            for (int s = 0; s < 2; s++) {
                union { unsigned u[4]; s16x8 v8; } pu;
                pu.u[0] = pkbf(p[s][0], p[s][1]);
                pu.u[1] = pkbf(p[s][2], p[s][3]);
                pu.u[2] = pkbf(p[s][4], p[s][5]);
                pu.u[3] = pkbf(p[s][6], p[s][7]);
                pf[s] = pu.v8;
            }
            #pragma unroll
            for (int dh = 0; dh < 2; dh++)
                #pragma unroll
                for (int s = 0; s < 2; s++)
                    Oa[qi][dh] = __builtin_amdgcn_mfma_f32_16x16x32_bf16(vf[dh][s], pf[s], Oa[qi][dh], 0, 0, 0);
        }
    }

    #pragma unroll
    for (int qi = 0; qi < 4; qi++) {
        float lv = lrow[qi];
        lv += __shfl_xor(lv, 16);
        lv += __shfl_xor(lv, 32);
        float rl = 1.0f / lv;
        int qrow = qw + qi * 16 + lr;
        short* op = out + headoff + (size_t)qrow * D;
        #pragma unroll
        for (int dh = 0; dh < 2; dh++) {
            union { unsigned u[2]; ushort4 s4; } ou;
            ou.u[0] = pkbf(Oa[qi][dh][0] * rl, Oa[qi][dh][1] * rl);
            ou.u[1] = pkbf(Oa[qi][dh][2] * rl, Oa[qi][dh][3] * rl);
            *(ushort4*)(op + dh * 16 + lg * 4) = ou.s4;
        }
    }
}

// ---------------- Cross-m attention per (b,t): 4 heads of 32x32, bf16 in/out ----------------
__global__ __launch_bounds__(256) void crossm_kernel(const short* __restrict__ in, short* __restrict__ out)
{
    __shared__ float xs[32][133];
    __shared__ float ss[4][32][33];
    int b = blockIdx.x >> 9;
    int t = blockIdx.x & 511;
    int tid = threadIdx.x;
    for (int idx = tid; idx < 32 * 16; idx += 256) {
        int mq = idx >> 4, c8 = idx & 15;
        s16x8 v = *(const s16x8*)(in + (size_t)((b * M + mq) * T + t) * D + c8 * 8);
        #pragma unroll
        for (int d = 0; d < 8; d++) xs[mq][c8 * 8 + d] = bf2f(v[d]);
    }
    __syncthreads();
    int head = tid >> 6, sub = tid & 63, qi = sub >> 1, half = sub & 1;
    int off = head * 32;
    const float rscale = 0.1767766952966369f;
    float sreg[16];
    #pragma unroll
    for (int u = 0; u < 16; u++) sreg[u] = 0.0f;
    for (int dc = 0; dc < 32; dc++) {
        float xq = xs[qi][off + dc];
        #pragma unroll
        for (int u = 0; u < 16; u++)
            sreg[u] = fmaf(xq, xs[half * 16 + u][off + dc], sreg[u]);
    }
    #pragma unroll
    for (int u = 0; u < 16; u++) ss[head][qi][half * 16 + u] = sreg[u] * rscale;
    __syncthreads();
    if (tid < 128) {
        int hh = tid >> 5, qq = tid & 31;
        float mx = ss[hh][qq][0];
        for (int kk = 1; kk < 32; kk++) mx = fmaxf(mx, ss[hh][qq][kk]);
        float sum = 0.0f;
        for (int kk = 0; kk < 32; kk++) { float e = __expf(ss[hh][qq][kk] - mx); ss[hh][qq][kk] = e; sum += e; }
        float rs = 1.0f / sum;
        for (int kk = 0; kk < 32; kk++) ss[hh][qq][kk] *= rs;
    }
    __syncthreads();
    float o[16];
    #pragma unroll
    for (int u = 0; u < 16; u++) o[u] = 0.0f;
    for (int kk = 0; kk < 32; kk++) {
        float wgt = ss[head][qi][kk];
        #pragma unroll
        for (int u = 0; u < 16; u++)
            o[u] = fmaf(wgt, xs[kk][off + half * 16 + u], o[u]);
    }
    short* op = out + (size_t)((b * M + qi) * T + t) * D + off + half * 16;
    #pragma unroll
    for (int u = 0; u < 4; u++) {
        ushort4 pk;
        pk.x = (unsigned short)f2bf(o[u*4]);   pk.y = (unsigned short)f2bf(o[u*4+1]);
        pk.z = (unsigned short)f2bf(o[u*4+2]); pk.w = (unsigned short)f2bf(o[u*4+3]);
        *(ushort4*)(op + u * 4) = pk;
    }
}

// ---------------- launch ----------------
extern "C" void kernel_launch(void* const* d_in, const int* in_sizes, int n_in,
                              void* d_out, int out_size, void* d_ws, size_t ws_size,
                              hipStream_t stream)
{
    (void)in_sizes; (void)n_in; (void)out_size; (void)ws_size;
    const float* xin = (const float*)d_in[0];
    const float* Wq  = (const float*)d_in[1];
    const float* bq  = (const float*)d_in[2];
    const float* Wk  = (const float*)d_in[3];
    const float* bk  = (const float*)d_in[4];
    const float* Wv  = (const float*)d_in[5];
    const float* bv  = (const float*)d_in[6];
    const float* Wfc = (const float*)d_in[7];
    const float* bfc = (const float*)d_in[8];
    const float* W1  = (const float*)d_in[9];
    const float* b1  = (const float*)d_in[10];
    const float* W2  = (const float*)d_in[11];
    const float* b2  = (const float*)d_in[12];
    const float* g1  = (const float*)d_in[13];
    const float* be1 = (const float*)d_in[14];
    const float* g2  = (const float*)d_in[15];
    const float* be2 = (const float*)d_in[16];
    const float* gf  = (const float*)d_in[17];
    const float* bef = (const float*)d_in[18];

    float* X = (float*)d_out;
    char* wsb = (char*)d_ws;
    const size_t SEGB = (size_t)NTOK * D * sizeof(float);
    const size_t SEGH = SEGB / 2;
    short* Ybf = (short*)(wsb);
    short* Qpb = (short*)(wsb + SEGH);
    short* Kpb = (short*)(wsb + 2 * SEGH);
    short* Vbf = (short*)(wsb + 3 * SEGH);
    short* CQb = (short*)(wsb + 4 * SEGH);
    short* CKb = (short*)(wsb + 5 * SEGH);
    short* Hbf = Qpb;

    size_t woff = 6 * SEGH;
    short* Wqb  = (short*)(wsb + woff); woff += (size_t)2 * D * D * 2;
    short* Wkb  = (short*)(wsb + woff); woff += (size_t)2 * D * D * 2;
    short* Wvb  = (short*)(wsb + woff); woff += (size_t)2 * D * D * 2;
    short* Wfcb = (short*)(wsb + woff); woff += (size_t)2 * D * D * 2;
    short* W1b  = (short*)(wsb + woff); woff += (size_t)2 * 4 * D * D * 2;
    short* W2b  = (short*)(wsb + woff);

    hipMemcpyAsync(X, xin, SEGB, hipMemcpyDeviceToDevice, stream);

    cvt_kernel<<<(2 * D * D) / 1024, 256, 0, stream>>>(Wq,  Wqb,  2 * D * D);
    cvt_kernel<<<(2 * D * D) / 1024, 256, 0, stream>>>(Wk,  Wkb,  2 * D * D);
    cvt_kernel<<<(2 * D * D) / 1024, 256, 0, stream>>>(Wv,  Wvb,  2 * D * D);
    cvt_kernel<<<(2 * D * D) / 1024, 256, 0, stream>>>(Wfc, Wfcb, 2 * D * D);
    cvt_kernel<<<(2 * 4 * D * D) / 1024, 256, 0, stream>>>(W1, W1b, 2 * 4 * D * D);
    cvt_kernel<<<(2 * 4 * D * D) / 1024, 256, 0, stream>>>(W2, W2b, 2 * 4 * D * D);

    for (int i = 0; i < 2; i++) {
        ln_kernel<<<NTOK / 4, 256, 0, stream>>>(X, nullptr, Ybf, g1 + i * D, be1 + i * D);
        gemm_bf16_kernel<128><<<dim3(1, NTOK / 128), 512, 0, stream>>>(Ybf, Wqb + i * D * D, bq + i * D, nullptr, nullptr, Qpb, D, 0);
        gemm_bf16_kernel<128><<<dim3(1, NTOK / 128), 512, 0, stream>>>(Ybf, Wkb + i * D * D, bk + i * D, nullptr, nullptr, Kpb, D, 0);
        gemm_bf16_kernel<128><<<dim3(1, NTOK / 128), 512, 0, stream>>>(Ybf, Wvb + i * D * D, bv + i * D, nullptr, nullptr, Vbf, D, 0);
        ctx_mfma_kernel<<<dim3(B * M * (T / 64), 2), 256, 0, stream>>>(Qpb, CQb, Kpb, CKb);
        attn_mfma_kernel<<<B * M * H * 2, 256, 0, stream>>>(CQb, CKb, Vbf, Qpb);
        crossm_kernel<<<B * T, 256, 0, stream>>>(Qpb, Kpb);
        gemm_bf16_kernel<128><<<dim3(1, NTOK / 128), 512, 0, stream>>>(Kpb, Wfcb + i * D * D, bfc + i * D, X, X, nullptr, D, 0);
        ln_kernel<<<NTOK / 4, 256, 0, stream>>>(X, nullptr, Ybf, g2 + i * D, be2 + i * D);
        gemm_bf16_kernel<128><<<dim3(4, NTOK / 128), 512, 0, stream>>>(Ybf, W1b + i * 4 * D * D, b1 + i * 4 * D, nullptr, nullptr, Hbf, 4 * D, 1);
        gemm_bf16_kernel<512><<<dim3(1, NTOK / 128), 512, 0, stream>>>(Hbf, W2b + i * 4 * D * D, b2 + i * D, X, X, nullptr, D, 0);
    }
    ln_kernel<<<NTOK / 4, 256, 0, stream>>>(X, X, nullptr, gf, bef);
}

// Round 6
// 292.457 us; speedup vs baseline: 5.3549x; 1.1950x over previous
//
#include <hip/hip_runtime.h>
#include <hip/hip_bf16.h>
#include <math.h>

#define B 2
#define M 32
#define T 512
#define D 128
#define H 4
#define DK 32
#define LW 16
#define NTOK (B*M*T)   /* 32768 rows */

using s16x8 = __attribute__((ext_vector_type(8))) short;
using s16x4 = __attribute__((ext_vector_type(4))) short;
using f32x4 = __attribute__((ext_vector_type(4))) float;

__device__ __forceinline__ short f2bf(float x) {
    union { float f; unsigned u; } a; a.f = x;
    unsigned r = a.u + 0x7fffu + ((a.u >> 16) & 1u);   // RNE
    return (short)(r >> 16);
}
__device__ __forceinline__ float bf2f(short x) {
    union { unsigned u; float f; } a; a.u = ((unsigned)(unsigned short)x) << 16;
    return a.f;
}
__device__ __forceinline__ unsigned pkbf(float lo, float hi) {
    union { __hip_bfloat162 h; unsigned u; } c;
    c.h = __float22bfloat162_rn(float2{lo, hi});
    return c.u;
}

// ---------------- fp32 -> bf16 bulk convert (weights) ----------------
__global__ __launch_bounds__(256) void cvt_kernel(const float* __restrict__ in, short* __restrict__ out, int n)
{
    int i = (blockIdx.x * 256 + threadIdx.x) * 4;
    if (i >= n) return;
    float4 v = *(const float4*)(in + i);
    ushort4 u;
    u.x = (unsigned short)f2bf(v.x); u.y = (unsigned short)f2bf(v.y);
    u.z = (unsigned short)f2bf(v.z); u.w = (unsigned short)f2bf(v.w);
    *(ushort4*)(out + i) = u;
}

// ---------------- LayerNorm: one wave per row of 128; fp32 or bf16 out ----------------
__global__ __launch_bounds__(256) void ln_kernel(const float* __restrict__ in, float* __restrict__ outf,
                                                 short* __restrict__ outb,
                                                 const float* __restrict__ g, const float* __restrict__ b)
{
    int wave = threadIdx.x >> 6;
    int lane = threadIdx.x & 63;
    int row  = blockIdx.x * 4 + wave;
    const float* rp = in + (size_t)row * D;
    float v0 = rp[lane], v1 = rp[lane + 64];
    float s = v0 + v1, ss = v0 * v0 + v1 * v1;
    #pragma unroll
    for (int off = 32; off; off >>= 1) { s += __shfl_xor(s, off); ss += __shfl_xor(ss, off); }
    float mu  = s * (1.0f / 128.0f);
    float var = ss * (1.0f / 128.0f) - mu * mu;
    float rs  = rsqrtf(var + 1e-6f);
    float y0 = (v0 - mu) * rs * g[lane]      + b[lane];
    float y1 = (v1 - mu) * rs * g[lane + 64] + b[lane + 64];
    if (outb) {
        short* op = outb + (size_t)row * D;
        op[lane] = f2bf(y0); op[lane + 64] = f2bf(y1);
    } else {
        float* op = outf + (size_t)row * D;
        op[lane] = y0; op[lane + 64] = y1;
    }
}

// ---------------- bf16 MFMA GEMM: out[N x Dout] = act(A . W^T + bias) (+res) ----------------
#define KP 136
template<int DIN>
__global__ __launch_bounds__(512) void gemm_bf16_kernel(const short* __restrict__ A, const short* __restrict__ W,
                                                        const float* __restrict__ bias, const float* __restrict__ res,
                                                        float* __restrict__ outf, short* __restrict__ outb,
                                                        int Dout, int relu)
{
    __shared__ short As[128 * KP];
    __shared__ short Ws[128 * KP];
    const int tid = threadIdx.x;
    const int rowBase = blockIdx.y * 128;
    const int colBase = blockIdx.x * 128;
    const int sr = tid >> 2, sq = tid & 3;
    const int w = tid >> 6, l = tid & 63;
    const int lg = l >> 4, lr = l & 15;
    const int wr = w >> 2, wc = w & 3;

    f32x4 acc[4][2];
    #pragma unroll
    for (int qi = 0; qi < 4; qi++)
        #pragma unroll
        for (int nj = 0; nj < 2; nj++)
            acc[qi][nj] = (f32x4){0.0f, 0.0f, 0.0f, 0.0f};

    const short* ap = A + (size_t)(rowBase + sr) * DIN + sq * 32;
    const short* wp = W + (size_t)(colBase + sr) * DIN + sq * 32;
    short* asd = &As[sr * KP + sq * 32];
    short* wsd = &Ws[sr * KP + sq * 32];

    #pragma unroll
    for (int kt = 0; kt < DIN / 128; kt++) {
        s16x8 av[4], wv[4];
        #pragma unroll
        for (int i = 0; i < 4; i++) {
            av[i] = *(const s16x8*)(ap + kt * 128 + i * 8);
            wv[i] = *(const s16x8*)(wp + kt * 128 + i * 8);
        }
        if (kt) __syncthreads();
        #pragma unroll
        for (int i = 0; i < 4; i++) {
            *(s16x8*)(asd + i * 8) = av[i];
            *(s16x8*)(wsd + i * 8) = wv[i];
        }
        __syncthreads();
        #pragma unroll
        for (int kk = 0; kk < 4; kk++) {
            s16x8 af[4], bfr[2];
            #pragma unroll
            for (int qi = 0; qi < 4; qi++)
                af[qi] = *(const s16x8*)&As[(wr * 64 + qi * 16 + lr) * KP + kk * 32 + lg * 8];
            #pragma unroll
            for (int nj = 0; nj < 2; nj++)
                bfr[nj] = *(const s16x8*)&Ws[(wc * 32 + nj * 16 + lr) * KP + kk * 32 + lg * 8];
            #pragma unroll
            for (int qi = 0; qi < 4; qi++)
                #pragma unroll
                for (int nj = 0; nj < 2; nj++)
                    acc[qi][nj] = __builtin_amdgcn_mfma_f32_16x16x32_bf16(af[qi], bfr[nj], acc[qi][nj], 0, 0, 0);
        }
    }

    #pragma unroll
    for (int nj = 0; nj < 2; nj++) {
        int col = colBase + wc * 32 + nj * 16 + lr;
        float bb = bias[col];
        #pragma unroll
        for (int qi = 0; qi < 4; qi++) {
            #pragma unroll
            for (int rr = 0; rr < 4; rr++) {
                int row = rowBase + wr * 64 + qi * 16 + lg * 4 + rr;
                size_t o = (size_t)row * Dout + col;
                float v = acc[qi][nj][rr] + bb;
                if (res) v += res[o];
                if (relu) v = fmaxf(v, 0.0f);
                if (outb) outb[o] = f2bf(v);
                else      outf[o] = v;
            }
        }
    }
}

// ---------------- Context attention via banded MFMA (window L=16, d=128) ----------------
#define XSP 136   /* Xs row stride (bf16) */
#define XTP 84    /* Xt row stride (bf16) */
__global__ __launch_bounds__(256) void ctx_mfma_kernel(const short* __restrict__ in0, short* __restrict__ out0,
                                                       const short* __restrict__ in1, short* __restrict__ out1)
{
    __shared__ short Xs[80 * XSP];    // rows t0-16 .. t0+63, [pos][d]
    __shared__ short Xt[128 * XTP];   // [d][pos_rel]

    const short* in  = blockIdx.y ? in1 : in0;
    short*       out = blockIdx.y ? out1 : out0;
    int bm = blockIdx.x >> 3;
    int t0 = (blockIdx.x & 7) * 64;
    int tid = threadIdx.x;
    const short* base = in + (size_t)bm * T * D;

    #pragma unroll
    for (int it = 0; it < 5; it++) {
        int idx = it * 256 + tid;
        int row = idx >> 4, c16 = idx & 15;
        int t = t0 - 16 + row;
        s16x8 v = {0, 0, 0, 0, 0, 0, 0, 0};
        if (t >= 0) v = *(const s16x8*)(base + (size_t)t * D + c16 * 8);
        *(s16x8*)&Xs[row * XSP + c16 * 8] = v;
    }
    __syncthreads();
    #pragma unroll
    for (int it = 0; it < 5; it++) {
        int task = it * 256 + tid;
        int g = task / 80, row = task % 80;
        s16x8 v = *(const s16x8*)&Xs[row * XSP + g * 8];
        #pragma unroll
        for (int j = 0; j < 8; j++) Xt[(g * 8 + j) * XTP + row] = v[j];
    }
    __syncthreads();

    int w = tid >> 6, l = tid & 63;
    int lg = l >> 4, lr = l & 15;
    f32x4 zacc = {0.0f, 0.0f, 0.0f, 0.0f};
    const float C1 = 0.0883883476483184f * 1.4426950408889634f;   // (1/sqrt(128))*log2e

    s16x8 qf[4];
    #pragma unroll
    for (int kd = 0; kd < 4; kd++)
        qf[kd] = *(const s16x8*)&Xs[(16 + w * 16 + lr) * XSP + kd * 32 + lg * 8];

    f32x4 sacc[2];
    #pragma unroll
    for (int s = 0; s < 2; s++) {
        f32x4 a = zacc;
        #pragma unroll
        for (int kd = 0; kd < 4; kd++) {
            s16x8 kf = *(const s16x8*)&Xs[(w * 16 + s * 16 + lr) * XSP + kd * 32 + lg * 8];
            a = __builtin_amdgcn_mfma_f32_16x16x32_bf16(kf, qf[kd], a, 0, 0, 0);
        }
        sacc[s] = a;
    }

    float p[2][4];
    float mx = -1e30f;
    #pragma unroll
    for (int s = 0; s < 2; s++)
        #pragma unroll
        for (int r = 0; r < 4; r++) {
            int dlt = s * 16 + lg * 4 + r - 16 - lr;   // k - q
            float val = (dlt >= -15 && dlt <= 0) ? sacc[s][r] : -1e30f;
            p[s][r] = val;
            mx = fmaxf(mx, val);
        }
    mx = fmaxf(mx, __shfl_xor(mx, 16));
    mx = fmaxf(mx, __shfl_xor(mx, 32));
    float mc = mx * C1;
    float ps = 0.0f;
    #pragma unroll
    for (int s = 0; s < 2; s++)
        #pragma unroll
        for (int r = 0; r < 4; r++) {
            float e = exp2f(fmaf(p[s][r], C1, -mc));
            p[s][r] = e;
            ps += e;
        }
    ps += __shfl_xor(ps, 16);
    ps += __shfl_xor(ps, 32);

    union { unsigned u[4]; s16x8 v8; } pu;
    pu.u[0] = pkbf(p[0][0], p[0][1]);
    pu.u[1] = pkbf(p[0][2], p[0][3]);
    pu.u[2] = pkbf(p[1][0], p[1][1]);
    pu.u[3] = pkbf(p[1][2], p[1][3]);
    s16x8 pf = pu.v8;

    float rl = 1.0f / ps;
    short* op = out + (size_t)(bm * T + t0 + w * 16 + lr) * D;
    #pragma unroll
    for (int dt = 0; dt < 8; dt++) {
        const short* vb = &Xt[(dt * 16 + lr) * XTP + w * 16 + lg * 4];
        s16x4 a = *(const s16x4*)(vb);
        s16x4 b = *(const s16x4*)(vb + 16);
        s16x8 vf = __builtin_shufflevector(a, b, 0, 1, 2, 3, 4, 5, 6, 7);
        f32x4 Oa = __builtin_amdgcn_mfma_f32_16x16x32_bf16(vf, pf, zacc, 0, 0, 0);
        union { unsigned u[2]; ushort4 s4; } ou;
        ou.u[0] = pkbf(Oa[0] * rl, Oa[1] * rl);
        ou.u[1] = pkbf(Oa[2] * rl, Oa[3] * rl);
        *(ushort4*)(op + dt * 16 + lg * 4) = ou.s4;
    }
}

// ---------------- Full attention per (b,m,h): fixed-max swapped-layout bf16 MFMA flash ----------------
// Softmax is shift-invariant; scores are O(10), so exp without max subtraction is exact
// within fp32 range -> no max tree, no rescale, no serial chains.
#define KPAD 40
#define VTP  520
__global__ __launch_bounds__(512, 2) void attn_mfma_kernel(const short* __restrict__ q, const short* __restrict__ k,
                                                           const short* __restrict__ v, short* __restrict__ out)
{
    __shared__ short Ks[512 * KPAD];   // 40960 B
    __shared__ short Vt[32 * VTP];     // 33280 B

    int h  = blockIdx.x & 3;
    int bm = blockIdx.x >> 2;
    int tid = threadIdx.x;
    size_t headoff = (size_t)(bm * T) * D + h * DK;

    {
        int row = tid;
        const s16x8* krow = (const s16x8*)(k + headoff + (size_t)row * D);
        s16x8 k0 = krow[0], k1 = krow[1], k2 = krow[2], k3 = krow[3];
        short* kd = &Ks[row * KPAD];
        *(s16x8*)(kd)      = k0;
        *(s16x8*)(kd + 8)  = k1;
        *(s16x8*)(kd + 16) = k2;
        *(s16x8*)(kd + 24) = k3;
        const s16x8* vrow = (const s16x8*)(v + headoff + (size_t)row * D);
        s16x8 v0 = vrow[0], v1 = vrow[1], v2 = vrow[2], v3 = vrow[3];
        #pragma unroll
        for (int d = 0; d < 8; d++) {
            Vt[(d)      * VTP + row] = v0[d];
            Vt[(d + 8)  * VTP + row] = v1[d];
            Vt[(d + 16) * VTP + row] = v2[d];
            Vt[(d + 24) * VTP + row] = v3[d];
        }
    }
    __syncthreads();

    int w = tid >> 6, l = tid & 63;
    int lg = l >> 4, lr = l & 15;
    int qw = w * 64;

    s16x8 qf[4];
    #pragma unroll
    for (int qi = 0; qi < 4; qi++)
        qf[qi] = *(const s16x8*)(q + headoff + (size_t)(qw + qi * 16 + lr) * D + lg * 8);

    f32x4 Oa[4][2];
    float lrow[4];
    #pragma unroll
    for (int qi = 0; qi < 4; qi++) {
        lrow[qi] = 0.0f;
        #pragma unroll
        for (int r = 0; r < 4; r++) { Oa[qi][0][r] = 0.0f; Oa[qi][1][r] = 0.0f; }
    }
    const float C1 = 0.17677669529663689f * 1.4426950408889634f;   // (1/sqrt(32))*log2e
    f32x4 zacc = {0.0f, 0.0f, 0.0f, 0.0f};

    for (int kt = 0; kt < 8; kt++) {
        int kb = kt * 64;
        s16x8 kf[2][2];
        #pragma unroll
        for (int s = 0; s < 2; s++)
            #pragma unroll
            for (int hh = 0; hh < 2; hh++)
                kf[s][hh] = *(const s16x8*)&Ks[(kb + s * 32 + hh * 16 + lr) * KPAD + lg * 8];
        s16x8 vf[2][2];
        #pragma unroll
        for (int dh = 0; dh < 2; dh++)
            #pragma unroll
            for (int s = 0; s < 2; s++) {
                const short* vb = &Vt[(dh * 16 + lr) * VTP + kb + s * 32 + lg * 4];
                s16x4 a = *(const s16x4*)(vb);
                s16x4 b = *(const s16x4*)(vb + 16);
                vf[dh][s] = __builtin_shufflevector(a, b, 0, 1, 2, 3, 4, 5, 6, 7);
            }
        #pragma unroll
        for (int qi = 0; qi < 4; qi++) {
            f32x4 sa[2][2];
            #pragma unroll
            for (int s = 0; s < 2; s++)
                #pragma unroll
                for (int hh = 0; hh < 2; hh++)
                    sa[s][hh] = __builtin_amdgcn_mfma_f32_16x16x32_bf16(kf[s][hh], qf[qi], zacc, 0, 0, 0);
            float p[2][8];
            float ps = 0.0f;
            #pragma unroll
            for (int s = 0; s < 2; s++)
                #pragma unroll
                for (int hh = 0; hh < 2; hh++)
                    #pragma unroll
                    for (int r = 0; r < 4; r++) {
                        float e = exp2f(sa[s][hh][r] * C1);
                        p[s][hh * 4 + r] = e;
                        ps += e;
                    }
            lrow[qi] += ps;
            s16x8 pf[2];
            #pragma unroll
            for (int s = 0; s < 2; s++) {
                union { unsigned u[4]; s16x8 v8; } pu;
                pu.u[0] = pkbf(p[s][0], p[s][1]);
                pu.u[1] = pkbf(p[s][2], p[s][3]);
                pu.u[2] = pkbf(p[s][4], p[s][5]);
                pu.u[3] = pkbf(p[s][6], p[s][7]);
                pf[s] = pu.v8;
            }
            #pragma unroll
            for (int dh = 0; dh < 2; dh++)
                #pragma unroll
                for (int s = 0; s < 2; s++)
                    Oa[qi][dh] = __builtin_amdgcn_mfma_f32_16x16x32_bf16(vf[dh][s], pf[s], Oa[qi][dh], 0, 0, 0);
        }
    }

    #pragma unroll
    for (int qi = 0; qi < 4; qi++) {
        float lv = lrow[qi];
        lv += __shfl_xor(lv, 16);
        lv += __shfl_xor(lv, 32);
        float rl = 1.0f / lv;
        int qrow = qw + qi * 16 + lr;
        short* op = out + headoff + (size_t)qrow * D;
        #pragma unroll
        for (int dh = 0; dh < 2; dh++) {
            union { unsigned u[2]; ushort4 s4; } ou;
            ou.u[0] = pkbf(Oa[qi][dh][0] * rl, Oa[qi][dh][1] * rl);
            ou.u[1] = pkbf(Oa[qi][dh][2] * rl, Oa[qi][dh][3] * rl);
            *(ushort4*)(op + dh * 16 + lg * 4) = ou.s4;
        }
    }
}

// ---------------- Cross-m attention per (b,t) via MFMA: 4 waves = 4 heads of 32x32 ----------------
#define CXP 136   /* Xs row stride */
#define CTP 36    /* Xt row stride */
__global__ __launch_bounds__(256) void crossm_mfma_kernel(const short* __restrict__ in, short* __restrict__ out)
{
    __shared__ short Xs[32 * CXP];    // [m][d]   8.5 KB
    __shared__ short Xt[128 * CTP];   // [d][m]   9 KB
    int b = blockIdx.x >> 9;
    int t = blockIdx.x & 511;
    int tid = threadIdx.x;

    #pragma unroll
    for (int it = 0; it < 2; it++) {
        int idx = it * 256 + tid;
        int m = idx >> 4, c16 = idx & 15;
        s16x8 v = *(const s16x8*)(in + (size_t)((b * M + m) * T + t) * D + c16 * 8);
        *(s16x8*)&Xs[m * CXP + c16 * 8] = v;
    }
    __syncthreads();
    #pragma unroll
    for (int it = 0; it < 2; it++) {
        int task = it * 256 + tid;
        int g = task >> 5, m = task & 31;
        s16x8 v = *(const s16x8*)&Xs[m * CXP + g * 8];
        #pragma unroll
        for (int j = 0; j < 8; j++) Xt[(g * 8 + j) * CTP + m] = v[j];
    }
    __syncthreads();

    int h = tid >> 6, l = tid & 63;
    int lg = l >> 4, lr = l & 15;
    f32x4 zacc = {0.0f, 0.0f, 0.0f, 0.0f};
    const float C1 = 0.17677669529663689f * 1.4426950408889634f;   // (1/sqrt(32))*log2e

    // X fragments (Q = K = same rows): lane holds X[m = i*16+lr][h*32 + lg*8 + j]
    s16x8 xf[2];
    #pragma unroll
    for (int i = 0; i < 2; i++)
        xf[i] = *(const s16x8*)&Xs[(i * 16 + lr) * CXP + h * 32 + lg * 8];

    // S^T tiles: sacc[kt][qt], lane holds k = kt*16+lg*4+r, q = qt*16+lr
    f32x4 sacc[2][2];
    #pragma unroll
    for (int kt = 0; kt < 2; kt++)
        #pragma unroll
        for (int qt = 0; qt < 2; qt++)
            sacc[kt][qt] = __builtin_amdgcn_mfma_f32_16x16x32_bf16(xf[kt], xf[qt], zacc, 0, 0, 0);

    s16x8 pf[2];
    float rl[2];
    #pragma unroll
    for (int qt = 0; qt < 2; qt++) {
        float p[2][4];
        float ps = 0.0f;
        #pragma unroll
        for (int kt = 0; kt < 2; kt++)
            #pragma unroll
            for (int r = 0; r < 4; r++) {
                float e = exp2f(sacc[kt][qt][r] * C1);
                p[kt][r] = e;
                ps += e;
            }
        ps += __shfl_xor(ps, 16);
        ps += __shfl_xor(ps, 32);
        rl[qt] = 1.0f / ps;
        union { unsigned u[4]; s16x8 v8; } pu;
        pu.u[0] = pkbf(p[0][0], p[0][1]);
        pu.u[1] = pkbf(p[0][2], p[0][3]);
        pu.u[2] = pkbf(p[1][0], p[1][1]);
        pu.u[3] = pkbf(p[1][2], p[1][3]);
        pf[qt] = pu.v8;
    }

    // O^T = X^T . P^T : per qt, 2 d-tiles of 16 within this head's 32 dims
    #pragma unroll
    for (int qt = 0; qt < 2; qt++) {
        int qm = qt * 16 + lr;
        short* op = out + (size_t)((b * M + qm) * T + t) * D + h * 32;
        #pragma unroll
        for (int dt = 0; dt < 2; dt++) {
            const short* vb = &Xt[(h * 32 + dt * 16 + lr) * CTP + lg * 4];
            s16x4 a = *(const s16x4*)(vb);
            s16x4 bb = *(const s16x4*)(vb + 16);
            s16x8 vf = __builtin_shufflevector(a, bb, 0, 1, 2, 3, 4, 5, 6, 7);
            f32x4 Oa = __builtin_amdgcn_mfma_f32_16x16x32_bf16(vf, pf[qt], zacc, 0, 0, 0);
            union { unsigned u[2]; ushort4 s4; } ou;
            ou.u[0] = pkbf(Oa[0] * rl[qt], Oa[1] * rl[qt]);
            ou.u[1] = pkbf(Oa[2] * rl[qt], Oa[3] * rl[qt]);
            *(ushort4*)(op + dt * 16 + lg * 4) = ou.s4;
        }
    }
}

// ---------------- launch ----------------
extern "C" void kernel_launch(void* const* d_in, const int* in_sizes, int n_in,
                              void* d_out, int out_size, void* d_ws, size_t ws_size,
                              hipStream_t stream)
{
    (void)in_sizes; (void)n_in; (void)out_size; (void)ws_size;
    const float* xin = (const float*)d_in[0];
    const float* Wq  = (const float*)d_in[1];
    const float* bq  = (const float*)d_in[2];
    const float* Wk  = (const float*)d_in[3];
    const float* bk  = (const float*)d_in[4];
    const float* Wv  = (const float*)d_in[5];
    const float* bv  = (const float*)d_in[6];
    const float* Wfc = (const float*)d_in[7];
    const float* bfc = (const float*)d_in[8];
    const float* W1  = (const float*)d_in[9];
    const float* b1  = (const float*)d_in[10];
    const float* W2  = (const float*)d_in[11];
    const float* b2  = (const float*)d_in[12];
    const float* g1  = (const float*)d_in[13];
    const float* be1 = (const float*)d_in[14];
    const float* g2  = (const float*)d_in[15];
    const float* be2 = (const float*)d_in[16];
    const float* gf  = (const float*)d_in[17];
    const float* bef = (const float*)d_in[18];

    float* X = (float*)d_out;
    char* wsb = (char*)d_ws;
    const size_t SEGB = (size_t)NTOK * D * sizeof(float);
    const size_t SEGH = SEGB / 2;
    short* Ybf = (short*)(wsb);
    short* Qpb = (short*)(wsb + SEGH);
    short* Kpb = (short*)(wsb + 2 * SEGH);
    short* Vbf = (short*)(wsb + 3 * SEGH);
    short* CQb = (short*)(wsb + 4 * SEGH);
    short* CKb = (short*)(wsb + 5 * SEGH);
    short* Hbf = Qpb;

    size_t woff = 6 * SEGH;
    short* Wqb  = (short*)(wsb + woff); woff += (size_t)2 * D * D * 2;
    short* Wkb  = (short*)(wsb + woff); woff += (size_t)2 * D * D * 2;
    short* Wvb  = (short*)(wsb + woff); woff += (size_t)2 * D * D * 2;
    short* Wfcb = (short*)(wsb + woff); woff += (size_t)2 * D * D * 2;
    short* W1b  = (short*)(wsb + woff); woff += (size_t)2 * 4 * D * D * 2;
    short* W2b  = (short*)(wsb + woff);

    hipMemcpyAsync(X, xin, SEGB, hipMemcpyDeviceToDevice, stream);

    cvt_kernel<<<(2 * D * D) / 1024, 256, 0, stream>>>(Wq,  Wqb,  2 * D * D);
    cvt_kernel<<<(2 * D * D) / 1024, 256, 0, stream>>>(Wk,  Wkb,  2 * D * D);
    cvt_kernel<<<(2 * D * D) / 1024, 256, 0, stream>>>(Wv,  Wvb,  2 * D * D);
    cvt_kernel<<<(2 * D * D) / 1024, 256, 0, stream>>>(Wfc, Wfcb, 2 * D * D);
    cvt_kernel<<<(2 * 4 * D * D) / 1024, 256, 0, stream>>>(W1, W1b, 2 * 4 * D * D);
    cvt_kernel<<<(2 * 4 * D * D) / 1024, 256, 0, stream>>>(W2, W2b, 2 * 4 * D * D);

    for (int i = 0; i < 2; i++) {
        ln_kernel<<<NTOK / 4, 256, 0, stream>>>(X, nullptr, Ybf, g1 + i * D, be1 + i * D);
        gemm_bf16_kernel<128><<<dim3(1, NTOK / 128), 512, 0, stream>>>(Ybf, Wqb + i * D * D, bq + i * D, nullptr, nullptr, Qpb, D, 0);
        gemm_bf16_kernel<128><<<dim3(1, NTOK / 128), 512, 0, stream>>>(Ybf, Wkb + i * D * D, bk + i * D, nullptr, nullptr, Kpb, D, 0);
        gemm_bf16_kernel<128><<<dim3(1, NTOK / 128), 512, 0, stream>>>(Ybf, Wvb + i * D * D, bv + i * D, nullptr, nullptr, Vbf, D, 0);
        ctx_mfma_kernel<<<dim3(B * M * (T / 64), 2), 256, 0, stream>>>(Qpb, CQb, Kpb, CKb);
        attn_mfma_kernel<<<B * M * H, 512, 0, stream>>>(CQb, CKb, Vbf, Qpb);
        crossm_mfma_kernel<<<B * T, 256, 0, stream>>>(Qpb, Kpb);
        gemm_bf16_kernel<128><<<dim3(1, NTOK / 128), 512, 0, stream>>>(Kpb, Wfcb + i * D * D, bfc + i * D, X, X, nullptr, D, 0);
        ln_kernel<<<NTOK / 4, 256, 0, stream>>>(X, nullptr, Ybf, g2 + i * D, be2 + i * D);
        gemm_bf16_kernel<128><<<dim3(4, NTOK / 128), 512, 0, stream>>>(Ybf, W1b + i * 4 * D * D, b1 + i * 4 * D, nullptr, nullptr, Hbf, 4 * D, 1);
        gemm_bf16_kernel<512><<<dim3(1, NTOK / 128), 512, 0, stream>>>(Hbf, W2b + i * 4 * D * D, b2 + i * D, X, X, nullptr, D, 0);
    }
    ln_kernel<<<NTOK / 4, 256, 0, stream>>>(X, X, nullptr, gf, bef);
}

// Round 8
// 236.072 us; speedup vs baseline: 6.6339x; 1.2389x over previous
//
#include <hip/hip_runtime.h>
#include <hip/hip_bf16.h>
#include <math.h>

#define B 2
#define M 32
#define T 512
#define D 128
#define H 4
#define DK 32
#define NTOK (B*M*T)   /* 32768 rows */

using s16x8 = __attribute__((ext_vector_type(8))) short;
using s16x4 = __attribute__((ext_vector_type(4))) short;
using f32x4 = __attribute__((ext_vector_type(4))) float;

__device__ __forceinline__ short f2bf(float x) {
    union { float f; unsigned u; } a; a.f = x;
    unsigned r = a.u + 0x7fffu + ((a.u >> 16) & 1u);   // RNE
    return (short)(r >> 16);
}
__device__ __forceinline__ unsigned pkbf(float lo, float hi) {
    union { __hip_bfloat162 h; unsigned u; } c;
    c.h = __float22bfloat162_rn(float2{lo, hi});
    return c.u;
}

// ---------------- all weights fp32 -> bf16 in one dispatch ----------------
// dst layout: Wq[0,32768) Wk[32768,65536) Wv[65536,98304) Wfc[98304,131072)
//             W1[131072,262144) W2[262144,393216)
__global__ __launch_bounds__(256) void cvt_all_kernel(const float* __restrict__ Wq, const float* __restrict__ Wk,
                                                      const float* __restrict__ Wv, const float* __restrict__ Wfc,
                                                      const float* __restrict__ W1, const float* __restrict__ W2,
                                                      short* __restrict__ dst)
{
    int i = (blockIdx.x * 256 + threadIdx.x) * 4;
    if (i >= 393216) return;
    const float* src; int off;
    if (i < 131072) {
        int wsel = i >> 15; off = i & 32767;
        src = (wsel == 0) ? Wq : (wsel == 1) ? Wk : (wsel == 2) ? Wv : Wfc;
    } else if (i < 262144) { src = W1; off = i - 131072; }
    else                   { src = W2; off = i - 262144; }
    float4 v = *(const float4*)(src + off);
    ushort4 u;
    u.x = (unsigned short)f2bf(v.x); u.y = (unsigned short)f2bf(v.y);
    u.z = (unsigned short)f2bf(v.z); u.w = (unsigned short)f2bf(v.w);
    *(ushort4*)(dst + i) = u;
}

// ---------------- LayerNorm (final only): one wave per row of 128, fp32 out ----------------
__global__ __launch_bounds__(256) void ln_kernel(const float* __restrict__ in, float* __restrict__ outf,
                                                 const float* __restrict__ g, const float* __restrict__ b)
{
    int wave = threadIdx.x >> 6;
    int lane = threadIdx.x & 63;
    int row  = blockIdx.x * 4 + wave;
    const float* rp = in + (size_t)row * D;
    float v0 = rp[lane], v1 = rp[lane + 64];
    float s = v0 + v1, ss = v0 * v0 + v1 * v1;
    #pragma unroll
    for (int off = 32; off; off >>= 1) { s += __shfl_xor(s, off); ss += __shfl_xor(ss, off); }
    float mu  = s * (1.0f / 128.0f);
    float var = ss * (1.0f / 128.0f) - mu * mu;
    float rs  = rsqrtf(var + 1e-6f);
    float* op = outf + (size_t)row * D;
    op[lane]      = (v0 - mu) * rs * g[lane]      + b[lane];
    op[lane + 64] = (v1 - mu) * rs * g[lane + 64] + b[lane + 64];
}

#define KP 136

// LN staging helper: computes LN of row (rowBase+sr), cols sq*32..+31, writes bf16 into As.
#define LN_STAGE(XPTR, GPTR, BEPTR)                                              \
    {                                                                            \
        const float* xp = (XPTR) + (size_t)(rowBase + sr) * D + sq * 32;         \
        float4 xv[8];                                                            \
        _Pragma("unroll")                                                        \
        for (int j = 0; j < 8; j++) xv[j] = *(const float4*)(xp + j * 4);        \
        float s = 0.0f, ss = 0.0f;                                               \
        _Pragma("unroll")                                                        \
        for (int j = 0; j < 8; j++) {                                            \
            s  += xv[j].x + xv[j].y + xv[j].z + xv[j].w;                         \
            ss += xv[j].x*xv[j].x + xv[j].y*xv[j].y + xv[j].z*xv[j].z + xv[j].w*xv[j].w; \
        }                                                                        \
        s  += __shfl_xor(s, 1);  s  += __shfl_xor(s, 2);                         \
        ss += __shfl_xor(ss, 1); ss += __shfl_xor(ss, 2);                        \
        float mu  = s * (1.0f / 128.0f);                                         \
        float var = ss * (1.0f / 128.0f) - mu * mu;                              \
        float rs  = rsqrtf(var + 1e-6f);                                         \
        const float* gp  = (GPTR) + sq * 32;                                     \
        const float* bep = (BEPTR) + sq * 32;                                    \
        short* asd = &As[sr * KP + sq * 32];                                     \
        _Pragma("unroll")                                                        \
        for (int c = 0; c < 4; c++) {                                            \
            float4 a0 = xv[2*c], a1 = xv[2*c+1];                                 \
            float4 g0 = *(const float4*)(gp + c * 8);                            \
            float4 g1 = *(const float4*)(gp + c * 8 + 4);                        \
            float4 b0 = *(const float4*)(bep + c * 8);                           \
            float4 b1 = *(const float4*)(bep + c * 8 + 4);                       \
            union { unsigned u[4]; s16x8 v8; } pu;                               \
            pu.u[0] = pkbf((a0.x-mu)*rs*g0.x+b0.x, (a0.y-mu)*rs*g0.y+b0.y);      \
            pu.u[1] = pkbf((a0.z-mu)*rs*g0.z+b0.z, (a0.w-mu)*rs*g0.w+b0.w);      \
            pu.u[2] = pkbf((a1.x-mu)*rs*g1.x+b1.x, (a1.y-mu)*rs*g1.y+b1.y);      \
            pu.u[3] = pkbf((a1.z-mu)*rs*g1.z+b1.z, (a1.w-mu)*rs*g1.w+b1.w);      \
            *(s16x8*)(asd + c * 8) = pu.v8;                                      \
        }                                                                        \
    }

// ---------------- Fused LN + Q/K/V projections: A tile staged once ----------------
__global__ __launch_bounds__(512) void qkv_ln_kernel(const float* __restrict__ X,
                                                     const float* __restrict__ g, const float* __restrict__ be,
                                                     const short* __restrict__ Wq, const short* __restrict__ Wk,
                                                     const short* __restrict__ Wv,
                                                     const float* __restrict__ bq, const float* __restrict__ bk,
                                                     const float* __restrict__ bv,
                                                     short* __restrict__ Qo, short* __restrict__ Ko,
                                                     short* __restrict__ Vo)
{
    __shared__ short As[128 * KP];
    __shared__ short Ws[128 * KP];
    const int tid = threadIdx.x;
    const int rowBase = blockIdx.x * 128;
    const int sr = tid >> 2, sq = tid & 3;
    const int w = tid >> 6, l = tid & 63;
    const int lg = l >> 4, lr = l & 15;
    const int wr = w >> 2, wc = w & 3;

    LN_STAGE(X, g, be)

    const short* wsrc[3] = { Wq, Wk, Wv };
    const float* bsrc[3] = { bq, bk, bv };
    short*       osrc[3] = { Qo, Ko, Vo };

    for (int gsel = 0; gsel < 3; gsel++) {
        s16x8 wv4[4];
        const short* wp = wsrc[gsel] + (size_t)sr * D + sq * 32;
        #pragma unroll
        for (int i = 0; i < 4; i++) wv4[i] = *(const s16x8*)(wp + i * 8);
        __syncthreads();                         // prev readers of Ws done (also A visible on gsel=0)
        short* wsd = &Ws[sr * KP + sq * 32];
        #pragma unroll
        for (int i = 0; i < 4; i++) *(s16x8*)(wsd + i * 8) = wv4[i];
        __syncthreads();

        f32x4 acc[4][2];
        #pragma unroll
        for (int qi = 0; qi < 4; qi++)
            #pragma unroll
            for (int nj = 0; nj < 2; nj++)
                acc[qi][nj] = (f32x4){0.0f, 0.0f, 0.0f, 0.0f};
        #pragma unroll
        for (int kk = 0; kk < 4; kk++) {
            s16x8 af[4], bfr[2];
            #pragma unroll
            for (int qi = 0; qi < 4; qi++)
                af[qi] = *(const s16x8*)&As[(wr * 64 + qi * 16 + lr) * KP + kk * 32 + lg * 8];
            #pragma unroll
            for (int nj = 0; nj < 2; nj++)
                bfr[nj] = *(const s16x8*)&Ws[(wc * 32 + nj * 16 + lr) * KP + kk * 32 + lg * 8];
            #pragma unroll
            for (int qi = 0; qi < 4; qi++)
                #pragma unroll
                for (int nj = 0; nj < 2; nj++)
                    acc[qi][nj] = __builtin_amdgcn_mfma_f32_16x16x32_bf16(af[qi], bfr[nj], acc[qi][nj], 0, 0, 0);
        }
        #pragma unroll
        for (int nj = 0; nj < 2; nj++) {
            int col = wc * 32 + nj * 16 + lr;
            float bb = bsrc[gsel][col];
            #pragma unroll
            for (int qi = 0; qi < 4; qi++) {
                #pragma unroll
                for (int rr = 0; rr < 4; rr++) {
                    int row = rowBase + wr * 64 + qi * 16 + lg * 4 + rr;
                    osrc[gsel][(size_t)row * D + col] = f2bf(acc[qi][nj][rr] + bb);
                }
            }
        }
    }
}

// ---------------- Fused LN + MLP-W1 (relu), Dout=512 via internal col loop ----------------
__global__ __launch_bounds__(512) void mlp1_ln_kernel(const float* __restrict__ X,
                                                      const float* __restrict__ g, const float* __restrict__ be,
                                                      const short* __restrict__ W1, const float* __restrict__ b1,
                                                      short* __restrict__ Hb)
{
    __shared__ short As[128 * KP];
    __shared__ short Ws[128 * KP];
    const int tid = threadIdx.x;
    const int rowBase = blockIdx.x * 128;
    const int sr = tid >> 2, sq = tid & 3;
    const int w = tid >> 6, l = tid & 63;
    const int lg = l >> 4, lr = l & 15;
    const int wr = w >> 2, wc = w & 3;

    LN_STAGE(X, g, be)

    for (int ct = 0; ct < 4; ct++) {
        s16x8 wv4[4];
        const short* wp = W1 + (size_t)(ct * 128 + sr) * D + sq * 32;
        #pragma unroll
        for (int i = 0; i < 4; i++) wv4[i] = *(const s16x8*)(wp + i * 8);
        __syncthreads();
        short* wsd = &Ws[sr * KP + sq * 32];
        #pragma unroll
        for (int i = 0; i < 4; i++) *(s16x8*)(wsd + i * 8) = wv4[i];
        __syncthreads();

        f32x4 acc[4][2];
        #pragma unroll
        for (int qi = 0; qi < 4; qi++)
            #pragma unroll
            for (int nj = 0; nj < 2; nj++)
                acc[qi][nj] = (f32x4){0.0f, 0.0f, 0.0f, 0.0f};
        #pragma unroll
        for (int kk = 0; kk < 4; kk++) {
            s16x8 af[4], bfr[2];
            #pragma unroll
            for (int qi = 0; qi < 4; qi++)
                af[qi] = *(const s16x8*)&As[(wr * 64 + qi * 16 + lr) * KP + kk * 32 + lg * 8];
            #pragma unroll
            for (int nj = 0; nj < 2; nj++)
                bfr[nj] = *(const s16x8*)&Ws[(wc * 32 + nj * 16 + lr) * KP + kk * 32 + lg * 8];
            #pragma unroll
            for (int qi = 0; qi < 4; qi++)
                #pragma unroll
                for (int nj = 0; nj < 2; nj++)
                    acc[qi][nj] = __builtin_amdgcn_mfma_f32_16x16x32_bf16(af[qi], bfr[nj], acc[qi][nj], 0, 0, 0);
        }
        #pragma unroll
        for (int nj = 0; nj < 2; nj++) {
            int col = ct * 128 + wc * 32 + nj * 16 + lr;
            float bb = b1[col];
            #pragma unroll
            for (int qi = 0; qi < 4; qi++) {
                #pragma unroll
                for (int rr = 0; rr < 4; rr++) {
                    int row = rowBase + wr * 64 + qi * 16 + lg * 4 + rr;
                    Hb[(size_t)row * 512 + col] = f2bf(fmaxf(acc[qi][nj][rr] + bb, 0.0f));
                }
            }
        }
    }
}

// ---------------- bf16 MFMA GEMM (FC and MLP-W2): out = A . W^T + bias + res ----------------
template<int DIN>
__global__ __launch_bounds__(512) void gemm_bf16_kernel(const short* __restrict__ A, const short* __restrict__ W,
                                                        const float* __restrict__ bias, const float* __restrict__ res,
                                                        float* __restrict__ outf, int Dout)
{
    __shared__ short As[128 * KP];
    __shared__ short Ws[128 * KP];
    const int tid = threadIdx.x;
    const int rowBase = blockIdx.y * 128;
    const int colBase = blockIdx.x * 128;
    const int sr = tid >> 2, sq = tid & 3;
    const int w = tid >> 6, l = tid & 63;
    const int lg = l >> 4, lr = l & 15;
    const int wr = w >> 2, wc = w & 3;

    f32x4 acc[4][2];
    #pragma unroll
    for (int qi = 0; qi < 4; qi++)
        #pragma unroll
        for (int nj = 0; nj < 2; nj++)
            acc[qi][nj] = (f32x4){0.0f, 0.0f, 0.0f, 0.0f};

    const short* ap = A + (size_t)(rowBase + sr) * DIN + sq * 32;
    const short* wp = W + (size_t)(colBase + sr) * DIN + sq * 32;
    short* asd = &As[sr * KP + sq * 32];
    short* wsd = &Ws[sr * KP + sq * 32];

    #pragma unroll
    for (int kt = 0; kt < DIN / 128; kt++) {
        s16x8 av[4], wv[4];
        #pragma unroll
        for (int i = 0; i < 4; i++) {
            av[i] = *(const s16x8*)(ap + kt * 128 + i * 8);
            wv[i] = *(const s16x8*)(wp + kt * 128 + i * 8);
        }
        if (kt) __syncthreads();
        #pragma unroll
        for (int i = 0; i < 4; i++) {
            *(s16x8*)(asd + i * 8) = av[i];
            *(s16x8*)(wsd + i * 8) = wv[i];
        }
        __syncthreads();
        #pragma unroll
        for (int kk = 0; kk < 4; kk++) {
            s16x8 af[4], bfr[2];
            #pragma unroll
            for (int qi = 0; qi < 4; qi++)
                af[qi] = *(const s16x8*)&As[(wr * 64 + qi * 16 + lr) * KP + kk * 32 + lg * 8];
            #pragma unroll
            for (int nj = 0; nj < 2; nj++)
                bfr[nj] = *(const s16x8*)&Ws[(wc * 32 + nj * 16 + lr) * KP + kk * 32 + lg * 8];
            #pragma unroll
            for (int qi = 0; qi < 4; qi++)
                #pragma unroll
                for (int nj = 0; nj < 2; nj++)
                    acc[qi][nj] = __builtin_amdgcn_mfma_f32_16x16x32_bf16(af[qi], bfr[nj], acc[qi][nj], 0, 0, 0);
        }
    }

    #pragma unroll
    for (int nj = 0; nj < 2; nj++) {
        int col = colBase + wc * 32 + nj * 16 + lr;
        float bb = bias[col];
        #pragma unroll
        for (int qi = 0; qi < 4; qi++) {
            #pragma unroll
            for (int rr = 0; rr < 4; rr++) {
                int row = rowBase + wr * 64 + qi * 16 + lg * 4 + rr;
                size_t o = (size_t)row * Dout + col;
                outf[o] = acc[qi][nj][rr] + bb + res[o];
            }
        }
    }
}

// ---------------- Context attention via banded MFMA (window L=16, d=128) ----------------
#define XSP 136
#define XTP 84
__global__ __launch_bounds__(256) void ctx_mfma_kernel(const short* __restrict__ in0, short* __restrict__ out0,
                                                       const short* __restrict__ in1, short* __restrict__ out1)
{
    __shared__ short Xs[80 * XSP];
    __shared__ short Xt[128 * XTP];

    const short* in  = blockIdx.y ? in1 : in0;
    short*       out = blockIdx.y ? out1 : out0;
    int bm = blockIdx.x >> 3;
    int t0 = (blockIdx.x & 7) * 64;
    int tid = threadIdx.x;
    const short* base = in + (size_t)bm * T * D;

    #pragma unroll
    for (int it = 0; it < 5; it++) {
        int idx = it * 256 + tid;
        int row = idx >> 4, c16 = idx & 15;
        int t = t0 - 16 + row;
        s16x8 v = {0, 0, 0, 0, 0, 0, 0, 0};
        if (t >= 0) v = *(const s16x8*)(base + (size_t)t * D + c16 * 8);
        *(s16x8*)&Xs[row * XSP + c16 * 8] = v;
    }
    __syncthreads();
    #pragma unroll
    for (int it = 0; it < 5; it++) {
        int task = it * 256 + tid;
        int g = task / 80, row = task % 80;
        s16x8 v = *(const s16x8*)&Xs[row * XSP + g * 8];
        #pragma unroll
        for (int j = 0; j < 8; j++) Xt[(g * 8 + j) * XTP + row] = v[j];
    }
    __syncthreads();

    int w = tid >> 6, l = tid & 63;
    int lg = l >> 4, lr = l & 15;
    f32x4 zacc = {0.0f, 0.0f, 0.0f, 0.0f};
    const float C1 = 0.0883883476483184f * 1.4426950408889634f;   // (1/sqrt(128))*log2e

    s16x8 qf[4];
    #pragma unroll
    for (int kd = 0; kd < 4; kd++)
        qf[kd] = *(const s16x8*)&Xs[(16 + w * 16 + lr) * XSP + kd * 32 + lg * 8];

    f32x4 sacc[2];
    #pragma unroll
    for (int s = 0; s < 2; s++) {
        f32x4 a = zacc;
        #pragma unroll
        for (int kd = 0; kd < 4; kd++) {
            s16x8 kf = *(const s16x8*)&Xs[(w * 16 + s * 16 + lr) * XSP + kd * 32 + lg * 8];
            a = __builtin_amdgcn_mfma_f32_16x16x32_bf16(kf, qf[kd], a, 0, 0, 0);
        }
        sacc[s] = a;
    }

    float p[2][4];
    float mx = -1e30f;
    #pragma unroll
    for (int s = 0; s < 2; s++)
        #pragma unroll
        for (int r = 0; r < 4; r++) {
            int dlt = s * 16 + lg * 4 + r - 16 - lr;   // k - q
            float val = (dlt >= -15 && dlt <= 0) ? sacc[s][r] : -1e30f;
            p[s][r] = val;
            mx = fmaxf(mx, val);
        }
    mx = fmaxf(mx, __shfl_xor(mx, 16));
    mx = fmaxf(mx, __shfl_xor(mx, 32));
    float mc = mx * C1;
    float ps = 0.0f;
    #pragma unroll
    for (int s = 0; s < 2; s++)
        #pragma unroll
        for (int r = 0; r < 4; r++) {
            float e = exp2f(fmaf(p[s][r], C1, -mc));
            p[s][r] = e;
            ps += e;
        }
    ps += __shfl_xor(ps, 16);
    ps += __shfl_xor(ps, 32);

    union { unsigned u[4]; s16x8 v8; } pu;
    pu.u[0] = pkbf(p[0][0], p[0][1]);
    pu.u[1] = pkbf(p[0][2], p[0][3]);
    pu.u[2] = pkbf(p[1][0], p[1][1]);
    pu.u[3] = pkbf(p[1][2], p[1][3]);
    s16x8 pf = pu.v8;

    float rl = 1.0f / ps;
    short* op = out + (size_t)(bm * T + t0 + w * 16 + lr) * D;
    #pragma unroll
    for (int dt = 0; dt < 8; dt++) {
        const short* vb = &Xt[(dt * 16 + lr) * XTP + w * 16 + lg * 4];
        s16x4 a = *(const s16x4*)(vb);
        s16x4 b = *(const s16x4*)(vb + 16);
        s16x8 vf = __builtin_shufflevector(a, b, 0, 1, 2, 3, 4, 5, 6, 7);
        f32x4 Oa = __builtin_amdgcn_mfma_f32_16x16x32_bf16(vf, pf, zacc, 0, 0, 0);
        union { unsigned u[2]; ushort4 s4; } ou;
        ou.u[0] = pkbf(Oa[0] * rl, Oa[1] * rl);
        ou.u[1] = pkbf(Oa[2] * rl, Oa[3] * rl);
        *(ushort4*)(op + dt * 16 + lg * 4) = ou.s4;
    }
}

// ---------------- Full attention per (b,m,h): fixed-max swapped-layout bf16 MFMA flash ----------------
#define KPAD 40
#define VTP  520
__global__ __launch_bounds__(512, 2) void attn_mfma_kernel(const short* __restrict__ q, const short* __restrict__ k,
                                                           const short* __restrict__ v, short* __restrict__ out)
{
    __shared__ short Ks[512 * KPAD];
    __shared__ short Vt[32 * VTP];

    int h  = blockIdx.x & 3;
    int bm = blockIdx.x >> 2;
    int tid = threadIdx.x;
    size_t headoff = (size_t)(bm * T) * D + h * DK;

    {
        int row = tid;
        const s16x8* krow = (const s16x8*)(k + headoff + (size_t)row * D);
        s16x8 k0 = krow[0], k1 = krow[1], k2 = krow[2], k3 = krow[3];
        short* kd = &Ks[row * KPAD];
        *(s16x8*)(kd)      = k0;
        *(s16x8*)(kd + 8)  = k1;
        *(s16x8*)(kd + 16) = k2;
        *(s16x8*)(kd + 24) = k3;
        const s16x8* vrow = (const s16x8*)(v + headoff + (size_t)row * D);
        s16x8 v0 = vrow[0], v1 = vrow[1], v2 = vrow[2], v3 = vrow[3];
        #pragma unroll
        for (int d = 0; d < 8; d++) {
            Vt[(d)      * VTP + row] = v0[d];
            Vt[(d + 8)  * VTP + row] = v1[d];
            Vt[(d + 16) * VTP + row] = v2[d];
            Vt[(d + 24) * VTP + row] = v3[d];
        }
    }
    __syncthreads();

    int w = tid >> 6, l = tid & 63;
    int lg = l >> 4, lr = l & 15;
    int qw = w * 64;

    s16x8 qf[4];
    #pragma unroll
    for (int qi = 0; qi < 4; qi++)
        qf[qi] = *(const s16x8*)(q + headoff + (size_t)(qw + qi * 16 + lr) * D + lg * 8);

    f32x4 Oa[4][2];
    float lrow[4];
    #pragma unroll
    for (int qi = 0; qi < 4; qi++) {
        lrow[qi] = 0.0f;
        #pragma unroll
        for (int r = 0; r < 4; r++) { Oa[qi][0][r] = 0.0f; Oa[qi][1][r] = 0.0f; }
    }
    const float C1 = 0.17677669529663689f * 1.4426950408889634f;   // (1/sqrt(32))*log2e
    f32x4 zacc = {0.0f, 0.0f, 0.0f, 0.0f};

    for (int kt = 0; kt < 8; kt++) {
        int kb = kt * 64;
        s16x8 kf[2][2];
        #pragma unroll
        for (int s = 0; s < 2; s++)
            #pragma unroll
            for (int hh = 0; hh < 2; hh++)
                kf[s][hh] = *(const s16x8*)&Ks[(kb + s * 32 + hh * 16 + lr) * KPAD + lg * 8];
        s16x8 vf[2][2];
        #pragma unroll
        for (int dh = 0; dh < 2; dh++)
            #pragma unroll
            for (int s = 0; s < 2; s++) {
                const short* vb = &Vt[(dh * 16 + lr) * VTP + kb + s * 32 + lg * 4];
                s16x4 a = *(const s16x4*)(vb);
                s16x4 b = *(const s16x4*)(vb + 16);
                vf[dh][s] = __builtin_shufflevector(a, b, 0, 1, 2, 3, 4, 5, 6, 7);
            }
        #pragma unroll
        for (int qi = 0; qi < 4; qi++) {
            f32x4 sa[2][2];
            #pragma unroll
            for (int s = 0; s < 2; s++)
                #pragma unroll
                for (int hh = 0; hh < 2; hh++)
                    sa[s][hh] = __builtin_amdgcn_mfma_f32_16x16x32_bf16(kf[s][hh], qf[qi], zacc, 0, 0, 0);
            float p[2][8];
            float ps = 0.0f;
            #pragma unroll
            for (int s = 0; s < 2; s++)
                #pragma unroll
                for (int hh = 0; hh < 2; hh++)
                    #pragma unroll
                    for (int r = 0; r < 4; r++) {
                        float e = exp2f(sa[s][hh][r] * C1);
                        p[s][hh * 4 + r] = e;
                        ps += e;
                    }
            lrow[qi] += ps;
            s16x8 pf[2];
            #pragma unroll
            for (int s = 0; s < 2; s++) {
                union { unsigned u[4]; s16x8 v8; } pu;
                pu.u[0] = pkbf(p[s][0], p[s][1]);
                pu.u[1] = pkbf(p[s][2], p[s][3]);
                pu.u[2] = pkbf(p[s][4], p[s][5]);
                pu.u[3] = pkbf(p[s][6], p[s][7]);
                pf[s] = pu.v8;
            }
            #pragma unroll
            for (int dh = 0; dh < 2; dh++)
                #pragma unroll
                for (int s = 0; s < 2; s++)
                    Oa[qi][dh] = __builtin_amdgcn_mfma_f32_16x16x32_bf16(vf[dh][s], pf[s], Oa[qi][dh], 0, 0, 0);
        }
    }

    #pragma unroll
    for (int qi = 0; qi < 4; qi++) {
        float lv = lrow[qi];
        lv += __shfl_xor(lv, 16);
        lv += __shfl_xor(lv, 32);
        float rl = 1.0f / lv;
        int qrow = qw + qi * 16 + lr;
        short* op = out + headoff + (size_t)qrow * D;
        #pragma unroll
        for (int dh = 0; dh < 2; dh++) {
            union { unsigned u[2]; ushort4 s4; } ou;
            ou.u[0] = pkbf(Oa[qi][dh][0] * rl, Oa[qi][dh][1] * rl);
            ou.u[1] = pkbf(Oa[qi][dh][2] * rl, Oa[qi][dh][3] * rl);
            *(ushort4*)(op + dh * 16 + lg * 4) = ou.s4;
        }
    }
}

// ---------------- Cross-m attention per (b,t) via MFMA: 4 waves = 4 heads of 32x32 ----------------
#define CXP 136
#define CTP 36
__global__ __launch_bounds__(256) void crossm_mfma_kernel(const short* __restrict__ in, short* __restrict__ out)
{
    __shared__ short Xs[32 * CXP];
    __shared__ short Xt[128 * CTP];
    int b = blockIdx.x >> 9;
    int t = blockIdx.x & 511;
    int tid = threadIdx.x;

    #pragma unroll
    for (int it = 0; it < 2; it++) {
        int idx = it * 256 + tid;
        int m = idx >> 4, c16 = idx & 15;
        s16x8 v = *(const s16x8*)(in + (size_t)((b * M + m) * T + t) * D + c16 * 8);
        *(s16x8*)&Xs[m * CXP + c16 * 8] = v;
    }
    __syncthreads();
    #pragma unroll
    for (int it = 0; it < 2; it++) {
        int task = it * 256 + tid;
        int g = task >> 5, m = task & 31;
        s16x8 v = *(const s16x8*)&Xs[m * CXP + g * 8];
        #pragma unroll
        for (int j = 0; j < 8; j++) Xt[(g * 8 + j) * CTP + m] = v[j];
    }
    __syncthreads();

    int h = tid >> 6, l = tid & 63;
    int lg = l >> 4, lr = l & 15;
    f32x4 zacc = {0.0f, 0.0f, 0.0f, 0.0f};
    const float C1 = 0.17677669529663689f * 1.4426950408889634f;

    s16x8 xf[2];
    #pragma unroll
    for (int i = 0; i < 2; i++)
        xf[i] = *(const s16x8*)&Xs[(i * 16 + lr) * CXP + h * 32 + lg * 8];

    f32x4 sacc[2][2];
    #pragma unroll
    for (int kt = 0; kt < 2; kt++)
        #pragma unroll
        for (int qt = 0; qt < 2; qt++)
            sacc[kt][qt] = __builtin_amdgcn_mfma_f32_16x16x32_bf16(xf[kt], xf[qt], zacc, 0, 0, 0);

    s16x8 pf[2];
    float rl[2];
    #pragma unroll
    for (int qt = 0; qt < 2; qt++) {
        float p[2][4];
        float ps = 0.0f;
        #pragma unroll
        for (int kt = 0; kt < 2; kt++)
            #pragma unroll
            for (int r = 0; r < 4; r++) {
                float e = exp2f(sacc[kt][qt][r] * C1);
                p[kt][r] = e;
                ps += e;
            }
        ps += __shfl_xor(ps, 16);
        ps += __shfl_xor(ps, 32);
        rl[qt] = 1.0f / ps;
        union { unsigned u[4]; s16x8 v8; } pu;
        pu.u[0] = pkbf(p[0][0], p[0][1]);
        pu.u[1] = pkbf(p[0][2], p[0][3]);
        pu.u[2] = pkbf(p[1][0], p[1][1]);
        pu.u[3] = pkbf(p[1][2], p[1][3]);
        pf[qt] = pu.v8;
    }

    #pragma unroll
    for (int qt = 0; qt < 2; qt++) {
        int qm = qt * 16 + lr;
        short* op = out + (size_t)((b * M + qm) * T + t) * D + h * 32;
        #pragma unroll
        for (int dt = 0; dt < 2; dt++) {
            const short* vb = &Xt[(h * 32 + dt * 16 + lr) * CTP + lg * 4];
            s16x4 a = *(const s16x4*)(vb);
            s16x4 bb = *(const s16x4*)(vb + 16);
            s16x8 vf = __builtin_shufflevector(a, bb, 0, 1, 2, 3, 4, 5, 6, 7);
            f32x4 Oa = __builtin_amdgcn_mfma_f32_16x16x32_bf16(vf, pf[qt], zacc, 0, 0, 0);
            union { unsigned u[2]; ushort4 s4; } ou;
            ou.u[0] = pkbf(Oa[0] * rl[qt], Oa[1] * rl[qt]);
            ou.u[1] = pkbf(Oa[2] * rl[qt], Oa[3] * rl[qt]);
            *(ushort4*)(op + dt * 16 + lg * 4) = ou.s4;
        }
    }
}

// ---------------- launch ----------------
extern "C" void kernel_launch(void* const* d_in, const int* in_sizes, int n_in,
                              void* d_out, int out_size, void* d_ws, size_t ws_size,
                              hipStream_t stream)
{
    (void)in_sizes; (void)n_in; (void)out_size; (void)ws_size;
    const float* xin = (const float*)d_in[0];
    const float* Wq  = (const float*)d_in[1];
    const float* bq  = (const float*)d_in[2];
    const float* Wk  = (const float*)d_in[3];
    const float* bk  = (const float*)d_in[4];
    const float* Wv  = (const float*)d_in[5];
    const float* bv  = (const float*)d_in[6];
    const float* Wfc = (const float*)d_in[7];
    const float* bfc = (const float*)d_in[8];
    const float* W1  = (const float*)d_in[9];
    const float* b1  = (const float*)d_in[10];
    const float* W2  = (const float*)d_in[11];
    const float* b2  = (const float*)d_in[12];
    const float* g1  = (const float*)d_in[13];
    const float* be1 = (const float*)d_in[14];
    const float* g2  = (const float*)d_in[15];
    const float* be2 = (const float*)d_in[16];
    const float* gf  = (const float*)d_in[17];
    const float* bef = (const float*)d_in[18];

    float* X = (float*)d_out;
    char* wsb = (char*)d_ws;
    const size_t SEGB = (size_t)NTOK * D * sizeof(float);   // 16 MiB
    const size_t SEGH = SEGB / 2;                           // 8 MiB bf16
    short* Qpb = (short*)(wsb + SEGH);
    short* Kpb = (short*)(wsb + 2 * SEGH);
    short* Vbf = (short*)(wsb + 3 * SEGH);
    short* CQb = (short*)(wsb + 4 * SEGH);
    short* CKb = (short*)(wsb + 5 * SEGH);
    short* Hbf = (short*)(wsb);          // MLP hidden 32 MiB spans seg 0..3 (Qpb..Vbf dead then)

    // packed bf16 weight table (matches cvt_all_kernel layout; each of Wq/Wk/Wv/Wfc
    // is 2 layers x 128 x 128 = 32768 elements)
    short* Wall = (short*)(wsb + 6 * SEGH);
    short* Wqb  = Wall;
    short* Wkb  = Wall + 32768;
    short* Wvb  = Wall + 65536;
    short* Wfcb = Wall + 98304;
    short* W1b  = Wall + 131072;
    short* W2b  = Wall + 262144;

    cvt_all_kernel<<<384, 256, 0, stream>>>(Wq, Wk, Wv, Wfc, W1, W2, Wall);

    for (int i = 0; i < 2; i++) {
        const float* xi  = i ? X : xin;   // LN1 input / FC residual
        qkv_ln_kernel<<<NTOK / 128, 512, 0, stream>>>(xi, g1 + i * D, be1 + i * D,
                                                      Wqb + i * D * D, Wkb + i * D * D, Wvb + i * D * D,
                                                      bq + i * D, bk + i * D, bv + i * D,
                                                      Qpb, Kpb, Vbf);
        ctx_mfma_kernel<<<dim3(B * M * (T / 64), 2), 256, 0, stream>>>(Qpb, CQb, Kpb, CKb);
        attn_mfma_kernel<<<B * M * H, 512, 0, stream>>>(CQb, CKb, Vbf, Qpb);
        crossm_mfma_kernel<<<B * T, 256, 0, stream>>>(Qpb, Kpb);
        gemm_bf16_kernel<128><<<dim3(1, NTOK / 128), 512, 0, stream>>>(Kpb, Wfcb + i * D * D, bfc + i * D, xi, X, D);
        mlp1_ln_kernel<<<NTOK / 128, 512, 0, stream>>>(X, g2 + i * D, be2 + i * D,
                                                       W1b + i * 4 * D * D, b1 + i * 4 * D, Hbf);
        gemm_bf16_kernel<512><<<dim3(1, NTOK / 128), 512, 0, stream>>>(Hbf, W2b + i * 4 * D * D, b2 + i * D, X, X, D);
    }
    ln_kernel<<<NTOK / 4, 256, 0, stream>>>(X, X, gf, bef);
}

// Round 9
// 231.092 us; speedup vs baseline: 6.7769x; 1.0215x over previous
//
#include <hip/hip_runtime.h>
#include <hip/hip_bf16.h>
#include <math.h>

#define B 2
#define M 32
#define T 512
#define D 128
#define H 4
#define DK 32
#define NTOK (B*M*T)   /* 32768 rows */

using s16x8 = __attribute__((ext_vector_type(8))) short;
using s16x4 = __attribute__((ext_vector_type(4))) short;
using f32x4 = __attribute__((ext_vector_type(4))) float;

__device__ __forceinline__ short f2bf(float x) {
    union { float f; unsigned u; } a; a.f = x;
    unsigned r = a.u + 0x7fffu + ((a.u >> 16) & 1u);   // RNE
    return (short)(r >> 16);
}
__device__ __forceinline__ unsigned pkbf(float lo, float hi) {
    union { __hip_bfloat162 h; unsigned u; } c;
    c.h = __float22bfloat162_rn(float2{lo, hi});
    return c.u;
}

// ---------------- all weights fp32 -> bf16 in one dispatch ----------------
// dst layout: Wq[0,32768) Wk[32768,65536) Wv[65536,98304) Wfc[98304,131072)
//             W1[131072,262144) W2[262144,393216)
__global__ __launch_bounds__(256) void cvt_all_kernel(const float* __restrict__ Wq, const float* __restrict__ Wk,
                                                      const float* __restrict__ Wv, const float* __restrict__ Wfc,
                                                      const float* __restrict__ W1, const float* __restrict__ W2,
                                                      short* __restrict__ dst)
{
    int i = (blockIdx.x * 256 + threadIdx.x) * 4;
    if (i >= 393216) return;
    const float* src; int off;
    if (i < 131072) {
        int wsel = i >> 15; off = i & 32767;
        src = (wsel == 0) ? Wq : (wsel == 1) ? Wk : (wsel == 2) ? Wv : Wfc;
    } else if (i < 262144) { src = W1; off = i - 131072; }
    else                   { src = W2; off = i - 262144; }
    float4 v = *(const float4*)(src + off);
    ushort4 u;
    u.x = (unsigned short)f2bf(v.x); u.y = (unsigned short)f2bf(v.y);
    u.z = (unsigned short)f2bf(v.z); u.w = (unsigned short)f2bf(v.w);
    *(ushort4*)(dst + i) = u;
}

// ---------------- LayerNorm (final only): one wave per row of 128, fp32 out ----------------
__global__ __launch_bounds__(256) void ln_kernel(const float* __restrict__ in, float* __restrict__ outf,
                                                 const float* __restrict__ g, const float* __restrict__ b)
{
    int wave = threadIdx.x >> 6;
    int lane = threadIdx.x & 63;
    int row  = blockIdx.x * 4 + wave;
    const float* rp = in + (size_t)row * D;
    float v0 = rp[lane], v1 = rp[lane + 64];
    float s = v0 + v1, ss = v0 * v0 + v1 * v1;
    #pragma unroll
    for (int off = 32; off; off >>= 1) { s += __shfl_xor(s, off); ss += __shfl_xor(ss, off); }
    float mu  = s * (1.0f / 128.0f);
    float var = ss * (1.0f / 128.0f) - mu * mu;
    float rs  = rsqrtf(var + 1e-6f);
    float* op = outf + (size_t)row * D;
    op[lane]      = (v0 - mu) * rs * g[lane]      + b[lane];
    op[lane + 64] = (v1 - mu) * rs * g[lane + 64] + b[lane + 64];
}

#define KP 136

// LN staging helper: computes LN of row (rowBase+sr), cols sq*32..+31, writes bf16 into As.
#define LN_STAGE(XPTR, GPTR, BEPTR)                                              \
    {                                                                            \
        const float* xp = (XPTR) + (size_t)(rowBase + sr) * D + sq * 32;         \
        float4 xv[8];                                                            \
        _Pragma("unroll")                                                        \
        for (int j = 0; j < 8; j++) xv[j] = *(const float4*)(xp + j * 4);        \
        float s = 0.0f, ss = 0.0f;                                               \
        _Pragma("unroll")                                                        \
        for (int j = 0; j < 8; j++) {                                            \
            s  += xv[j].x + xv[j].y + xv[j].z + xv[j].w;                         \
            ss += xv[j].x*xv[j].x + xv[j].y*xv[j].y + xv[j].z*xv[j].z + xv[j].w*xv[j].w; \
        }                                                                        \
        s  += __shfl_xor(s, 1);  s  += __shfl_xor(s, 2);                         \
        ss += __shfl_xor(ss, 1); ss += __shfl_xor(ss, 2);                        \
        float mu  = s * (1.0f / 128.0f);                                         \
        float var = ss * (1.0f / 128.0f) - mu * mu;                              \
        float rs  = rsqrtf(var + 1e-6f);                                         \
        const float* gp  = (GPTR) + sq * 32;                                     \
        const float* bep = (BEPTR) + sq * 32;                                    \
        short* asd = &As[sr * KP + sq * 32];                                     \
        _Pragma("unroll")                                                        \
        for (int c = 0; c < 4; c++) {                                            \
            float4 a0 = xv[2*c], a1 = xv[2*c+1];                                 \
            float4 g0 = *(const float4*)(gp + c * 8);                            \
            float4 g1 = *(const float4*)(gp + c * 8 + 4);                        \
            float4 b0 = *(const float4*)(bep + c * 8);                           \
            float4 b1 = *(const float4*)(bep + c * 8 + 4);                       \
            union { unsigned u[4]; s16x8 v8; } pu;                               \
            pu.u[0] = pkbf((a0.x-mu)*rs*g0.x+b0.x, (a0.y-mu)*rs*g0.y+b0.y);      \
            pu.u[1] = pkbf((a0.z-mu)*rs*g0.z+b0.z, (a0.w-mu)*rs*g0.w+b0.w);      \
            pu.u[2] = pkbf((a1.x-mu)*rs*g1.x+b1.x, (a1.y-mu)*rs*g1.y+b1.y);      \
            pu.u[3] = pkbf((a1.z-mu)*rs*g1.z+b1.z, (a1.w-mu)*rs*g1.w+b1.w);      \
            *(s16x8*)(asd + c * 8) = pu.v8;                                      \
        }                                                                        \
    }

// ---------------- Fused LN + Q/K/V projections: A tile staged once ----------------
__global__ __launch_bounds__(512) void qkv_ln_kernel(const float* __restrict__ X,
                                                     const float* __restrict__ g, const float* __restrict__ be,
                                                     const short* __restrict__ Wq, const short* __restrict__ Wk,
                                                     const short* __restrict__ Wv,
                                                     const float* __restrict__ bq, const float* __restrict__ bk,
                                                     const float* __restrict__ bv,
                                                     short* __restrict__ Qo, short* __restrict__ Ko,
                                                     short* __restrict__ Vo)
{
    __shared__ short As[128 * KP];
    __shared__ short Ws[128 * KP];
    const int tid = threadIdx.x;
    const int rowBase = blockIdx.x * 128;
    const int sr = tid >> 2, sq = tid & 3;
    const int w = tid >> 6, l = tid & 63;
    const int lg = l >> 4, lr = l & 15;
    const int wr = w >> 2, wc = w & 3;

    LN_STAGE(X, g, be)

    const short* wsrc[3] = { Wq, Wk, Wv };
    const float* bsrc[3] = { bq, bk, bv };
    short*       osrc[3] = { Qo, Ko, Vo };

    for (int gsel = 0; gsel < 3; gsel++) {
        s16x8 wv4[4];
        const short* wp = wsrc[gsel] + (size_t)sr * D + sq * 32;
        #pragma unroll
        for (int i = 0; i < 4; i++) wv4[i] = *(const s16x8*)(wp + i * 8);
        __syncthreads();                         // prev readers of Ws done (also A visible on gsel=0)
        short* wsd = &Ws[sr * KP + sq * 32];
        #pragma unroll
        for (int i = 0; i < 4; i++) *(s16x8*)(wsd + i * 8) = wv4[i];
        __syncthreads();

        f32x4 acc[4][2];
        #pragma unroll
        for (int qi = 0; qi < 4; qi++)
            #pragma unroll
            for (int nj = 0; nj < 2; nj++)
                acc[qi][nj] = (f32x4){0.0f, 0.0f, 0.0f, 0.0f};
        #pragma unroll
        for (int kk = 0; kk < 4; kk++) {
            s16x8 af[4], bfr[2];
            #pragma unroll
            for (int qi = 0; qi < 4; qi++)
                af[qi] = *(const s16x8*)&As[(wr * 64 + qi * 16 + lr) * KP + kk * 32 + lg * 8];
            #pragma unroll
            for (int nj = 0; nj < 2; nj++)
                bfr[nj] = *(const s16x8*)&Ws[(wc * 32 + nj * 16 + lr) * KP + kk * 32 + lg * 8];
            #pragma unroll
            for (int qi = 0; qi < 4; qi++)
                #pragma unroll
                for (int nj = 0; nj < 2; nj++)
                    acc[qi][nj] = __builtin_amdgcn_mfma_f32_16x16x32_bf16(af[qi], bfr[nj], acc[qi][nj], 0, 0, 0);
        }
        #pragma unroll
        for (int nj = 0; nj < 2; nj++) {
            int col = wc * 32 + nj * 16 + lr;
            float bb = bsrc[gsel][col];
            #pragma unroll
            for (int qi = 0; qi < 4; qi++) {
                #pragma unroll
                for (int rr = 0; rr < 4; rr++) {
                    int row = rowBase + wr * 64 + qi * 16 + lg * 4 + rr;
                    osrc[gsel][(size_t)row * D + col] = f2bf(acc[qi][nj][rr] + bb);
                }
            }
        }
    }
}

// ---------------- Fused LN + MLP-W1 (relu), Dout=512 via internal col loop ----------------
__global__ __launch_bounds__(512) void mlp1_ln_kernel(const float* __restrict__ X,
                                                      const float* __restrict__ g, const float* __restrict__ be,
                                                      const short* __restrict__ W1, const float* __restrict__ b1,
                                                      short* __restrict__ Hb)
{
    __shared__ short As[128 * KP];
    __shared__ short Ws[128 * KP];
    const int tid = threadIdx.x;
    const int rowBase = blockIdx.x * 128;
    const int sr = tid >> 2, sq = tid & 3;
    const int w = tid >> 6, l = tid & 63;
    const int lg = l >> 4, lr = l & 15;
    const int wr = w >> 2, wc = w & 3;

    LN_STAGE(X, g, be)

    for (int ct = 0; ct < 4; ct++) {
        s16x8 wv4[4];
        const short* wp = W1 + (size_t)(ct * 128 + sr) * D + sq * 32;
        #pragma unroll
        for (int i = 0; i < 4; i++) wv4[i] = *(const s16x8*)(wp + i * 8);
        __syncthreads();
        short* wsd = &Ws[sr * KP + sq * 32];
        #pragma unroll
        for (int i = 0; i < 4; i++) *(s16x8*)(wsd + i * 8) = wv4[i];
        __syncthreads();

        f32x4 acc[4][2];
        #pragma unroll
        for (int qi = 0; qi < 4; qi++)
            #pragma unroll
            for (int nj = 0; nj < 2; nj++)
                acc[qi][nj] = (f32x4){0.0f, 0.0f, 0.0f, 0.0f};
        #pragma unroll
        for (int kk = 0; kk < 4; kk++) {
            s16x8 af[4], bfr[2];
            #pragma unroll
            for (int qi = 0; qi < 4; qi++)
                af[qi] = *(const s16x8*)&As[(wr * 64 + qi * 16 + lr) * KP + kk * 32 + lg * 8];
            #pragma unroll
            for (int nj = 0; nj < 2; nj++)
                bfr[nj] = *(const s16x8*)&Ws[(wc * 32 + nj * 16 + lr) * KP + kk * 32 + lg * 8];
            #pragma unroll
            for (int qi = 0; qi < 4; qi++)
                #pragma unroll
                for (int nj = 0; nj < 2; nj++)
                    acc[qi][nj] = __builtin_amdgcn_mfma_f32_16x16x32_bf16(af[qi], bfr[nj], acc[qi][nj], 0, 0, 0);
        }
        #pragma unroll
        for (int nj = 0; nj < 2; nj++) {
            int col = ct * 128 + wc * 32 + nj * 16 + lr;
            float bb = b1[col];
            #pragma unroll
            for (int qi = 0; qi < 4; qi++) {
                #pragma unroll
                for (int rr = 0; rr < 4; rr++) {
                    int row = rowBase + wr * 64 + qi * 16 + lg * 4 + rr;
                    Hb[(size_t)row * 512 + col] = f2bf(fmaxf(acc[qi][nj][rr] + bb, 0.0f));
                }
            }
        }
    }
}

// ---------------- bf16 MFMA GEMM (FC and MLP-W2): out = A . W^T + bias + res ----------------
template<int DIN>
__global__ __launch_bounds__(512) void gemm_bf16_kernel(const short* __restrict__ A, const short* __restrict__ W,
                                                        const float* __restrict__ bias, const float* __restrict__ res,
                                                        float* __restrict__ outf, int Dout)
{
    __shared__ short As[128 * KP];
    __shared__ short Ws[128 * KP];
    const int tid = threadIdx.x;
    const int rowBase = blockIdx.y * 128;
    const int colBase = blockIdx.x * 128;
    const int sr = tid >> 2, sq = tid & 3;
    const int w = tid >> 6, l = tid & 63;
    const int lg = l >> 4, lr = l & 15;
    const int wr = w >> 2, wc = w & 3;

    f32x4 acc[4][2];
    #pragma unroll
    for (int qi = 0; qi < 4; qi++)
        #pragma unroll
        for (int nj = 0; nj < 2; nj++)
            acc[qi][nj] = (f32x4){0.0f, 0.0f, 0.0f, 0.0f};

    const short* ap = A + (size_t)(rowBase + sr) * DIN + sq * 32;
    const short* wp = W + (size_t)(colBase + sr) * DIN + sq * 32;
    short* asd = &As[sr * KP + sq * 32];
    short* wsd = &Ws[sr * KP + sq * 32];

    #pragma unroll
    for (int kt = 0; kt < DIN / 128; kt++) {
        s16x8 av[4], wv[4];
        #pragma unroll
        for (int i = 0; i < 4; i++) {
            av[i] = *(const s16x8*)(ap + kt * 128 + i * 8);
            wv[i] = *(const s16x8*)(wp + kt * 128 + i * 8);
        }
        if (kt) __syncthreads();
        #pragma unroll
        for (int i = 0; i < 4; i++) {
            *(s16x8*)(asd + i * 8) = av[i];
            *(s16x8*)(wsd + i * 8) = wv[i];
        }
        __syncthreads();
        #pragma unroll
        for (int kk = 0; kk < 4; kk++) {
            s16x8 af[4], bfr[2];
            #pragma unroll
            for (int qi = 0; qi < 4; qi++)
                af[qi] = *(const s16x8*)&As[(wr * 64 + qi * 16 + lr) * KP + kk * 32 + lg * 8];
            #pragma unroll
            for (int nj = 0; nj < 2; nj++)
                bfr[nj] = *(const s16x8*)&Ws[(wc * 32 + nj * 16 + lr) * KP + kk * 32 + lg * 8];
            #pragma unroll
            for (int qi = 0; qi < 4; qi++)
                #pragma unroll
                for (int nj = 0; nj < 2; nj++)
                    acc[qi][nj] = __builtin_amdgcn_mfma_f32_16x16x32_bf16(af[qi], bfr[nj], acc[qi][nj], 0, 0, 0);
        }
    }

    #pragma unroll
    for (int nj = 0; nj < 2; nj++) {
        int col = colBase + wc * 32 + nj * 16 + lr;
        float bb = bias[col];
        #pragma unroll
        for (int qi = 0; qi < 4; qi++) {
            #pragma unroll
            for (int rr = 0; rr < 4; rr++) {
                int row = rowBase + wr * 64 + qi * 16 + lg * 4 + rr;
                size_t o = (size_t)row * Dout + col;
                outf[o] = acc[qi][nj][rr] + bb + res[o];
            }
        }
    }
}

// ---------------- Context attention via banded MFMA (window L=16, d=128) ----------------
#define XSP 136
#define XTP 84
__global__ __launch_bounds__(256) void ctx_mfma_kernel(const short* __restrict__ in0, short* __restrict__ out0,
                                                       const short* __restrict__ in1, short* __restrict__ out1)
{
    __shared__ short Xs[80 * XSP];
    __shared__ short Xt[128 * XTP];

    const short* in  = blockIdx.y ? in1 : in0;
    short*       out = blockIdx.y ? out1 : out0;
    int bm = blockIdx.x >> 3;
    int t0 = (blockIdx.x & 7) * 64;
    int tid = threadIdx.x;
    const short* base = in + (size_t)bm * T * D;

    #pragma unroll
    for (int it = 0; it < 5; it++) {
        int idx = it * 256 + tid;
        int row = idx >> 4, c16 = idx & 15;
        int t = t0 - 16 + row;
        s16x8 v = {0, 0, 0, 0, 0, 0, 0, 0};
        if (t >= 0) v = *(const s16x8*)(base + (size_t)t * D + c16 * 8);
        *(s16x8*)&Xs[row * XSP + c16 * 8] = v;
    }
    __syncthreads();
    #pragma unroll
    for (int it = 0; it < 5; it++) {
        int task = it * 256 + tid;
        int g = task / 80, row = task % 80;
        s16x8 v = *(const s16x8*)&Xs[row * XSP + g * 8];
        #pragma unroll
        for (int j = 0; j < 8; j++) Xt[(g * 8 + j) * XTP + row] = v[j];
    }
    __syncthreads();

    int w = tid >> 6, l = tid & 63;
    int lg = l >> 4, lr = l & 15;
    f32x4 zacc = {0.0f, 0.0f, 0.0f, 0.0f};
    const float C1 = 0.0883883476483184f * 1.4426950408889634f;   // (1/sqrt(128))*log2e

    s16x8 qf[4];
    #pragma unroll
    for (int kd = 0; kd < 4; kd++)
        qf[kd] = *(const s16x8*)&Xs[(16 + w * 16 + lr) * XSP + kd * 32 + lg * 8];

    f32x4 sacc[2];
    #pragma unroll
    for (int s = 0; s < 2; s++) {
        f32x4 a = zacc;
        #pragma unroll
        for (int kd = 0; kd < 4; kd++) {
            s16x8 kf = *(const s16x8*)&Xs[(w * 16 + s * 16 + lr) * XSP + kd * 32 + lg * 8];
            a = __builtin_amdgcn_mfma_f32_16x16x32_bf16(kf, qf[kd], a, 0, 0, 0);
        }
        sacc[s] = a;
    }

    float p[2][4];
    float mx = -1e30f;
    #pragma unroll
    for (int s = 0; s < 2; s++)
        #pragma unroll
        for (int r = 0; r < 4; r++) {
            int dlt = s * 16 + lg * 4 + r - 16 - lr;   // k - q
            float val = (dlt >= -15 && dlt <= 0) ? sacc[s][r] : -1e30f;
            p[s][r] = val;
            mx = fmaxf(mx, val);
        }
    mx = fmaxf(mx, __shfl_xor(mx, 16));
    mx = fmaxf(mx, __shfl_xor(mx, 32));
    float mc = mx * C1;
    float ps = 0.0f;
    #pragma unroll
    for (int s = 0; s < 2; s++)
        #pragma unroll
        for (int r = 0; r < 4; r++) {
            float e = exp2f(fmaf(p[s][r], C1, -mc));
            p[s][r] = e;
            ps += e;
        }
    ps += __shfl_xor(ps, 16);
    ps += __shfl_xor(ps, 32);

    union { unsigned u[4]; s16x8 v8; } pu;
    pu.u[0] = pkbf(p[0][0], p[0][1]);
    pu.u[1] = pkbf(p[0][2], p[0][3]);
    pu.u[2] = pkbf(p[1][0], p[1][1]);
    pu.u[3] = pkbf(p[1][2], p[1][3]);
    s16x8 pf = pu.v8;

    float rl = 1.0f / ps;
    short* op = out + (size_t)(bm * T + t0 + w * 16 + lr) * D;
    #pragma unroll
    for (int dt = 0; dt < 8; dt++) {
        const short* vb = &Xt[(dt * 16 + lr) * XTP + w * 16 + lg * 4];
        s16x4 a = *(const s16x4*)(vb);
        s16x4 b = *(const s16x4*)(vb + 16);
        s16x8 vf = __builtin_shufflevector(a, b, 0, 1, 2, 3, 4, 5, 6, 7);
        f32x4 Oa = __builtin_amdgcn_mfma_f32_16x16x32_bf16(vf, pf, zacc, 0, 0, 0);
        union { unsigned u[2]; ushort4 s4; } ou;
        ou.u[0] = pkbf(Oa[0] * rl, Oa[1] * rl);
        ou.u[1] = pkbf(Oa[2] * rl, Oa[3] * rl);
        *(ushort4*)(op + dt * 16 + lg * 4) = ou.s4;
    }
}

// ---------------- Full attention per (b,m,h): fixed-max bf16 MFMA flash ----------------
// 1024 threads = 16 waves = 4 waves/SIMD (one workgroup, co-resident) -> 2x the
// latency hiding of the 512-thread version at identical staging traffic.
#define KPAD 40
#define VTP  520
__global__ __launch_bounds__(1024) void attn_mfma_kernel(const short* __restrict__ q, const short* __restrict__ k,
                                                         const short* __restrict__ v, short* __restrict__ out)
{
    __shared__ short Ks[512 * KPAD];
    __shared__ short Vt[32 * VTP];

    int h  = blockIdx.x & 3;
    int bm = blockIdx.x >> 2;
    int tid = threadIdx.x;
    size_t headoff = (size_t)(bm * T) * D + h * DK;

    {
        int row = tid >> 1, half = tid & 1;         // 32B of the 64B head slice per thread
        const s16x8* kp8 = (const s16x8*)(k + headoff + (size_t)row * D + half * 16);
        s16x8 k0 = kp8[0], k1 = kp8[1];
        short* kd = &Ks[row * KPAD + half * 16];
        *(s16x8*)(kd)     = k0;
        *(s16x8*)(kd + 8) = k1;
        const s16x8* vp8 = (const s16x8*)(v + headoff + (size_t)row * D + half * 16);
        s16x8 v0 = vp8[0], v1 = vp8[1];
        #pragma unroll
        for (int d = 0; d < 8; d++) {
            Vt[(half * 16 + d) * VTP + row]     = v0[d];
            Vt[(half * 16 + 8 + d) * VTP + row] = v1[d];
        }
    }
    __syncthreads();

    int w = tid >> 6, l = tid & 63;
    int lg = l >> 4, lr = l & 15;
    int qw = w * 32;

    s16x8 qf[2];
    #pragma unroll
    for (int qi = 0; qi < 2; qi++)
        qf[qi] = *(const s16x8*)(q + headoff + (size_t)(qw + qi * 16 + lr) * D + lg * 8);

    f32x4 Oa[2][2];
    float lrow[2];
    #pragma unroll
    for (int qi = 0; qi < 2; qi++) {
        lrow[qi] = 0.0f;
        #pragma unroll
        for (int r = 0; r < 4; r++) { Oa[qi][0][r] = 0.0f; Oa[qi][1][r] = 0.0f; }
    }
    const float C1 = 0.17677669529663689f * 1.4426950408889634f;   // (1/sqrt(32))*log2e
    f32x4 zacc = {0.0f, 0.0f, 0.0f, 0.0f};

    for (int kt = 0; kt < 8; kt++) {
        int kb = kt * 64;
        s16x8 kf[2][2];
        #pragma unroll
        for (int s = 0; s < 2; s++)
            #pragma unroll
            for (int hh = 0; hh < 2; hh++)
                kf[s][hh] = *(const s16x8*)&Ks[(kb + s * 32 + hh * 16 + lr) * KPAD + lg * 8];
        s16x8 vf[2][2];
        #pragma unroll
        for (int dh = 0; dh < 2; dh++)
            #pragma unroll
            for (int s = 0; s < 2; s++) {
                const short* vb = &Vt[(dh * 16 + lr) * VTP + kb + s * 32 + lg * 4];
                s16x4 a = *(const s16x4*)(vb);
                s16x4 b = *(const s16x4*)(vb + 16);
                vf[dh][s] = __builtin_shufflevector(a, b, 0, 1, 2, 3, 4, 5, 6, 7);
            }
        #pragma unroll
        for (int qi = 0; qi < 2; qi++) {
            f32x4 sa[2][2];
            #pragma unroll
            for (int s = 0; s < 2; s++)
                #pragma unroll
                for (int hh = 0; hh < 2; hh++)
                    sa[s][hh] = __builtin_amdgcn_mfma_f32_16x16x32_bf16(kf[s][hh], qf[qi], zacc, 0, 0, 0);
            float p[2][8];
            float ps = 0.0f;
            #pragma unroll
            for (int s = 0; s < 2; s++)
                #pragma unroll
                for (int hh = 0; hh < 2; hh++)
                    #pragma unroll
                    for (int r = 0; r < 4; r++) {
                        float e = exp2f(sa[s][hh][r] * C1);
                        p[s][hh * 4 + r] = e;
                        ps += e;
                    }
            lrow[qi] += ps;
            s16x8 pf[2];
            #pragma unroll
            for (int s = 0; s < 2; s++) {
                union { unsigned u[4]; s16x8 v8; } pu;
                pu.u[0] = pkbf(p[s][0], p[s][1]);
                pu.u[1] = pkbf(p[s][2], p[s][3]);
                pu.u[2] = pkbf(p[s][4], p[s][5]);
                pu.u[3] = pkbf(p[s][6], p[s][7]);
                pf[s] = pu.v8;
            }
            #pragma unroll
            for (int dh = 0; dh < 2; dh++)
                #pragma unroll
                for (int s = 0; s < 2; s++)
                    Oa[qi][dh] = __builtin_amdgcn_mfma_f32_16x16x32_bf16(vf[dh][s], pf[s], Oa[qi][dh], 0, 0, 0);
        }
    }

    #pragma unroll
    for (int qi = 0; qi < 2; qi++) {
        float lv = lrow[qi];
        lv += __shfl_xor(lv, 16);
        lv += __shfl_xor(lv, 32);
        float rl = 1.0f / lv;
        int qrow = qw + qi * 16 + lr;
        short* op = out + headoff + (size_t)qrow * D;
        #pragma unroll
        for (int dh = 0; dh < 2; dh++) {
            union { unsigned u[2]; ushort4 s4; } ou;
            ou.u[0] = pkbf(Oa[qi][dh][0] * rl, Oa[qi][dh][1] * rl);
            ou.u[1] = pkbf(Oa[qi][dh][2] * rl, Oa[qi][dh][3] * rl);
            *(ushort4*)(op + dh * 16 + lg * 4) = ou.s4;
        }
    }
}

// ---------------- Cross-m attention per (b,t) via MFMA: 4 waves = 4 heads of 32x32 ----------------
#define CXP 136
#define CTP 36
__global__ __launch_bounds__(256) void crossm_mfma_kernel(const short* __restrict__ in, short* __restrict__ out)
{
    __shared__ short Xs[32 * CXP];
    __shared__ short Xt[128 * CTP];
    int b = blockIdx.x >> 9;
    int t = blockIdx.x & 511;
    int tid = threadIdx.x;

    #pragma unroll
    for (int it = 0; it < 2; it++) {
        int idx = it * 256 + tid;
        int m = idx >> 4, c16 = idx & 15;
        s16x8 v = *(const s16x8*)(in + (size_t)((b * M + m) * T + t) * D + c16 * 8);
        *(s16x8*)&Xs[m * CXP + c16 * 8] = v;
    }
    __syncthreads();
    #pragma unroll
    for (int it = 0; it < 2; it++) {
        int task = it * 256 + tid;
        int g = task >> 5, m = task & 31;
        s16x8 v = *(const s16x8*)&Xs[m * CXP + g * 8];
        #pragma unroll
        for (int j = 0; j < 8; j++) Xt[(g * 8 + j) * CTP + m] = v[j];
    }
    __syncthreads();

    int h = tid >> 6, l = tid & 63;
    int lg = l >> 4, lr = l & 15;
    f32x4 zacc = {0.0f, 0.0f, 0.0f, 0.0f};
    const float C1 = 0.17677669529663689f * 1.4426950408889634f;

    s16x8 xf[2];
    #pragma unroll
    for (int i = 0; i < 2; i++)
        xf[i] = *(const s16x8*)&Xs[(i * 16 + lr) * CXP + h * 32 + lg * 8];

    f32x4 sacc[2][2];
    #pragma unroll
    for (int kt = 0; kt < 2; kt++)
        #pragma unroll
        for (int qt = 0; qt < 2; qt++)
            sacc[kt][qt] = __builtin_amdgcn_mfma_f32_16x16x32_bf16(xf[kt], xf[qt], zacc, 0, 0, 0);

    s16x8 pf[2];
    float rl[2];
    #pragma unroll
    for (int qt = 0; qt < 2; qt++) {
        float p[2][4];
        float ps = 0.0f;
        #pragma unroll
        for (int kt = 0; kt < 2; kt++)
            #pragma unroll
            for (int r = 0; r < 4; r++) {
                float e = exp2f(sacc[kt][qt][r] * C1);
                p[kt][r] = e;
                ps += e;
            }
        ps += __shfl_xor(ps, 16);
        ps += __shfl_xor(ps, 32);
        rl[qt] = 1.0f / ps;
        union { unsigned u[4]; s16x8 v8; } pu;
        pu.u[0] = pkbf(p[0][0], p[0][1]);
        pu.u[1] = pkbf(p[0][2], p[0][3]);
        pu.u[2] = pkbf(p[1][0], p[1][1]);
        pu.u[3] = pkbf(p[1][2], p[1][3]);
        pf[qt] = pu.v8;
    }

    #pragma unroll
    for (int qt = 0; qt < 2; qt++) {
        int qm = qt * 16 + lr;
        short* op = out + (size_t)((b * M + qm) * T + t) * D + h * 32;
        #pragma unroll
        for (int dt = 0; dt < 2; dt++) {
            const short* vb = &Xt[(h * 32 + dt * 16 + lr) * CTP + lg * 4];
            s16x4 a = *(const s16x4*)(vb);
            s16x4 bb = *(const s16x4*)(vb + 16);
            s16x8 vf = __builtin_shufflevector(a, bb, 0, 1, 2, 3, 4, 5, 6, 7);
            f32x4 Oa = __builtin_amdgcn_mfma_f32_16x16x32_bf16(vf, pf[qt], zacc, 0, 0, 0);
            union { unsigned u[2]; ushort4 s4; } ou;
            ou.u[0] = pkbf(Oa[0] * rl[qt], Oa[1] * rl[qt]);
            ou.u[1] = pkbf(Oa[2] * rl[qt], Oa[3] * rl[qt]);
            *(ushort4*)(op + dt * 16 + lg * 4) = ou.s4;
        }
    }
}

// ---------------- launch ----------------
extern "C" void kernel_launch(void* const* d_in, const int* in_sizes, int n_in,
                              void* d_out, int out_size, void* d_ws, size_t ws_size,
                              hipStream_t stream)
{
    (void)in_sizes; (void)n_in; (void)out_size; (void)ws_size;
    const float* xin = (const float*)d_in[0];
    const float* Wq  = (const float*)d_in[1];
    const float* bq  = (const float*)d_in[2];
    const float* Wk  = (const float*)d_in[3];
    const float* bk  = (const float*)d_in[4];
    const float* Wv  = (const float*)d_in[5];
    const float* bv  = (const float*)d_in[6];
    const float* Wfc = (const float*)d_in[7];
    const float* bfc = (const float*)d_in[8];
    const float* W1  = (const float*)d_in[9];
    const float* b1  = (const float*)d_in[10];
    const float* W2  = (const float*)d_in[11];
    const float* b2  = (const float*)d_in[12];
    const float* g1  = (const float*)d_in[13];
    const float* be1 = (const float*)d_in[14];
    const float* g2  = (const float*)d_in[15];
    const float* be2 = (const float*)d_in[16];
    const float* gf  = (const float*)d_in[17];
    const float* bef = (const float*)d_in[18];

    float* X = (float*)d_out;
    char* wsb = (char*)d_ws;
    const size_t SEGB = (size_t)NTOK * D * sizeof(float);   // 16 MiB
    const size_t SEGH = SEGB / 2;                           // 8 MiB bf16
    short* Qpb = (short*)(wsb + SEGH);
    short* Kpb = (short*)(wsb + 2 * SEGH);
    short* Vbf = (short*)(wsb + 3 * SEGH);
    short* CQb = (short*)(wsb + 4 * SEGH);
    short* CKb = (short*)(wsb + 5 * SEGH);
    short* Hbf = (short*)(wsb);          // MLP hidden 32 MiB spans seg 0..3 (Qpb..Vbf dead then)

    // packed bf16 weight table (matches cvt_all_kernel layout)
    short* Wall = (short*)(wsb + 6 * SEGH);
    short* Wqb  = Wall;
    short* Wkb  = Wall + 32768;
    short* Wvb  = Wall + 65536;
    short* Wfcb = Wall + 98304;
    short* W1b  = Wall + 131072;
    short* W2b  = Wall + 262144;

    cvt_all_kernel<<<384, 256, 0, stream>>>(Wq, Wk, Wv, Wfc, W1, W2, Wall);

    for (int i = 0; i < 2; i++) {
        const float* xi  = i ? X : xin;   // LN1 input / FC residual
        qkv_ln_kernel<<<NTOK / 128, 512, 0, stream>>>(xi, g1 + i * D, be1 + i * D,
                                                      Wqb + i * D * D, Wkb + i * D * D, Wvb + i * D * D,
                                                      bq + i * D, bk + i * D, bv + i * D,
                                                      Qpb, Kpb, Vbf);
        ctx_mfma_kernel<<<dim3(B * M * (T / 64), 2), 256, 0, stream>>>(Qpb, CQb, Kpb, CKb);
        attn_mfma_kernel<<<B * M * H, 1024, 0, stream>>>(CQb, CKb, Vbf, Qpb);
        crossm_mfma_kernel<<<B * T, 256, 0, stream>>>(Qpb, Kpb);
        gemm_bf16_kernel<128><<<dim3(1, NTOK / 128), 512, 0, stream>>>(Kpb, Wfcb + i * D * D, bfc + i * D, xi, X, D);
        mlp1_ln_kernel<<<NTOK / 128, 512, 0, stream>>>(X, g2 + i * D, be2 + i * D,
                                                       W1b + i * 4 * D * D, b1 + i * 4 * D, Hbf);
        gemm_bf16_kernel<512><<<dim3(1, NTOK / 128), 512, 0, stream>>>(Hbf, W2b + i * 4 * D * D, b2 + i * D, X, X, D);
    }
    ln_kernel<<<NTOK / 4, 256, 0, stream>>>(X, X, gf, bef);
}